// Round 6
// baseline (247.914 us; speedup 1.0000x reference)
//
#include <hip/hip_runtime.h>
#include <hip/hip_bf16.h>

// Problem constants (B=2, N=2048, DIM=1024, H=16, HD=64, BS=64, M=32)
#define BB 2
#define NN 2048
#define DIMD 1024
#define HH 16
#define HD64 64
#define MB 32
#define SCALE_F 0.125f   // HD^-0.5

typedef __attribute__((ext_vector_type(8))) short bf16x8;
typedef __attribute__((ext_vector_type(8))) short short8v;
typedef __attribute__((ext_vector_type(4))) float f32x4;
typedef _Float16 f16;
typedef __attribute__((ext_vector_type(8))) _Float16 f16x8;

#define LSTR 72   // padded LDS row stride (f16) for Pb

// counted-vmcnt barrier discipline (T4)
#define VM_WAIT8 asm volatile("s_waitcnt vmcnt(8)" ::: "memory")
#define VM_WAIT6 asm volatile("s_waitcnt vmcnt(6)" ::: "memory")
#define VM_WAIT0 asm volatile("s_waitcnt vmcnt(0)" ::: "memory")
#define SBAR __builtin_amdgcn_s_barrier()
#define SCHED0 __builtin_amdgcn_sched_barrier(0)

__device__ __forceinline__ unsigned short bf16_hi(float f) {
    return __builtin_bit_cast(unsigned short, __float2bfloat16(f));
}
__device__ __forceinline__ float bf16_val(unsigned short u) {
    return __bfloat162float(__builtin_bit_cast(__hip_bfloat16, u));
}
__device__ __forceinline__ void async_copy16(const void* g, void* l) {
    __builtin_amdgcn_global_load_lds((const __attribute__((address_space(1))) void*)g,
                                     (__attribute__((address_space(3))) void*)l, 16, 0, 0);
}

// ===========================================================================
// FAST PATH
// ===========================================================================

// Fused input split: [0,4096) x -> Axs; [4096,7168) qkv_w -> Wqs;
// [7168,8192) proj_w -> Wp (R6: moved off the qkv->attn critical path).
__global__ __launch_bounds__(256) void split_in_fused_kernel(
    const float* __restrict__ x, short* __restrict__ Axs,
    const float* __restrict__ w, short* __restrict__ Wqs,
    const float* __restrict__ pw, short* __restrict__ Wp)
{
    const int bid = blockIdx.x;
    const float* src; short* dst; int idx;
    if (bid < 4096)      { src = x;  dst = Axs; idx = bid * 256 + threadIdx.x; }
    else if (bid < 7168) { src = w;  dst = Wqs; idx = (bid - 4096) * 256 + threadIdx.x; }
    else                 { src = pw; dst = Wp;  idx = (bid - 7168) * 256 + threadIdx.x; }
    int e = idx * 4;
    int r = e >> 10, c = e & 1023;
    float4 v = *(const float4*)(src + e);
    unsigned short h0 = bf16_hi(v.x), h1 = bf16_hi(v.y), h2 = bf16_hi(v.z), h3 = bf16_hi(v.w);
    unsigned short l0 = bf16_hi(v.x - bf16_val(h0));
    unsigned short l1 = bf16_hi(v.y - bf16_val(h1));
    unsigned short l2 = bf16_hi(v.z - bf16_val(h2));
    unsigned short l3 = bf16_hi(v.w - bf16_val(h3));
    size_t base = (size_t)r * 2048 + c;
    *(ushort4*)(dst + base)        = make_ushort4(h0, h1, h2, h3);
    *(ushort4*)(dst + base + 1024) = make_ushort4(l0, l1, l2, l3);
}

// QKV GEMM via bf16x3 MFMA, R4-proven counted-vmcnt 2-phase pipeline.
// R6: XCD-chunked blockIdx swizzle (T1): 768 = 8 XCDs x 96 contiguous wgs;
// same-row blocks (sharing the A panel) co-reside on one XCD's L2.
// Epilogue writes producer-formatted f16 images (R5-proven).
__global__ __launch_bounds__(256) void qkv_mfma_kernel(
    const short* __restrict__ A, const short* __restrict__ W,
    short* __restrict__ QhI, short* __restrict__ QlI,
    short* __restrict__ KhI, short* __restrict__ KlI,
    short* __restrict__ VtI,
    float* __restrict__ qbf, float* __restrict__ kbf)
{
    __shared__ short SM[32768];   // 64 KB: 4 planes x 2 bufs x 4096 shorts
    const int bid = blockIdx.x;
    const int wg = (bid & 7) * 96 + (bid >> 3);   // bijective (768 % 8 == 0)
    const int row0 = (wg / 24) * 128;
    const int col0 = (wg % 24) * 128;
    const int tid = threadIdx.x;
    const int lane = tid & 63;
    const int wave = tid >> 6;
    const int wm = wave & 1, wn = wave >> 1;

    auto AHS = [&](int b) { return SM + b * 4096; };
    auto ALS = [&](int b) { return SM + 8192 + b * 4096; };
    auto WHS = [&](int b) { return SM + 16384 + b * 4096; };
    auto WLS = [&](int b) { return SM + 24576 + b * 4096; };

    f32x4 acc[4][4];
    const f32x4 zero = {0.f, 0.f, 0.f, 0.f};
    #pragma unroll
    for (int i = 0; i < 4; ++i)
        #pragma unroll
        for (int j = 0; j < 4; ++j) acc[i][j] = zero;

    const int ldr = lane >> 2;                              // row in 16-row chunk
    const int lko = (((lane & 3) ^ ((lane >> 3) & 3))) * 8; // swizzled k-chunk
    const int rsl = ((lane >> 4) ^ ((lane >> 1) & 3)) * 8;  // frag-read slot

    // 8 global_load_lds per wave per call (the vmcnt quantum)
    auto stage = [&](int bufi, int ktn) {
        const int kk = ktn << 5;
        #pragma unroll
        for (int i = 0; i < 2; ++i) {
            const int chunk = wave * 2 + i;
            const short* gA = A + (size_t)(row0 + chunk * 16 + ldr) * 2048 + kk + lko;
            const short* gW = W + (size_t)(col0 + chunk * 16 + ldr) * 2048 + kk + lko;
            async_copy16(gA,        (char*)AHS(bufi) + chunk * 1024);   // A hi
            async_copy16(gA + 1024, (char*)ALS(bufi) + chunk * 1024);   // A lo
            async_copy16(gW,        (char*)WHS(bufi) + chunk * 1024);   // W hi
            async_copy16(gW + 1024, (char*)WLS(bufi) + chunk * 1024);   // W lo
        }
    };

    auto compute = [&](int bufi) {
        const short* Ah = AHS(bufi);
        const short* Al = ALS(bufi);
        const short* Wh = WHS(bufi);
        const short* Wl = WLS(bufi);
        // cluster 1: Ah x Wh
        bf16x8 ah[4], wh[4];
        #pragma unroll
        for (int mi = 0; mi < 4; ++mi)
            ah[mi] = *(const bf16x8*)(Ah + (wm * 64 + mi * 16 + (lane & 15)) * 32 + rsl);
        #pragma unroll
        for (int ni = 0; ni < 4; ++ni)
            wh[ni] = *(const bf16x8*)(Wh + (wn * 64 + ni * 16 + (lane & 15)) * 32 + rsl);
        #pragma unroll
        for (int mi = 0; mi < 4; ++mi)
            #pragma unroll
            for (int ni = 0; ni < 4; ++ni)
                acc[mi][ni] = __builtin_amdgcn_mfma_f32_16x16x32_bf16(ah[mi], wh[ni], acc[mi][ni], 0, 0, 0);
        // cluster 2: Ah x Wl
        bf16x8 wl[4];
        #pragma unroll
        for (int ni = 0; ni < 4; ++ni)
            wl[ni] = *(const bf16x8*)(Wl + (wn * 64 + ni * 16 + (lane & 15)) * 32 + rsl);
        #pragma unroll
        for (int mi = 0; mi < 4; ++mi)
            #pragma unroll
            for (int ni = 0; ni < 4; ++ni)
                acc[mi][ni] = __builtin_amdgcn_mfma_f32_16x16x32_bf16(ah[mi], wl[ni], acc[mi][ni], 0, 0, 0);
        // cluster 3: Al x Wh
        bf16x8 al[4];
        #pragma unroll
        for (int mi = 0; mi < 4; ++mi)
            al[mi] = *(const bf16x8*)(Al + (wm * 64 + mi * 16 + (lane & 15)) * 32 + rsl);
        #pragma unroll
        for (int mi = 0; mi < 4; ++mi)
            #pragma unroll
            for (int ni = 0; ni < 4; ++ni)
                acc[mi][ni] = __builtin_amdgcn_mfma_f32_16x16x32_bf16(al[mi], wh[ni], acc[mi][ni], 0, 0, 0);
    };

    stage(0, 0);
    for (int kt = 0; kt < 30; kt += 2) {
        stage(1, kt + 1);
        VM_WAIT8; SBAR; SCHED0;
        compute(0);
        SBAR;
        stage(0, kt + 2);
        VM_WAIT8; SBAR; SCHED0;
        compute(1);
        SBAR;
    }
    stage(1, 31);
    VM_WAIT8; SBAR; SCHED0;
    compute(0);
    SBAR;
    VM_WAIT0; SBAR; SCHED0;
    compute(1);
    SBAR;   // protect LDS reuse by V-wave transpose below

    // ---- epilogue: write f16 image tiles (+ fused block-mean for q/k)
    const int gr_first = row0 + wm * 64;          // wave's 64-row token block
    const int bb = gr_first >> 11;
    const int mblk = (gr_first & 2047) >> 6;
    const int gc0 = col0 + wn * 64;               // wave's 64-col band (one head)
    const int tsel = gc0 >> 10;
    const int h = (gc0 >> 6) & 15;
    const int tile = ((bb << 4) + h) * 32 + mblk;
    const float sc = (tsel == 0) ? SCALE_F : 1.0f;

    if (tsel != 2) {
        short* baseH = ((tsel == 0) ? QhI : KhI) + (size_t)tile * 4096;
        short* baseL = ((tsel == 0) ? QlI : KlI) + (size_t)tile * 4096;
        float* mdst  = ((tsel == 0) ? qbf : kbf) + ((size_t)((bb << 4) + h) * 32 + mblk) * 64;
        #pragma unroll
        for (int ni = 0; ni < 4; ++ni) {
            const int d = ni * 16 + (lane & 15);
            float colsum = 0.f;
            #pragma unroll
            for (int mi = 0; mi < 4; ++mi) {
                #pragma unroll
                for (int r = 0; r < 4; ++r) {
                    const int row = mi * 16 + (lane >> 4) * 4 + r;
                    float v = acc[mi][ni][r] * sc;
                    colsum += v;
                    f16 hh = (f16)v;
                    f16 ll = (f16)(v - (float)hh);
                    const int off = (row * 64 + d) ^ ((row & 7) << 3);   // shorts
                    baseH[off] = __builtin_bit_cast(short, hh);
                    baseL[off] = __builtin_bit_cast(short, ll);
                }
            }
            colsum += __shfl_xor(colsum, 16);
            colsum += __shfl_xor(colsum, 32);
            if ((lane >> 4) == 0) mdst[d] = colsum * (1.f / 64.f);
        }
    } else {
        // V: transpose 64x64 tile in per-wave LDS region, write Vt[d][kk] image
        short* tb = SM + wave * 4160;   // 64x65 shorts, per-wave exclusive
        #pragma unroll
        for (int ni = 0; ni < 4; ++ni)
            #pragma unroll
            for (int mi = 0; mi < 4; ++mi)
                #pragma unroll
                for (int r = 0; r < 4; ++r) {
                    const int row = mi * 16 + (lane >> 4) * 4 + r;   // kk
                    const int d = ni * 16 + (lane & 15);
                    f16 hv = (f16)acc[mi][ni][r];
                    tb[row * 65 + d] = __builtin_bit_cast(short, hv);
                }
        // wave-internal ds_write->ds_read ordering handled by compiler lgkmcnt
        short* vout = VtI + (size_t)tile * 4096;
        #pragma unroll
        for (int c = 0; c < 8; ++c) {
            short8v tv;
            #pragma unroll
            for (int j = 0; j < 8; ++j)
                tv[j] = tb[(c * 8 + j) * 65 + lane];
            const int off = (lane * 64 + c * 8) ^ ((lane & 7) << 3);   // shorts
            *(short8v*)(vout + off) = tv;
        }
    }
}

// Block-scores + top-2 mask only (proj_w split moved to split_in). 32 blocks.
__global__ __launch_bounds__(256) void scores_splitw_kernel(
    const float* __restrict__ qbf, const float* __restrict__ kbf,
    unsigned int* __restrict__ maskbits, float scale,
    const float* __restrict__ projw, short* __restrict__ Wdst)
{
    __shared__ float qs_[32][64];
    __shared__ float ks_[32][64];
    __shared__ float cb[32][32];
    const int bid = blockIdx.x;
    const int tid = threadIdx.x;

    if (bid >= 32) {
        int idx = (bid - 32) * 256 + tid;
        int e = idx * 4;
        int r = e >> 10, c = e & 1023;
        float4 v = *(const float4*)(projw + e);
        unsigned short h0 = bf16_hi(v.x), h1 = bf16_hi(v.y), h2 = bf16_hi(v.z), h3 = bf16_hi(v.w);
        unsigned short l0 = bf16_hi(v.x - bf16_val(h0));
        unsigned short l1 = bf16_hi(v.y - bf16_val(h1));
        unsigned short l2 = bf16_hi(v.z - bf16_val(h2));
        unsigned short l3 = bf16_hi(v.w - bf16_val(h3));
        size_t base = (size_t)r * 2048 + c;
        *(ushort4*)(Wdst + base)        = make_ushort4(h0, h1, h2, h3);
        *(ushort4*)(Wdst + base + 1024) = make_ushort4(l0, l1, l2, l3);
        return;
    }

    #pragma unroll
    for (int i = 0; i < 8; ++i) {
        int e = tid + i * 256;
        qs_[e >> 6][e & 63] = qbf[(size_t)bid * 2048 + e];
        ks_[e >> 6][e & 63] = kbf[(size_t)bid * 2048 + e];
    }
    __syncthreads();

    #pragma unroll
    for (int i = 0; i < 4; ++i) {
        int idx = tid + i * 256;
        int r = idx >> 5, c = idx & 31;
        float s = 0.f;
        #pragma unroll
        for (int d = 0; d < 64; ++d) s += qs_[r][d] * ks_[c][d];
        cb[r][c] = s * scale;
    }
    __syncthreads();

    if (tid < 32) {
        float m1 = -INFINITY, m2 = -INFINITY;
        for (int n = 0; n < 32; ++n) {
            float v = cb[tid][n];
            if (v > m1) { m2 = m1; m1 = v; }
            else if (v > m2) { m2 = v; }
        }
        unsigned int bits = 1u << tid;
        for (int n = 0; n < 32; ++n)
            if (cb[tid][n] >= m2) bits |= 1u << n;
        maskbits[bid * 32 + tid] = bits;
    }
}

// Proj GEMM via bf16x3 MFMA + bias. Counted-vmcnt 2-phase pipeline.
// R6: XCD-chunked swizzle (512 = 8 x 64).
__global__ __launch_bounds__(256) void proj_mfma_kernel(
    const short* __restrict__ A, const short* __restrict__ W,
    const float* __restrict__ bias, float* __restrict__ out)
{
    __shared__ short Ahs[2][128 * 32];
    __shared__ short Als[2][128 * 32];
    __shared__ short Whs[2][64 * 32];
    __shared__ short Wls[2][64 * 32];
    const int bid = blockIdx.x;
    const int wg = (bid & 7) * 64 + (bid >> 3);   // bijective (512 % 8 == 0)
    const int row0 = (wg >> 4) * 128;
    const int col0 = (wg & 15) * 64;
    const int tid = threadIdx.x;
    const int lane = tid & 63;
    const int wave = tid >> 6;

    f32x4 acc[2][4];
    const f32x4 zero = {0.f, 0.f, 0.f, 0.f};
    #pragma unroll
    for (int i = 0; i < 2; ++i)
        #pragma unroll
        for (int j = 0; j < 4; ++j) acc[i][j] = zero;

    const int ldr = lane >> 2;
    const int lko = (((lane & 3) ^ ((lane >> 3) & 3))) * 8;
    const int rsl = ((lane >> 4) ^ ((lane >> 1) & 3)) * 8;

    auto stage = [&](int bufi, int ktn) {
        const int kk = ktn << 5;
        #pragma unroll
        for (int i = 0; i < 2; ++i) {
            const int chunk = wave * 2 + i;
            const short* gA = A + (size_t)(row0 + chunk * 16 + ldr) * 2048 + kk + lko;
            async_copy16(gA,        (char*)&Ahs[bufi][0] + chunk * 1024);
            async_copy16(gA + 1024, (char*)&Als[bufi][0] + chunk * 1024);
        }
        {
            const short* gW = W + (size_t)(col0 + wave * 16 + ldr) * 2048 + kk + lko;
            async_copy16(gW,        (char*)&Whs[bufi][0] + wave * 1024);
            async_copy16(gW + 1024, (char*)&Wls[bufi][0] + wave * 1024);
        }
    };

    auto compute = [&](int bufi) {
        const short* Ah = Ahs[bufi];
        const short* Al = Als[bufi];
        const short* Wh = Whs[bufi];
        const short* Wl = Wls[bufi];
        bf16x8 ah[2], wh[4];
        #pragma unroll
        for (int mi = 0; mi < 2; ++mi)
            ah[mi] = *(const bf16x8*)(Ah + (wave * 32 + mi * 16 + (lane & 15)) * 32 + rsl);
        #pragma unroll
        for (int ni = 0; ni < 4; ++ni)
            wh[ni] = *(const bf16x8*)(Wh + (ni * 16 + (lane & 15)) * 32 + rsl);
        #pragma unroll
        for (int mi = 0; mi < 2; ++mi)
            #pragma unroll
            for (int ni = 0; ni < 4; ++ni)
                acc[mi][ni] = __builtin_amdgcn_mfma_f32_16x16x32_bf16(ah[mi], wh[ni], acc[mi][ni], 0, 0, 0);
        bf16x8 wl[4];
        #pragma unroll
        for (int ni = 0; ni < 4; ++ni)
            wl[ni] = *(const bf16x8*)(Wl + (ni * 16 + (lane & 15)) * 32 + rsl);
        #pragma unroll
        for (int mi = 0; mi < 2; ++mi)
            #pragma unroll
            for (int ni = 0; ni < 4; ++ni)
                acc[mi][ni] = __builtin_amdgcn_mfma_f32_16x16x32_bf16(ah[mi], wl[ni], acc[mi][ni], 0, 0, 0);
        bf16x8 al[2];
        #pragma unroll
        for (int mi = 0; mi < 2; ++mi)
            al[mi] = *(const bf16x8*)(Al + (wave * 32 + mi * 16 + (lane & 15)) * 32 + rsl);
        #pragma unroll
        for (int mi = 0; mi < 2; ++mi)
            #pragma unroll
            for (int ni = 0; ni < 4; ++ni)
                acc[mi][ni] = __builtin_amdgcn_mfma_f32_16x16x32_bf16(al[mi], wh[ni], acc[mi][ni], 0, 0, 0);
    };

    stage(0, 0);
    for (int kt = 0; kt < 30; kt += 2) {
        stage(1, kt + 1);
        VM_WAIT6; SBAR; SCHED0;
        compute(0);
        SBAR;
        stage(0, kt + 2);
        VM_WAIT6; SBAR; SCHED0;
        compute(1);
        SBAR;
    }
    stage(1, 31);
    VM_WAIT6; SBAR; SCHED0;
    compute(0);
    SBAR;
    VM_WAIT0; SBAR; SCHED0;
    compute(1);

    #pragma unroll
    for (int ni = 0; ni < 4; ++ni) {
        int gc = col0 + ni * 16 + (lane & 15);
        float bv = bias[gc];
        #pragma unroll
        for (int mi = 0; mi < 2; ++mi) {
            int gr0 = row0 + wave * 32 + mi * 16 + (lane >> 4) * 4;
            #pragma unroll
            for (int r = 0; r < 4; ++r)
                out[(size_t)(gr0 + r) * 1024 + gc] = acc[mi][ni][r] + bv;
        }
    }
}

// ---------------------------------------------------------------------------
// Sparse block attention — R5-proven image consumer, R6: XCD-chunked swizzle
// (1024 = 8 x 128; all 32 m-blocks of a bh group co-reside on one XCD's L2,
// sharing its 768 KB K/V image pool).
// ---------------------------------------------------------------------------
__global__ __launch_bounds__(256) void sparse_attn_mfma_kernel(
    const short* __restrict__ QhI, const short* __restrict__ QlI,
    const short* __restrict__ KhI, const short* __restrict__ KlI,
    const short* __restrict__ VtI, const unsigned int* __restrict__ maskbits,
    short* __restrict__ aout)
{
    __shared__ f16 Qh[4096], Ql[4096];        // [64][64] swizzled
    __shared__ f16 Kh[2][4096], Kl[2][4096];  // dbuf
    __shared__ f16 Vt[2][4096];               // dbuf, [d][kk] swizzled
    __shared__ f16 Pb[64 * LSTR];             // P[q][kk], wave-private rows

    const int bid = blockIdx.x;
    const int wg = (bid & 7) * 128 + (bid >> 3);  // bijective (1024 % 8 == 0)
    const int m  = wg & 31;
    const int bh = wg >> 5;
    const int b  = bh >> 4, h = bh & 15;
    const int tid = threadIdx.x;
    const int lane = tid & 63;
    const int wave = tid >> 6;
    const f32x4 zero = {0.f, 0.f, 0.f, 0.f};

    const unsigned int mask = maskbits[bh * 32 + m];

    // ---- stage Q (once): 4 issues/wave
    {
        const size_t qt = (size_t)(bh * 32 + m) * 4096;
        const int so = wave * 1024 + lane * 8;
        async_copy16(QhI + qt + so,       (char*)Qh + wave * 2048);
        async_copy16(QhI + qt + so + 512, (char*)Qh + wave * 2048 + 1024);
        async_copy16(QlI + qt + so,       (char*)Ql + wave * 2048);
        async_copy16(QlI + qt + so + 512, (char*)Ql + wave * 2048 + 1024);
    }

    // ---- K/V tile stage: 6 issues/wave (the vmcnt quantum)
    auto stageKV = [&](int bufi, int nb) {
        const size_t t4 = (size_t)(bh * 32 + nb) * 4096;
        const int so = wave * 1024 + lane * 8;
        async_copy16(KhI + t4 + so,       (char*)&Kh[bufi][0] + wave * 2048);
        async_copy16(KhI + t4 + so + 512, (char*)&Kh[bufi][0] + wave * 2048 + 1024);
        async_copy16(KlI + t4 + so,       (char*)&Kl[bufi][0] + wave * 2048);
        async_copy16(KlI + t4 + so + 512, (char*)&Kl[bufi][0] + wave * 2048 + 1024);
        async_copy16(VtI + t4 + so,       (char*)&Vt[bufi][0] + wave * 2048);
        async_copy16(VtI + t4 + so + 512, (char*)&Vt[bufi][0] + wave * 2048 + 1024);
    };

    f32x4 o_acc[4];
    float macc[4], lacc[4];
    #pragma unroll
    for (int r = 0; r < 4; ++r) { macc[r] = -INFINITY; lacc[r] = 0.f; }
    #pragma unroll
    for (int t = 0; t < 4; ++t) o_acc[t] = zero;

    const int arow = wave * 16 + (lane & 15);
    const int kofs = (lane >> 4) * 8;      // shorts (for Pb)
    const int colb = (lane >> 4) * 16;     // bytes (for swizzled images)

    auto computeTile = [&](int bi) {
        const f16* KhB = &Kh[bi][0];
        const f16* KlB = &Kl[bi][0];
        // ---- QK^T: f16x3 emulation (swizzled reads)
        f32x4 s_acc[4];
        #pragma unroll
        for (int t = 0; t < 4; ++t) s_acc[t] = zero;
        #pragma unroll
        for (int c = 0; c < 2; ++c) {
            const int qoff = (arow * 128 + c * 64 + colb) ^ ((arow & 7) << 4);
            f16x8 ah = *(const f16x8*)((const char*)Qh + qoff);
            f16x8 al = *(const f16x8*)((const char*)Ql + qoff);
            #pragma unroll
            for (int t = 0; t < 4; ++t) {
                const int krow = t * 16 + (lane & 15);
                const int koff = (krow * 128 + c * 64 + colb) ^ ((krow & 7) << 4);
                f16x8 bh_ = *(const f16x8*)((const char*)KhB + koff);
                f16x8 bl_ = *(const f16x8*)((const char*)KlB + koff);
                s_acc[t] = __builtin_amdgcn_mfma_f32_16x16x32_f16(ah, bh_, s_acc[t], 0, 0, 0);
                s_acc[t] = __builtin_amdgcn_mfma_f32_16x16x32_f16(ah, bl_, s_acc[t], 0, 0, 0);
                s_acc[t] = __builtin_amdgcn_mfma_f32_16x16x32_f16(al, bh_, s_acc[t], 0, 0, 0);
            }
        }

        // ---- online softmax
        float alpha[4], psum[4];
        #pragma unroll
        for (int r = 0; r < 4; ++r) {
            float v0 = fmaxf(fmaxf(s_acc[0][r], s_acc[1][r]), fmaxf(s_acc[2][r], s_acc[3][r]));
            #pragma unroll
            for (int off = 1; off < 16; off <<= 1)
                v0 = fmaxf(v0, __shfl_xor(v0, off));
            float mnew = fmaxf(macc[r], v0);
            alpha[r] = expf(macc[r] - mnew);
            macc[r] = mnew;
            psum[r] = 0.f;
        }
        #pragma unroll
        for (int t = 0; t < 4; ++t) {
            #pragma unroll
            for (int r = 0; r < 4; ++r) {
                float p = expf(s_acc[t][r] - macc[r]);
                psum[r] += p;
                Pb[(wave * 16 + (lane >> 4) * 4 + r) * LSTR + t * 16 + (lane & 15)] = (f16)p;
            }
        }
        #pragma unroll
        for (int r = 0; r < 4; ++r) {
            float v0 = psum[r];
            #pragma unroll
            for (int off = 1; off < 16; off <<= 1) v0 += __shfl_xor(v0, off);
            lacc[r] = lacc[r] * alpha[r] + v0;
            #pragma unroll
            for (int t = 0; t < 4; ++t) o_acc[t][r] *= alpha[r];
        }

        // ---- PV (Pb rows are wave-private; Vt stable until trailing barrier)
        const f16* VtB = &Vt[bi][0];
        #pragma unroll
        for (int c = 0; c < 2; ++c) {
            f16x8 af = *(const f16x8*)(Pb + arow * LSTR + c * 32 + kofs);
            #pragma unroll
            for (int t = 0; t < 4; ++t) {
                const int vrow = t * 16 + (lane & 15);
                const int voff = (vrow * 128 + c * 64 + colb) ^ ((vrow & 7) << 4);
                f16x8 bf = *(const f16x8*)((const char*)VtB + voff);
                o_acc[t] = __builtin_amdgcn_mfma_f32_16x16x32_f16(af, bf, o_acc[t], 0, 0, 0);
            }
        }
    };

    // ---- pipelined masked loop (mask always has the diagonal bit set)
    unsigned int mm = mask;
    int nb0 = __builtin_ctz(mm); mm &= mm - 1;
    stageKV(0, nb0);
    int cur = 0;
    for (;;) {
        int nb_nxt = -1;
        if (mm) { nb_nxt = __builtin_ctz(mm); mm &= mm - 1; stageKV(cur ^ 1, nb_nxt); }
        if (nb_nxt >= 0) { VM_WAIT6; } else { VM_WAIT0; }
        SBAR; SCHED0;
        computeTile(cur);
        SBAR;
        if (nb_nxt < 0) break;
        cur ^= 1;
    }

    // ---- epilogue: normalize, split bf16 hi|lo, scatter
    float inv[4];
    #pragma unroll
    for (int r = 0; r < 4; ++r) inv[r] = (lacc[r] > 0.f) ? (1.f / lacc[r]) : 0.f;
    #pragma unroll
    for (int t = 0; t < 4; ++t) {
        int gc = h * 64 + t * 16 + (lane & 15);
        #pragma unroll
        for (int r = 0; r < 4; ++r) {
            int grow = b * NN + m * 64 + wave * 16 + (lane >> 4) * 4 + r;
            float v = o_acc[t][r] * inv[r];
            unsigned short hh = bf16_hi(v);
            unsigned short ll = bf16_hi(v - bf16_val(hh));
            aout[(size_t)grow * 2048 + gc] = (short)hh;
            aout[(size_t)grow * 2048 + 1024 + gc] = (short)ll;
        }
    }
}

// ===========================================================================
// FALLBACK KERNELS (round-2 proven fp32 path)
// ===========================================================================

__global__ __launch_bounds__(256) void block_mean_kernel(
    const float* __restrict__ qf, const float* __restrict__ kf,
    float* __restrict__ qbf, float* __restrict__ kbf)
{
    int idx = blockIdx.x * 256 + threadIdx.x;
    const float* src = (idx < 65536) ? qf : kf;
    float* dst       = (idx < 65536) ? qbf : kbf;
    int e = idx & 65535;
    int d = e & 63;
    int r = e >> 6;
    size_t base = (size_t)r * 4096 + d;
    float s = 0.f;
    #pragma unroll
    for (int i = 0; i < 64; ++i) s += src[base + (size_t)i * 64];
    dst[e] = s * (1.f / 64.f);
}

__global__ __launch_bounds__(256) void qkv_gemm_fb(
    const float* __restrict__ x, const float* __restrict__ w,
    float* __restrict__ qf, float* __restrict__ kf, float* __restrict__ vf)
{
    __shared__ float As[64][33];
    __shared__ float Bs[64][33];
    const int tid = threadIdx.x;
    const int row0 = blockIdx.y * 64;
    const int col0 = blockIdx.x * 64;
    const int ty = tid >> 4, tx = tid & 15;

    float acc[4][4] = {};
    for (int k0 = 0; k0 < 1024; k0 += 32) {
        #pragma unroll
        for (int i = 0; i < 8; ++i) {
            int e = tid + i * 256;
            int r = e >> 5, c = e & 31;
            As[r][c] = x[(size_t)(row0 + r) * 1024 + k0 + c];
            Bs[r][c] = w[(size_t)(col0 + r) * 1024 + k0 + c];
        }
        __syncthreads();
        #pragma unroll
        for (int kk = 0; kk < 32; ++kk) {
            float a[4], bq[4];
            #pragma unroll
            for (int i = 0; i < 4; ++i) a[i] = As[ty * 4 + i][kk];
            #pragma unroll
            for (int j = 0; j < 4; ++j) bq[j] = Bs[tx * 4 + j][kk];
            #pragma unroll
            for (int i = 0; i < 4; ++i)
                #pragma unroll
                for (int j = 0; j < 4; ++j)
                    acc[i][j] += a[i] * bq[j];
        }
        __syncthreads();
    }

    const int tsel = col0 >> 10;
    const int h    = (col0 & 1023) >> 6;
    float* dstbuf = (tsel == 0) ? qf : (tsel == 1) ? kf : vf;
    #pragma unroll
    for (int i = 0; i < 4; ++i) {
        int row = row0 + ty * 4 + i;
        int b   = row >> 11, n = row & 2047;
        size_t rb = ((size_t)(b * HH + h) * NN + n) * HD64;
        #pragma unroll
        for (int j = 0; j < 4; ++j)
            dstbuf[rb + tx * 4 + j] = acc[i][j];
    }
}

__global__ __launch_bounds__(256) void proj_gemm_fb(
    const float* __restrict__ attn, const float* __restrict__ w,
    const float* __restrict__ bias, float* __restrict__ out)
{
    __shared__ float As[64][33];
    __shared__ float Bs[64][33];
    const int tid = threadIdx.x;
    const int row0 = blockIdx.y * 64;
    const int col0 = blockIdx.x * 64;
    const int ty = tid >> 4, tx = tid & 15;

    float acc[4][4] = {};
    for (int k0 = 0; k0 < 1024; k0 += 32) {
        #pragma unroll
        for (int i = 0; i < 8; ++i) {
            int e = tid + i * 256;
            int r = e >> 5, c = e & 31;
            As[r][c] = attn[(size_t)(row0 + r) * 1024 + k0 + c];
            Bs[r][c] = w[(size_t)(col0 + r) * 1024 + k0 + c];
        }
        __syncthreads();
        #pragma unroll
        for (int kk = 0; kk < 32; ++kk) {
            float a[4], bq[4];
            #pragma unroll
            for (int i = 0; i < 4; ++i) a[i] = As[ty * 4 + i][kk];
            #pragma unroll
            for (int j = 0; j < 4; ++j) bq[j] = Bs[tx * 4 + j][kk];
            #pragma unroll
            for (int i = 0; i < 4; ++i)
                #pragma unroll
                for (int j = 0; j < 4; ++j)
                    acc[i][j] += a[i] * bq[j];
        }
        __syncthreads();
    }

    #pragma unroll
    for (int j = 0; j < 4; ++j) {
        int col = col0 + tx * 4 + j;
        float bv = bias[col];
        #pragma unroll
        for (int i = 0; i < 4; ++i) {
            int row = row0 + ty * 4 + i;
            out[(size_t)row * 1024 + col] = acc[i][j] + bv;
        }
    }
}

__global__ __launch_bounds__(256) void sparse_attn_fb(
    const float* __restrict__ qf, const float* __restrict__ kf,
    const float* __restrict__ vf, const unsigned int* __restrict__ maskbits,
    float* __restrict__ attnf)
{
    __shared__ float kbuf[64][64];
    __shared__ float vbuf[64][64];
    __shared__ float sbuf[64][65];
    const int m  = blockIdx.x & 31;
    const int bh = blockIdx.x >> 5;
    const int b  = bh >> 4, h = bh & 15;
    const int t  = threadIdx.x;
    const int qr = t >> 2;
    const int dg = t & 3;
    const int d0 = dg * 16;

    float qreg[16];
    {
        const float* qp = qf + ((size_t)bh * NN + m * 64 + qr) * HD64 + d0;
        #pragma unroll
        for (int j = 0; j < 16; j += 4) {
            float4 v = *(const float4*)(qp + j);
            qreg[j] = v.x; qreg[j+1] = v.y; qreg[j+2] = v.z; qreg[j+3] = v.w;
        }
    }

    const unsigned int mask = maskbits[bh * 32 + m];
    float macc = -INFINITY, lacc = 0.f;
    float oacc[16];
    #pragma unroll
    for (int j = 0; j < 16; ++j) oacc[j] = 0.f;

    for (int nb = 0; nb < 32; ++nb) {
        if (!((mask >> nb) & 1u)) continue;
        __syncthreads();
        {
            const float* gk = kf + ((size_t)bh * NN + nb * 64) * HD64;
            const float* gv = vf + ((size_t)bh * NN + nb * 64) * HD64;
            #pragma unroll
            for (int i = 0; i < 4; ++i) {
                async_copy16(gk + t * 4 + i * 1024, (char*)kbuf + t * 16 + i * 4096);
                async_copy16(gv + t * 4 + i * 1024, (char*)vbuf + t * 16 + i * 4096);
            }
        }
        __syncthreads();

        float bmax = -INFINITY;
        for (int kk = 0; kk < 64; ++kk) {
            float s = 0.f;
            #pragma unroll
            for (int j = 0; j < 16; ++j) s += qreg[j] * kbuf[kk][d0 + j];
            s += __shfl_xor(s, 1);
            s += __shfl_xor(s, 2);
            s *= SCALE_F;
            if (dg == 0) sbuf[qr][kk] = s;
            bmax = fmaxf(bmax, s);
        }
        float mnew  = fmaxf(macc, bmax);
        float alpha = expf(macc - mnew);
        lacc *= alpha;
        #pragma unroll
        for (int j = 0; j < 16; ++j) oacc[j] *= alpha;
        for (int kk = 0; kk < 64; ++kk) {
            float p = expf(sbuf[qr][kk] - mnew);
            lacc += p;
            #pragma unroll
            for (int j = 0; j < 16; ++j) oacc[j] += p * vbuf[kk][d0 + j];
        }
        macc = mnew;
    }

    float inv = (lacc > 0.f) ? (1.f / lacc) : 0.f;
    size_t orow = ((size_t)(b * NN + m * 64 + qr)) * DIMD + h * 64 + d0;
    #pragma unroll
    for (int j = 0; j < 16; ++j) attnf[orow + j] = oacc[j] * inv;
}

// ---------------------------------------------------------------------------
extern "C" void kernel_launch(void* const* d_in, const int* in_sizes, int n_in,
                              void* d_out, int out_size, void* d_ws, size_t ws_size,
                              hipStream_t stream)
{
    const float* x      = (const float*)d_in[0];
    const float* qkv_w  = (const float*)d_in[1];
    const float* proj_w = (const float*)d_in[2];
    const float* proj_b = (const float*)d_in[3];
    float* out = (float*)d_out;

    // Carve (fast path, ~74 MB):
    //   Qh/Ql/Kh/Kl/Vt images: 5 x 8 MB f16 tiles
    //   qbf/kbf 512K | mask 4K
    //   Axs 16.8M (x-split; reused as attention output)
    //   Wqs 12.6M (qkv_w split) | Wp 4.2M (proj_w split)
    short* QhI = (short*)d_ws;
    short* QlI = QhI + 4194304;
    short* KhI = QlI + 4194304;
    short* KlI = KhI + 4194304;
    short* VtI = KlI + 4194304;
    float* qbf = (float*)(VtI + 4194304);
    float* kbf = qbf + 65536;
    unsigned int* maskb = (unsigned int*)(kbf + 65536);
    short* Axs = (short*)(maskb + 1024);
    short* Wqs = Axs + (size_t)4096 * 2048;
    short* Wp  = Wqs + (size_t)3072 * 2048;
    const size_t need_fast = (size_t)((char*)(Wp + (size_t)1024 * 2048) - (char*)d_ws);

    if (ws_size >= need_fast) {
        split_in_fused_kernel<<<8192, 256, 0, stream>>>(x, Axs, qkv_w, Wqs, proj_w, Wp);
        qkv_mfma_kernel<<<768, 256, 0, stream>>>(Axs, Wqs, QhI, QlI, KhI, KlI, VtI, qbf, kbf);
        scores_splitw_kernel<<<32, 256, 0, stream>>>(qbf, kbf, maskb, 1.0f,
                                                     (const float*)nullptr, (short*)nullptr);
        sparse_attn_mfma_kernel<<<1024, 256, 0, stream>>>(QhI, QlI, KhI, KlI, VtI, maskb, Axs);
        proj_mfma_kernel<<<512, 256, 0, stream>>>(Axs, Wp, proj_b, out);
    } else {
        float* qf2  = (float*)d_ws;
        float* kf2  = qf2 + 4194304;
        float* vf2  = kf2 + 4194304;
        float* qbf2 = vf2 + 4194304;
        float* kbf2 = qbf2 + 65536;
        unsigned int* maskb2 = (unsigned int*)(kbf2 + 65536);
        float* attnf = (float*)(maskb2 + 1024);
        qkv_gemm_fb<<<dim3(48, 64), 256, 0, stream>>>(x, qkv_w, qf2, kf2, vf2);
        block_mean_kernel<<<512, 256, 0, stream>>>(qf2, kf2, qbf2, kbf2);
        scores_splitw_kernel<<<32, 256, 0, stream>>>(qbf2, kbf2, maskb2, SCALE_F,
                                                     (const float*)nullptr, (short*)nullptr);
        sparse_attn_fb<<<1024, 256, 0, stream>>>(qf2, kf2, vf2, maskb2, attnf);
        proj_gemm_fb<<<dim3(16, 64), 256, 0, stream>>>(attnf, proj_w, proj_b, out);
    }
}

// Round 7
// 239.725 us; speedup vs baseline: 1.0342x; 1.0342x over previous
//
#include <hip/hip_runtime.h>
#include <hip/hip_bf16.h>

// Problem constants (B=2, N=2048, DIM=1024, H=16, HD=64, BS=64, M=32)
#define BB 2
#define NN 2048
#define DIMD 1024
#define HH 16
#define HD64 64
#define MB 32
#define SCALE_F 0.125f   // HD^-0.5

typedef __attribute__((ext_vector_type(8))) short bf16x8;
typedef __attribute__((ext_vector_type(8))) short short8v;
typedef __attribute__((ext_vector_type(4))) float f32x4;
typedef _Float16 f16;
typedef __attribute__((ext_vector_type(8))) _Float16 f16x8;

#define LSTR 72   // padded LDS row stride (f16) for Pb

// counted-vmcnt barrier discipline (T4)
#define VM_WAIT8 asm volatile("s_waitcnt vmcnt(8)" ::: "memory")
#define VM_WAIT6 asm volatile("s_waitcnt vmcnt(6)" ::: "memory")
#define VM_WAIT0 asm volatile("s_waitcnt vmcnt(0)" ::: "memory")
#define SBAR __builtin_amdgcn_s_barrier()
#define SCHED0 __builtin_amdgcn_sched_barrier(0)

__device__ __forceinline__ unsigned short bf16_hi(float f) {
    return __builtin_bit_cast(unsigned short, __float2bfloat16(f));
}
__device__ __forceinline__ float bf16_val(unsigned short u) {
    return __bfloat162float(__builtin_bit_cast(__hip_bfloat16, u));
}
__device__ __forceinline__ void async_copy16(const void* g, void* l) {
    __builtin_amdgcn_global_load_lds((const __attribute__((address_space(1))) void*)g,
                                     (__attribute__((address_space(3))) void*)l, 16, 0, 0);
}

// ===========================================================================
// FAST PATH
// ===========================================================================

// Fused input split: [0,4096) x -> Axs; [4096,7168) qkv_w -> Wqs;
// [7168,8192) proj_w -> Wp (off the qkv->attn critical path).
__global__ __launch_bounds__(256) void split_in_fused_kernel(
    const float* __restrict__ x, short* __restrict__ Axs,
    const float* __restrict__ w, short* __restrict__ Wqs,
    const float* __restrict__ pw, short* __restrict__ Wp)
{
    const int bid = blockIdx.x;
    const float* src; short* dst; int idx;
    if (bid < 4096)      { src = x;  dst = Axs; idx = bid * 256 + threadIdx.x; }
    else if (bid < 7168) { src = w;  dst = Wqs; idx = (bid - 4096) * 256 + threadIdx.x; }
    else                 { src = pw; dst = Wp;  idx = (bid - 7168) * 256 + threadIdx.x; }
    int e = idx * 4;
    int r = e >> 10, c = e & 1023;
    float4 v = *(const float4*)(src + e);
    unsigned short h0 = bf16_hi(v.x), h1 = bf16_hi(v.y), h2 = bf16_hi(v.z), h3 = bf16_hi(v.w);
    unsigned short l0 = bf16_hi(v.x - bf16_val(h0));
    unsigned short l1 = bf16_hi(v.y - bf16_val(h1));
    unsigned short l2 = bf16_hi(v.z - bf16_val(h2));
    unsigned short l3 = bf16_hi(v.w - bf16_val(h3));
    size_t base = (size_t)r * 2048 + c;
    *(ushort4*)(dst + base)        = make_ushort4(h0, h1, h2, h3);
    *(ushort4*)(dst + base + 1024) = make_ushort4(l0, l1, l2, l3);
}

// QKV GEMM via bf16x3 MFMA, counted-vmcnt 2-phase pipeline.
// R7: REVERT the XCD stripe swizzle (R6: FETCH 85->161 MB, dur 80.7->108.8).
// Identity mapping reproduces R5's x-major dispatch: consecutive blocks walk
// W columns in lockstep across XCDs -> temporal L2 dedupe (measured 85 MB).
// Epilogue writes producer-formatted f16 images (R5-proven).
__global__ __launch_bounds__(256) void qkv_mfma_kernel(
    const short* __restrict__ A, const short* __restrict__ W,
    short* __restrict__ QhI, short* __restrict__ QlI,
    short* __restrict__ KhI, short* __restrict__ KlI,
    short* __restrict__ VtI,
    float* __restrict__ qbf, float* __restrict__ kbf)
{
    __shared__ short SM[32768];   // 64 KB: 4 planes x 2 bufs x 4096 shorts
    const int wg = blockIdx.x;                    // identity (R7 revert)
    const int row0 = (wg / 24) * 128;
    const int col0 = (wg % 24) * 128;
    const int tid = threadIdx.x;
    const int lane = tid & 63;
    const int wave = tid >> 6;
    const int wm = wave & 1, wn = wave >> 1;

    auto AHS = [&](int b) { return SM + b * 4096; };
    auto ALS = [&](int b) { return SM + 8192 + b * 4096; };
    auto WHS = [&](int b) { return SM + 16384 + b * 4096; };
    auto WLS = [&](int b) { return SM + 24576 + b * 4096; };

    f32x4 acc[4][4];
    const f32x4 zero = {0.f, 0.f, 0.f, 0.f};
    #pragma unroll
    for (int i = 0; i < 4; ++i)
        #pragma unroll
        for (int j = 0; j < 4; ++j) acc[i][j] = zero;

    const int ldr = lane >> 2;                              // row in 16-row chunk
    const int lko = (((lane & 3) ^ ((lane >> 3) & 3))) * 8; // swizzled k-chunk
    const int rsl = ((lane >> 4) ^ ((lane >> 1) & 3)) * 8;  // frag-read slot

    // 8 global_load_lds per wave per call (the vmcnt quantum)
    auto stage = [&](int bufi, int ktn) {
        const int kk = ktn << 5;
        #pragma unroll
        for (int i = 0; i < 2; ++i) {
            const int chunk = wave * 2 + i;
            const short* gA = A + (size_t)(row0 + chunk * 16 + ldr) * 2048 + kk + lko;
            const short* gW = W + (size_t)(col0 + chunk * 16 + ldr) * 2048 + kk + lko;
            async_copy16(gA,        (char*)AHS(bufi) + chunk * 1024);   // A hi
            async_copy16(gA + 1024, (char*)ALS(bufi) + chunk * 1024);   // A lo
            async_copy16(gW,        (char*)WHS(bufi) + chunk * 1024);   // W hi
            async_copy16(gW + 1024, (char*)WLS(bufi) + chunk * 1024);   // W lo
        }
    };

    auto compute = [&](int bufi) {
        const short* Ah = AHS(bufi);
        const short* Al = ALS(bufi);
        const short* Wh = WHS(bufi);
        const short* Wl = WLS(bufi);
        // cluster 1: Ah x Wh
        bf16x8 ah[4], wh[4];
        #pragma unroll
        for (int mi = 0; mi < 4; ++mi)
            ah[mi] = *(const bf16x8*)(Ah + (wm * 64 + mi * 16 + (lane & 15)) * 32 + rsl);
        #pragma unroll
        for (int ni = 0; ni < 4; ++ni)
            wh[ni] = *(const bf16x8*)(Wh + (wn * 64 + ni * 16 + (lane & 15)) * 32 + rsl);
        #pragma unroll
        for (int mi = 0; mi < 4; ++mi)
            #pragma unroll
            for (int ni = 0; ni < 4; ++ni)
                acc[mi][ni] = __builtin_amdgcn_mfma_f32_16x16x32_bf16(ah[mi], wh[ni], acc[mi][ni], 0, 0, 0);
        // cluster 2: Ah x Wl
        bf16x8 wl[4];
        #pragma unroll
        for (int ni = 0; ni < 4; ++ni)
            wl[ni] = *(const bf16x8*)(Wl + (wn * 64 + ni * 16 + (lane & 15)) * 32 + rsl);
        #pragma unroll
        for (int mi = 0; mi < 4; ++mi)
            #pragma unroll
            for (int ni = 0; ni < 4; ++ni)
                acc[mi][ni] = __builtin_amdgcn_mfma_f32_16x16x32_bf16(ah[mi], wl[ni], acc[mi][ni], 0, 0, 0);
        // cluster 3: Al x Wh
        bf16x8 al[4];
        #pragma unroll
        for (int mi = 0; mi < 4; ++mi)
            al[mi] = *(const bf16x8*)(Al + (wm * 64 + mi * 16 + (lane & 15)) * 32 + rsl);
        #pragma unroll
        for (int mi = 0; mi < 4; ++mi)
            #pragma unroll
            for (int ni = 0; ni < 4; ++ni)
                acc[mi][ni] = __builtin_amdgcn_mfma_f32_16x16x32_bf16(al[mi], wh[ni], acc[mi][ni], 0, 0, 0);
    };

    stage(0, 0);
    for (int kt = 0; kt < 30; kt += 2) {
        stage(1, kt + 1);
        VM_WAIT8; SBAR; SCHED0;
        compute(0);
        SBAR;
        stage(0, kt + 2);
        VM_WAIT8; SBAR; SCHED0;
        compute(1);
        SBAR;
    }
    stage(1, 31);
    VM_WAIT8; SBAR; SCHED0;
    compute(0);
    SBAR;
    VM_WAIT0; SBAR; SCHED0;
    compute(1);
    SBAR;   // protect LDS reuse by V-wave transpose below

    // ---- epilogue: write f16 image tiles (+ fused block-mean for q/k)
    const int gr_first = row0 + wm * 64;          // wave's 64-row token block
    const int bb = gr_first >> 11;
    const int mblk = (gr_first & 2047) >> 6;
    const int gc0 = col0 + wn * 64;               // wave's 64-col band (one head)
    const int tsel = gc0 >> 10;
    const int h = (gc0 >> 6) & 15;
    const int tile = ((bb << 4) + h) * 32 + mblk;
    const float sc = (tsel == 0) ? SCALE_F : 1.0f;

    if (tsel != 2) {
        short* baseH = ((tsel == 0) ? QhI : KhI) + (size_t)tile * 4096;
        short* baseL = ((tsel == 0) ? QlI : KlI) + (size_t)tile * 4096;
        float* mdst  = ((tsel == 0) ? qbf : kbf) + ((size_t)((bb << 4) + h) * 32 + mblk) * 64;
        #pragma unroll
        for (int ni = 0; ni < 4; ++ni) {
            const int d = ni * 16 + (lane & 15);
            float colsum = 0.f;
            #pragma unroll
            for (int mi = 0; mi < 4; ++mi) {
                #pragma unroll
                for (int r = 0; r < 4; ++r) {
                    const int row = mi * 16 + (lane >> 4) * 4 + r;
                    float v = acc[mi][ni][r] * sc;
                    colsum += v;
                    f16 hh = (f16)v;
                    f16 ll = (f16)(v - (float)hh);
                    const int off = (row * 64 + d) ^ ((row & 7) << 3);   // shorts
                    baseH[off] = __builtin_bit_cast(short, hh);
                    baseL[off] = __builtin_bit_cast(short, ll);
                }
            }
            colsum += __shfl_xor(colsum, 16);
            colsum += __shfl_xor(colsum, 32);
            if ((lane >> 4) == 0) mdst[d] = colsum * (1.f / 64.f);
        }
    } else {
        // V: transpose 64x64 tile in per-wave LDS region, write Vt[d][kk] image
        short* tb = SM + wave * 4160;   // 64x65 shorts, per-wave exclusive
        #pragma unroll
        for (int ni = 0; ni < 4; ++ni)
            #pragma unroll
            for (int mi = 0; mi < 4; ++mi)
                #pragma unroll
                for (int r = 0; r < 4; ++r) {
                    const int row = mi * 16 + (lane >> 4) * 4 + r;   // kk
                    const int d = ni * 16 + (lane & 15);
                    f16 hv = (f16)acc[mi][ni][r];
                    tb[row * 65 + d] = __builtin_bit_cast(short, hv);
                }
        // wave-internal ds_write->ds_read ordering handled by compiler lgkmcnt
        short* vout = VtI + (size_t)tile * 4096;
        #pragma unroll
        for (int c = 0; c < 8; ++c) {
            short8v tv;
            #pragma unroll
            for (int j = 0; j < 8; ++j)
                tv[j] = tb[(c * 8 + j) * 65 + lane];
            const int off = (lane * 64 + c * 8) ^ ((lane & 7) << 3);   // shorts
            *(short8v*)(vout + off) = tv;
        }
    }
}

// Block-scores + top-2 mask only. 32 blocks.
__global__ __launch_bounds__(256) void scores_splitw_kernel(
    const float* __restrict__ qbf, const float* __restrict__ kbf,
    unsigned int* __restrict__ maskbits, float scale,
    const float* __restrict__ projw, short* __restrict__ Wdst)
{
    __shared__ float qs_[32][64];
    __shared__ float ks_[32][64];
    __shared__ float cb[32][32];
    const int bid = blockIdx.x;
    const int tid = threadIdx.x;

    if (bid >= 32) {
        int idx = (bid - 32) * 256 + tid;
        int e = idx * 4;
        int r = e >> 10, c = e & 1023;
        float4 v = *(const float4*)(projw + e);
        unsigned short h0 = bf16_hi(v.x), h1 = bf16_hi(v.y), h2 = bf16_hi(v.z), h3 = bf16_hi(v.w);
        unsigned short l0 = bf16_hi(v.x - bf16_val(h0));
        unsigned short l1 = bf16_hi(v.y - bf16_val(h1));
        unsigned short l2 = bf16_hi(v.z - bf16_val(h2));
        unsigned short l3 = bf16_hi(v.w - bf16_val(h3));
        size_t base = (size_t)r * 2048 + c;
        *(ushort4*)(Wdst + base)        = make_ushort4(h0, h1, h2, h3);
        *(ushort4*)(Wdst + base + 1024) = make_ushort4(l0, l1, l2, l3);
        return;
    }

    #pragma unroll
    for (int i = 0; i < 8; ++i) {
        int e = tid + i * 256;
        qs_[e >> 6][e & 63] = qbf[(size_t)bid * 2048 + e];
        ks_[e >> 6][e & 63] = kbf[(size_t)bid * 2048 + e];
    }
    __syncthreads();

    #pragma unroll
    for (int i = 0; i < 4; ++i) {
        int idx = tid + i * 256;
        int r = idx >> 5, c = idx & 31;
        float s = 0.f;
        #pragma unroll
        for (int d = 0; d < 64; ++d) s += qs_[r][d] * ks_[c][d];
        cb[r][c] = s * scale;
    }
    __syncthreads();

    if (tid < 32) {
        float m1 = -INFINITY, m2 = -INFINITY;
        for (int n = 0; n < 32; ++n) {
            float v = cb[tid][n];
            if (v > m1) { m2 = m1; m1 = v; }
            else if (v > m2) { m2 = v; }
        }
        unsigned int bits = 1u << tid;
        for (int n = 0; n < 32; ++n)
            if (cb[tid][n] >= m2) bits |= 1u << n;
        maskbits[bid * 32 + tid] = bits;
    }
}

// Proj GEMM via bf16x3 MFMA + bias. Counted-vmcnt 2-phase pipeline.
// XCD-chunked swizzle kept (Wp 4.2 MB ~ fits one XCD L2; R6 non-qkv win).
__global__ __launch_bounds__(256) void proj_mfma_kernel(
    const short* __restrict__ A, const short* __restrict__ W,
    const float* __restrict__ bias, float* __restrict__ out)
{
    __shared__ short Ahs[2][128 * 32];
    __shared__ short Als[2][128 * 32];
    __shared__ short Whs[2][64 * 32];
    __shared__ short Wls[2][64 * 32];
    const int bid = blockIdx.x;
    const int wg = (bid & 7) * 64 + (bid >> 3);   // bijective (512 % 8 == 0)
    const int row0 = (wg >> 4) * 128;
    const int col0 = (wg & 15) * 64;
    const int tid = threadIdx.x;
    const int lane = tid & 63;
    const int wave = tid >> 6;

    f32x4 acc[2][4];
    const f32x4 zero = {0.f, 0.f, 0.f, 0.f};
    #pragma unroll
    for (int i = 0; i < 2; ++i)
        #pragma unroll
        for (int j = 0; j < 4; ++j) acc[i][j] = zero;

    const int ldr = lane >> 2;
    const int lko = (((lane & 3) ^ ((lane >> 3) & 3))) * 8;
    const int rsl = ((lane >> 4) ^ ((lane >> 1) & 3)) * 8;

    auto stage = [&](int bufi, int ktn) {
        const int kk = ktn << 5;
        #pragma unroll
        for (int i = 0; i < 2; ++i) {
            const int chunk = wave * 2 + i;
            const short* gA = A + (size_t)(row0 + chunk * 16 + ldr) * 2048 + kk + lko;
            async_copy16(gA,        (char*)&Ahs[bufi][0] + chunk * 1024);
            async_copy16(gA + 1024, (char*)&Als[bufi][0] + chunk * 1024);
        }
        {
            const short* gW = W + (size_t)(col0 + wave * 16 + ldr) * 2048 + kk + lko;
            async_copy16(gW,        (char*)&Whs[bufi][0] + wave * 1024);
            async_copy16(gW + 1024, (char*)&Wls[bufi][0] + wave * 1024);
        }
    };

    auto compute = [&](int bufi) {
        const short* Ah = Ahs[bufi];
        const short* Al = Als[bufi];
        const short* Wh = Whs[bufi];
        const short* Wl = Wls[bufi];
        bf16x8 ah[2], wh[4];
        #pragma unroll
        for (int mi = 0; mi < 2; ++mi)
            ah[mi] = *(const bf16x8*)(Ah + (wave * 32 + mi * 16 + (lane & 15)) * 32 + rsl);
        #pragma unroll
        for (int ni = 0; ni < 4; ++ni)
            wh[ni] = *(const bf16x8*)(Wh + (ni * 16 + (lane & 15)) * 32 + rsl);
        #pragma unroll
        for (int mi = 0; mi < 2; ++mi)
            #pragma unroll
            for (int ni = 0; ni < 4; ++ni)
                acc[mi][ni] = __builtin_amdgcn_mfma_f32_16x16x32_bf16(ah[mi], wh[ni], acc[mi][ni], 0, 0, 0);
        bf16x8 wl[4];
        #pragma unroll
        for (int ni = 0; ni < 4; ++ni)
            wl[ni] = *(const bf16x8*)(Wl + (ni * 16 + (lane & 15)) * 32 + rsl);
        #pragma unroll
        for (int mi = 0; mi < 2; ++mi)
            #pragma unroll
            for (int ni = 0; ni < 4; ++ni)
                acc[mi][ni] = __builtin_amdgcn_mfma_f32_16x16x32_bf16(ah[mi], wl[ni], acc[mi][ni], 0, 0, 0);
        bf16x8 al[2];
        #pragma unroll
        for (int mi = 0; mi < 2; ++mi)
            al[mi] = *(const bf16x8*)(Al + (wave * 32 + mi * 16 + (lane & 15)) * 32 + rsl);
        #pragma unroll
        for (int mi = 0; mi < 2; ++mi)
            #pragma unroll
            for (int ni = 0; ni < 4; ++ni)
                acc[mi][ni] = __builtin_amdgcn_mfma_f32_16x16x32_bf16(al[mi], wh[ni], acc[mi][ni], 0, 0, 0);
    };

    stage(0, 0);
    for (int kt = 0; kt < 30; kt += 2) {
        stage(1, kt + 1);
        VM_WAIT6; SBAR; SCHED0;
        compute(0);
        SBAR;
        stage(0, kt + 2);
        VM_WAIT6; SBAR; SCHED0;
        compute(1);
        SBAR;
    }
    stage(1, 31);
    VM_WAIT6; SBAR; SCHED0;
    compute(0);
    SBAR;
    VM_WAIT0; SBAR; SCHED0;
    compute(1);

    #pragma unroll
    for (int ni = 0; ni < 4; ++ni) {
        int gc = col0 + ni * 16 + (lane & 15);
        float bv = bias[gc];
        #pragma unroll
        for (int mi = 0; mi < 2; ++mi) {
            int gr0 = row0 + wave * 32 + mi * 16 + (lane >> 4) * 4;
            #pragma unroll
            for (int r = 0; r < 4; ++r)
                out[(size_t)(gr0 + r) * 1024 + gc] = acc[mi][ni][r] + bv;
        }
    }
}

// ---------------------------------------------------------------------------
// Sparse block attention — image consumer; XCD-chunked swizzle kept
// (per-bh K/V image pool = 768 KB, fits one XCD L2; R6 non-qkv win).
// ---------------------------------------------------------------------------
__global__ __launch_bounds__(256) void sparse_attn_mfma_kernel(
    const short* __restrict__ QhI, const short* __restrict__ QlI,
    const short* __restrict__ KhI, const short* __restrict__ KlI,
    const short* __restrict__ VtI, const unsigned int* __restrict__ maskbits,
    short* __restrict__ aout)
{
    __shared__ f16 Qh[4096], Ql[4096];        // [64][64] swizzled
    __shared__ f16 Kh[2][4096], Kl[2][4096];  // dbuf
    __shared__ f16 Vt[2][4096];               // dbuf, [d][kk] swizzled
    __shared__ f16 Pb[64 * LSTR];             // P[q][kk], wave-private rows

    const int bid = blockIdx.x;
    const int wg = (bid & 7) * 128 + (bid >> 3);  // bijective (1024 % 8 == 0)
    const int m  = wg & 31;
    const int bh = wg >> 5;
    const int b  = bh >> 4, h = bh & 15;
    const int tid = threadIdx.x;
    const int lane = tid & 63;
    const int wave = tid >> 6;
    const f32x4 zero = {0.f, 0.f, 0.f, 0.f};

    const unsigned int mask = maskbits[bh * 32 + m];

    // ---- stage Q (once): 4 issues/wave
    {
        const size_t qt = (size_t)(bh * 32 + m) * 4096;
        const int so = wave * 1024 + lane * 8;
        async_copy16(QhI + qt + so,       (char*)Qh + wave * 2048);
        async_copy16(QhI + qt + so + 512, (char*)Qh + wave * 2048 + 1024);
        async_copy16(QlI + qt + so,       (char*)Ql + wave * 2048);
        async_copy16(QlI + qt + so + 512, (char*)Ql + wave * 2048 + 1024);
    }

    // ---- K/V tile stage: 6 issues/wave (the vmcnt quantum)
    auto stageKV = [&](int bufi, int nb) {
        const size_t t4 = (size_t)(bh * 32 + nb) * 4096;
        const int so = wave * 1024 + lane * 8;
        async_copy16(KhI + t4 + so,       (char*)&Kh[bufi][0] + wave * 2048);
        async_copy16(KhI + t4 + so + 512, (char*)&Kh[bufi][0] + wave * 2048 + 1024);
        async_copy16(KlI + t4 + so,       (char*)&Kl[bufi][0] + wave * 2048);
        async_copy16(KlI + t4 + so + 512, (char*)&Kl[bufi][0] + wave * 2048 + 1024);
        async_copy16(VtI + t4 + so,       (char*)&Vt[bufi][0] + wave * 2048);
        async_copy16(VtI + t4 + so + 512, (char*)&Vt[bufi][0] + wave * 2048 + 1024);
    };

    f32x4 o_acc[4];
    float macc[4], lacc[4];
    #pragma unroll
    for (int r = 0; r < 4; ++r) { macc[r] = -INFINITY; lacc[r] = 0.f; }
    #pragma unroll
    for (int t = 0; t < 4; ++t) o_acc[t] = zero;

    const int arow = wave * 16 + (lane & 15);
    const int kofs = (lane >> 4) * 8;      // shorts (for Pb)
    const int colb = (lane >> 4) * 16;     // bytes (for swizzled images)

    auto computeTile = [&](int bi) {
        const f16* KhB = &Kh[bi][0];
        const f16* KlB = &Kl[bi][0];
        // ---- QK^T: f16x3 emulation (swizzled reads)
        f32x4 s_acc[4];
        #pragma unroll
        for (int t = 0; t < 4; ++t) s_acc[t] = zero;
        #pragma unroll
        for (int c = 0; c < 2; ++c) {
            const int qoff = (arow * 128 + c * 64 + colb) ^ ((arow & 7) << 4);
            f16x8 ah = *(const f16x8*)((const char*)Qh + qoff);
            f16x8 al = *(const f16x8*)((const char*)Ql + qoff);
            #pragma unroll
            for (int t = 0; t < 4; ++t) {
                const int krow = t * 16 + (lane & 15);
                const int koff = (krow * 128 + c * 64 + colb) ^ ((krow & 7) << 4);
                f16x8 bh_ = *(const f16x8*)((const char*)KhB + koff);
                f16x8 bl_ = *(const f16x8*)((const char*)KlB + koff);
                s_acc[t] = __builtin_amdgcn_mfma_f32_16x16x32_f16(ah, bh_, s_acc[t], 0, 0, 0);
                s_acc[t] = __builtin_amdgcn_mfma_f32_16x16x32_f16(ah, bl_, s_acc[t], 0, 0, 0);
                s_acc[t] = __builtin_amdgcn_mfma_f32_16x16x32_f16(al, bh_, s_acc[t], 0, 0, 0);
            }
        }

        // ---- online softmax
        float alpha[4], psum[4];
        #pragma unroll
        for (int r = 0; r < 4; ++r) {
            float v0 = fmaxf(fmaxf(s_acc[0][r], s_acc[1][r]), fmaxf(s_acc[2][r], s_acc[3][r]));
            #pragma unroll
            for (int off = 1; off < 16; off <<= 1)
                v0 = fmaxf(v0, __shfl_xor(v0, off));
            float mnew = fmaxf(macc[r], v0);
            alpha[r] = expf(macc[r] - mnew);
            macc[r] = mnew;
            psum[r] = 0.f;
        }
        #pragma unroll
        for (int t = 0; t < 4; ++t) {
            #pragma unroll
            for (int r = 0; r < 4; ++r) {
                float p = expf(s_acc[t][r] - macc[r]);
                psum[r] += p;
                Pb[(wave * 16 + (lane >> 4) * 4 + r) * LSTR + t * 16 + (lane & 15)] = (f16)p;
            }
        }
        #pragma unroll
        for (int r = 0; r < 4; ++r) {
            float v0 = psum[r];
            #pragma unroll
            for (int off = 1; off < 16; off <<= 1) v0 += __shfl_xor(v0, off);
            lacc[r] = lacc[r] * alpha[r] + v0;
            #pragma unroll
            for (int t = 0; t < 4; ++t) o_acc[t][r] *= alpha[r];
        }

        // ---- PV (Pb rows are wave-private; Vt stable until trailing barrier)
        const f16* VtB = &Vt[bi][0];
        #pragma unroll
        for (int c = 0; c < 2; ++c) {
            f16x8 af = *(const f16x8*)(Pb + arow * LSTR + c * 32 + kofs);
            #pragma unroll
            for (int t = 0; t < 4; ++t) {
                const int vrow = t * 16 + (lane & 15);
                const int voff = (vrow * 128 + c * 64 + colb) ^ ((vrow & 7) << 4);
                f16x8 bf = *(const f16x8*)((const char*)VtB + voff);
                o_acc[t] = __builtin_amdgcn_mfma_f32_16x16x32_f16(af, bf, o_acc[t], 0, 0, 0);
            }
        }
    };

    // ---- pipelined masked loop (mask always has the diagonal bit set)
    unsigned int mm = mask;
    int nb0 = __builtin_ctz(mm); mm &= mm - 1;
    stageKV(0, nb0);
    int cur = 0;
    for (;;) {
        int nb_nxt = -1;
        if (mm) { nb_nxt = __builtin_ctz(mm); mm &= mm - 1; stageKV(cur ^ 1, nb_nxt); }
        if (nb_nxt >= 0) { VM_WAIT6; } else { VM_WAIT0; }
        SBAR; SCHED0;
        computeTile(cur);
        SBAR;
        if (nb_nxt < 0) break;
        cur ^= 1;
    }

    // ---- epilogue: normalize, split bf16 hi|lo, scatter
    float inv[4];
    #pragma unroll
    for (int r = 0; r < 4; ++r) inv[r] = (lacc[r] > 0.f) ? (1.f / lacc[r]) : 0.f;
    #pragma unroll
    for (int t = 0; t < 4; ++t) {
        int gc = h * 64 + t * 16 + (lane & 15);
        #pragma unroll
        for (int r = 0; r < 4; ++r) {
            int grow = b * NN + m * 64 + wave * 16 + (lane >> 4) * 4 + r;
            float v = o_acc[t][r] * inv[r];
            unsigned short hh = bf16_hi(v);
            unsigned short ll = bf16_hi(v - bf16_val(hh));
            aout[(size_t)grow * 2048 + gc] = (short)hh;
            aout[(size_t)grow * 2048 + 1024 + gc] = (short)ll;
        }
    }
}

// ===========================================================================
// FALLBACK KERNELS (round-2 proven fp32 path)
// ===========================================================================

__global__ __launch_bounds__(256) void block_mean_kernel(
    const float* __restrict__ qf, const float* __restrict__ kf,
    float* __restrict__ qbf, float* __restrict__ kbf)
{
    int idx = blockIdx.x * 256 + threadIdx.x;
    const float* src = (idx < 65536) ? qf : kf;
    float* dst       = (idx < 65536) ? qbf : kbf;
    int e = idx & 65535;
    int d = e & 63;
    int r = e >> 6;
    size_t base = (size_t)r * 4096 + d;
    float s = 0.f;
    #pragma unroll
    for (int i = 0; i < 64; ++i) s += src[base + (size_t)i * 64];
    dst[e] = s * (1.f / 64.f);
}

__global__ __launch_bounds__(256) void qkv_gemm_fb(
    const float* __restrict__ x, const float* __restrict__ w,
    float* __restrict__ qf, float* __restrict__ kf, float* __restrict__ vf)
{
    __shared__ float As[64][33];
    __shared__ float Bs[64][33];
    const int tid = threadIdx.x;
    const int row0 = blockIdx.y * 64;
    const int col0 = blockIdx.x * 64;
    const int ty = tid >> 4, tx = tid & 15;

    float acc[4][4] = {};
    for (int k0 = 0; k0 < 1024; k0 += 32) {
        #pragma unroll
        for (int i = 0; i < 8; ++i) {
            int e = tid + i * 256;
            int r = e >> 5, c = e & 31;
            As[r][c] = x[(size_t)(row0 + r) * 1024 + k0 + c];
            Bs[r][c] = w[(size_t)(col0 + r) * 1024 + k0 + c];
        }
        __syncthreads();
        #pragma unroll
        for (int kk = 0; kk < 32; ++kk) {
            float a[4], bq[4];
            #pragma unroll
            for (int i = 0; i < 4; ++i) a[i] = As[ty * 4 + i][kk];
            #pragma unroll
            for (int j = 0; j < 4; ++j) bq[j] = Bs[tx * 4 + j][kk];
            #pragma unroll
            for (int i = 0; i < 4; ++i)
                #pragma unroll
                for (int j = 0; j < 4; ++j)
                    acc[i][j] += a[i] * bq[j];
        }
        __syncthreads();
    }

    const int tsel = col0 >> 10;
    const int h    = (col0 & 1023) >> 6;
    float* dstbuf = (tsel == 0) ? qf : (tsel == 1) ? kf : vf;
    #pragma unroll
    for (int i = 0; i < 4; ++i) {
        int row = row0 + ty * 4 + i;
        int b   = row >> 11, n = row & 2047;
        size_t rb = ((size_t)(b * HH + h) * NN + n) * HD64;
        #pragma unroll
        for (int j = 0; j < 4; ++j)
            dstbuf[rb + tx * 4 + j] = acc[i][j];
    }
}

__global__ __launch_bounds__(256) void proj_gemm_fb(
    const float* __restrict__ attn, const float* __restrict__ w,
    const float* __restrict__ bias, float* __restrict__ out)
{
    __shared__ float As[64][33];
    __shared__ float Bs[64][33];
    const int tid = threadIdx.x;
    const int row0 = blockIdx.y * 64;
    const int col0 = blockIdx.x * 64;
    const int ty = tid >> 4, tx = tid & 15;

    float acc[4][4] = {};
    for (int k0 = 0; k0 < 1024; k0 += 32) {
        #pragma unroll
        for (int i = 0; i < 8; ++i) {
            int e = tid + i * 256;
            int r = e >> 5, c = e & 31;
            As[r][c] = attn[(size_t)(row0 + r) * 1024 + k0 + c];
            Bs[r][c] = w[(size_t)(col0 + r) * 1024 + k0 + c];
        }
        __syncthreads();
        #pragma unroll
        for (int kk = 0; kk < 32; ++kk) {
            float a[4], bq[4];
            #pragma unroll
            for (int i = 0; i < 4; ++i) a[i] = As[ty * 4 + i][kk];
            #pragma unroll
            for (int j = 0; j < 4; ++j) bq[j] = Bs[tx * 4 + j][kk];
            #pragma unroll
            for (int i = 0; i < 4; ++i)
                #pragma unroll
                for (int j = 0; j < 4; ++j)
                    acc[i][j] += a[i] * bq[j];
        }
        __syncthreads();
    }

    #pragma unroll
    for (int j = 0; j < 4; ++j) {
        int col = col0 + tx * 4 + j;
        float bv = bias[col];
        #pragma unroll
        for (int i = 0; i < 4; ++i) {
            int row = row0 + ty * 4 + i;
            out[(size_t)row * 1024 + col] = acc[i][j] + bv;
        }
    }
}

__global__ __launch_bounds__(256) void sparse_attn_fb(
    const float* __restrict__ qf, const float* __restrict__ kf,
    const float* __restrict__ vf, const unsigned int* __restrict__ maskbits,
    float* __restrict__ attnf)
{
    __shared__ float kbuf[64][64];
    __shared__ float vbuf[64][64];
    __shared__ float sbuf[64][65];
    const int m  = blockIdx.x & 31;
    const int bh = blockIdx.x >> 5;
    const int b  = bh >> 4, h = bh & 15;
    const int t  = threadIdx.x;
    const int qr = t >> 2;
    const int dg = t & 3;
    const int d0 = dg * 16;

    float qreg[16];
    {
        const float* qp = qf + ((size_t)bh * NN + m * 64 + qr) * HD64 + d0;
        #pragma unroll
        for (int j = 0; j < 16; j += 4) {
            float4 v = *(const float4*)(qp + j);
            qreg[j] = v.x; qreg[j+1] = v.y; qreg[j+2] = v.z; qreg[j+3] = v.w;
        }
    }

    const unsigned int mask = maskbits[bh * 32 + m];
    float macc = -INFINITY, lacc = 0.f;
    float oacc[16];
    #pragma unroll
    for (int j = 0; j < 16; ++j) oacc[j] = 0.f;

    for (int nb = 0; nb < 32; ++nb) {
        if (!((mask >> nb) & 1u)) continue;
        __syncthreads();
        {
            const float* gk = kf + ((size_t)bh * NN + nb * 64) * HD64;
            const float* gv = vf + ((size_t)bh * NN + nb * 64) * HD64;
            #pragma unroll
            for (int i = 0; i < 4; ++i) {
                async_copy16(gk + t * 4 + i * 1024, (char*)kbuf + t * 16 + i * 4096);
                async_copy16(gv + t * 4 + i * 1024, (char*)vbuf + t * 16 + i * 4096);
            }
        }
        __syncthreads();

        float bmax = -INFINITY;
        for (int kk = 0; kk < 64; ++kk) {
            float s = 0.f;
            #pragma unroll
            for (int j = 0; j < 16; ++j) s += qreg[j] * kbuf[kk][d0 + j];
            s += __shfl_xor(s, 1);
            s += __shfl_xor(s, 2);
            s *= SCALE_F;
            if (dg == 0) sbuf[qr][kk] = s;
            bmax = fmaxf(bmax, s);
        }
        float mnew  = fmaxf(macc, bmax);
        float alpha = expf(macc - mnew);
        lacc *= alpha;
        #pragma unroll
        for (int j = 0; j < 16; ++j) oacc[j] *= alpha;
        for (int kk = 0; kk < 64; ++kk) {
            float p = expf(sbuf[qr][kk] - mnew);
            lacc += p;
            #pragma unroll
            for (int j = 0; j < 16; ++j) oacc[j] += p * vbuf[kk][d0 + j];
        }
        macc = mnew;
    }

    float inv = (lacc > 0.f) ? (1.f / lacc) : 0.f;
    size_t orow = ((size_t)(b * NN + m * 64 + qr)) * DIMD + h * 64 + d0;
    #pragma unroll
    for (int j = 0; j < 16; ++j) attnf[orow + j] = oacc[j] * inv;
}

// ---------------------------------------------------------------------------
extern "C" void kernel_launch(void* const* d_in, const int* in_sizes, int n_in,
                              void* d_out, int out_size, void* d_ws, size_t ws_size,
                              hipStream_t stream)
{
    const float* x      = (const float*)d_in[0];
    const float* qkv_w  = (const float*)d_in[1];
    const float* proj_w = (const float*)d_in[2];
    const float* proj_b = (const float*)d_in[3];
    float* out = (float*)d_out;

    // Carve (fast path, ~74 MB):
    //   Qh/Ql/Kh/Kl/Vt images: 5 x 8 MB f16 tiles
    //   qbf/kbf 512K | mask 4K
    //   Axs 16.8M (x-split; reused as attention output)
    //   Wqs 12.6M (qkv_w split) | Wp 4.2M (proj_w split)
    short* QhI = (short*)d_ws;
    short* QlI = QhI + 4194304;
    short* KhI = QlI + 4194304;
    short* KlI = KhI + 4194304;
    short* VtI = KlI + 4194304;
    float* qbf = (float*)(VtI + 4194304);
    float* kbf = qbf + 65536;
    unsigned int* maskb = (unsigned int*)(kbf + 65536);
    short* Axs = (short*)(maskb + 1024);
    short* Wqs = Axs + (size_t)4096 * 2048;
    short* Wp  = Wqs + (size_t)3072 * 2048;
    const size_t need_fast = (size_t)((char*)(Wp + (size_t)1024 * 2048) - (char*)d_ws);

    if (ws_size >= need_fast) {
        split_in_fused_kernel<<<8192, 256, 0, stream>>>(x, Axs, qkv_w, Wqs, proj_w, Wp);
        qkv_mfma_kernel<<<768, 256, 0, stream>>>(Axs, Wqs, QhI, QlI, KhI, KlI, VtI, qbf, kbf);
        scores_splitw_kernel<<<32, 256, 0, stream>>>(qbf, kbf, maskb, 1.0f,
                                                     (const float*)nullptr, (short*)nullptr);
        sparse_attn_mfma_kernel<<<1024, 256, 0, stream>>>(QhI, QlI, KhI, KlI, VtI, maskb, Axs);
        proj_mfma_kernel<<<512, 256, 0, stream>>>(Axs, Wp, proj_b, out);
    } else {
        float* qf2  = (float*)d_ws;
        float* kf2  = qf2 + 4194304;
        float* vf2  = kf2 + 4194304;
        float* qbf2 = vf2 + 4194304;
        float* kbf2 = qbf2 + 65536;
        unsigned int* maskb2 = (unsigned int*)(kbf2 + 65536);
        float* attnf = (float*)(maskb2 + 1024);
        qkv_gemm_fb<<<dim3(48, 64), 256, 0, stream>>>(x, qkv_w, qf2, kf2, vf2);
        block_mean_kernel<<<512, 256, 0, stream>>>(qf2, kf2, qbf2, kbf2);
        scores_splitw_kernel<<<32, 256, 0, stream>>>(qbf2, kbf2, maskb2, SCALE_F,
                                                     (const float*)nullptr, (short*)nullptr);
        sparse_attn_fb<<<1024, 256, 0, stream>>>(qf2, kf2, vf2, maskb2, attnf);
        proj_gemm_fb<<<dim3(16, 64), 256, 0, stream>>>(attnf, proj_w, proj_b, out);
    }
}

// Round 8
// 183.894 us; speedup vs baseline: 1.3481x; 1.3036x over previous
//
#include <hip/hip_runtime.h>
#include <hip/hip_bf16.h>

// Problem constants (B=2, N=2048, DIM=1024, H=16, HD=64, BS=64, M=32)
#define BB 2
#define NN 2048
#define DIMD 1024
#define HH 16
#define HD64 64
#define MB 32
#define SCALE_F 0.125f   // HD^-0.5

typedef __attribute__((ext_vector_type(8))) short bf16x8;
typedef __attribute__((ext_vector_type(8))) short short8v;
typedef __attribute__((ext_vector_type(4))) float f32x4;
typedef _Float16 f16;
typedef __attribute__((ext_vector_type(8))) _Float16 f16x8;

#define LSTR 72   // padded LDS row stride (f16) for Pb

// counted-vmcnt barrier discipline (T4)
#define VM_WAIT4 asm volatile("s_waitcnt vmcnt(4)" ::: "memory")
#define VM_WAIT3 asm volatile("s_waitcnt vmcnt(3)" ::: "memory")
#define VM_WAIT0 asm volatile("s_waitcnt vmcnt(0)" ::: "memory")
#define SBAR __builtin_amdgcn_s_barrier()
#define SCHED0 __builtin_amdgcn_sched_barrier(0)

__device__ __forceinline__ unsigned short bf16_hi(float f) {
    return __builtin_bit_cast(unsigned short, __float2bfloat16(f));
}
__device__ __forceinline__ float bf16_val(unsigned short u) {
    return __bfloat162float(__builtin_bit_cast(__hip_bfloat16, u));
}
__device__ __forceinline__ short f16_bits(float f) {
    return __builtin_bit_cast(short, (f16)f);
}
__device__ __forceinline__ void async_copy16(const void* g, void* l) {
    __builtin_amdgcn_global_load_lds((const __attribute__((address_space(1))) void*)g,
                                     (__attribute__((address_space(3))) void*)l, 16, 0, 0);
}

// ===========================================================================
// FAST PATH — ROUND-14: single-product f16 arithmetic everywhere.
// Rationale: V and P have been single-f16 since R0 with absmax pinned at
// 0.0039; f16x1 noise (~1e-3) is the same order. Cuts MFMA work 3x and
// staging bytes 2x across the whole pipeline.
// ===========================================================================

// Fused input split: [0,4096) x -> Axs; [4096,7168) qkv_w -> Wqs;
// [7168,8192) proj_w -> Wp.  All single-plane f16 now.
__global__ __launch_bounds__(256) void split_in_fused_kernel(
    const float* __restrict__ x, short* __restrict__ Axs,
    const float* __restrict__ w, short* __restrict__ Wqs,
    const float* __restrict__ pw, short* __restrict__ Wp)
{
    const int bid = blockIdx.x;
    const float* src; short* dst; int idx;
    if (bid < 4096)      { src = x;  dst = Axs; idx = bid * 256 + threadIdx.x; }
    else if (bid < 7168) { src = w;  dst = Wqs; idx = (bid - 4096) * 256 + threadIdx.x; }
    else                 { src = pw; dst = Wp;  idx = (bid - 7168) * 256 + threadIdx.x; }
    int e = idx * 4;
    float4 v = *(const float4*)(src + e);
    ushort4 o = make_ushort4((unsigned short)f16_bits(v.x), (unsigned short)f16_bits(v.y),
                             (unsigned short)f16_bits(v.z), (unsigned short)f16_bits(v.w));
    *(ushort4*)(dst + e) = o;
}

// QKV GEMM, f16 single-product, counted-vmcnt 2-phase pipeline (identity
// block mapping — R7-proven). A [4096][1024] f16, W [3072][1024] f16.
// Epilogue writes producer-formatted f16 images: Qh/Kh [64][64] swizzled,
// Vt [d][kk] swizzled; + fused block-mean for q/k.
__global__ __launch_bounds__(256) void qkv_mfma_kernel(
    const short* __restrict__ A, const short* __restrict__ W,
    short* __restrict__ QhI, short* __restrict__ KhI, short* __restrict__ VtI,
    float* __restrict__ qbf, float* __restrict__ kbf)
{
    __shared__ short SM[16640];   // 2 planes x 2 bufs x 4096 (+ V-transpose tail)
    const int wg = blockIdx.x;
    const int row0 = (wg / 24) * 128;
    const int col0 = (wg % 24) * 128;
    const int tid = threadIdx.x;
    const int lane = tid & 63;
    const int wave = tid >> 6;
    const int wm = wave & 1, wn = wave >> 1;

    auto AHS = [&](int b) { return SM + b * 4096; };
    auto WHS = [&](int b) { return SM + 8192 + b * 4096; };

    f32x4 acc[4][4];
    const f32x4 zero = {0.f, 0.f, 0.f, 0.f};
    #pragma unroll
    for (int i = 0; i < 4; ++i)
        #pragma unroll
        for (int j = 0; j < 4; ++j) acc[i][j] = zero;

    const int ldr = lane >> 2;                              // row in 16-row chunk
    const int lko = (((lane & 3) ^ ((lane >> 3) & 3))) * 8; // swizzled k-chunk
    const int rsl = ((lane >> 4) ^ ((lane >> 1) & 3)) * 8;  // frag-read slot

    // 4 global_load_lds per wave per call (the vmcnt quantum)
    auto stage = [&](int bufi, int ktn) {
        const int kk = ktn << 5;
        #pragma unroll
        for (int i = 0; i < 2; ++i) {
            const int chunk = wave * 2 + i;
            const short* gA = A + (size_t)(row0 + chunk * 16 + ldr) * 1024 + kk + lko;
            const short* gW = W + (size_t)(col0 + chunk * 16 + ldr) * 1024 + kk + lko;
            async_copy16(gA, (char*)AHS(bufi) + chunk * 1024);
            async_copy16(gW, (char*)WHS(bufi) + chunk * 1024);
        }
    };

    auto compute = [&](int bufi) {
        const short* Ah = AHS(bufi);
        const short* Wh = WHS(bufi);
        f16x8 ah[4], wh[4];
        #pragma unroll
        for (int mi = 0; mi < 4; ++mi)
            ah[mi] = *(const f16x8*)(Ah + (wm * 64 + mi * 16 + (lane & 15)) * 32 + rsl);
        #pragma unroll
        for (int ni = 0; ni < 4; ++ni)
            wh[ni] = *(const f16x8*)(Wh + (wn * 64 + ni * 16 + (lane & 15)) * 32 + rsl);
        #pragma unroll
        for (int mi = 0; mi < 4; ++mi)
            #pragma unroll
            for (int ni = 0; ni < 4; ++ni)
                acc[mi][ni] = __builtin_amdgcn_mfma_f32_16x16x32_f16(ah[mi], wh[ni], acc[mi][ni], 0, 0, 0);
    };

    stage(0, 0);
    for (int kt = 0; kt < 30; kt += 2) {
        stage(1, kt + 1);
        VM_WAIT4; SBAR; SCHED0;
        compute(0);
        SBAR;
        stage(0, kt + 2);
        VM_WAIT4; SBAR; SCHED0;
        compute(1);
        SBAR;
    }
    stage(1, 31);
    VM_WAIT4; SBAR; SCHED0;
    compute(0);
    SBAR;
    VM_WAIT0; SBAR; SCHED0;
    compute(1);
    SBAR;   // protect LDS reuse by V-wave transpose below

    // ---- epilogue: write f16 image tiles (+ fused block-mean for q/k)
    const int gr_first = row0 + wm * 64;          // wave's 64-row token block
    const int bb = gr_first >> 11;
    const int mblk = (gr_first & 2047) >> 6;
    const int gc0 = col0 + wn * 64;               // wave's 64-col band (one head)
    const int tsel = gc0 >> 10;
    const int h = (gc0 >> 6) & 15;
    const int tile = ((bb << 4) + h) * 32 + mblk;
    const float sc = (tsel == 0) ? SCALE_F : 1.0f;

    if (tsel != 2) {
        short* baseH = ((tsel == 0) ? QhI : KhI) + (size_t)tile * 4096;
        float* mdst  = ((tsel == 0) ? qbf : kbf) + ((size_t)((bb << 4) + h) * 32 + mblk) * 64;
        #pragma unroll
        for (int ni = 0; ni < 4; ++ni) {
            const int d = ni * 16 + (lane & 15);
            float colsum = 0.f;
            #pragma unroll
            for (int mi = 0; mi < 4; ++mi) {
                #pragma unroll
                for (int r = 0; r < 4; ++r) {
                    const int row = mi * 16 + (lane >> 4) * 4 + r;
                    float v = acc[mi][ni][r] * sc;
                    colsum += v;
                    const int off = (row * 64 + d) ^ ((row & 7) << 3);   // shorts
                    baseH[off] = f16_bits(v);
                }
            }
            colsum += __shfl_xor(colsum, 16);
            colsum += __shfl_xor(colsum, 32);
            if ((lane >> 4) == 0) mdst[d] = colsum * (1.f / 64.f);
        }
    } else {
        // V: transpose 64x64 tile in per-wave LDS region, write Vt[d][kk] image
        short* tb = SM + wave * 4160;   // 64x65 shorts, per-wave exclusive
        #pragma unroll
        for (int ni = 0; ni < 4; ++ni)
            #pragma unroll
            for (int mi = 0; mi < 4; ++mi)
                #pragma unroll
                for (int r = 0; r < 4; ++r) {
                    const int row = mi * 16 + (lane >> 4) * 4 + r;   // kk
                    const int d = ni * 16 + (lane & 15);
                    tb[row * 65 + d] = f16_bits(acc[mi][ni][r]);
                }
        short* vout = VtI + (size_t)tile * 4096;
        #pragma unroll
        for (int c = 0; c < 8; ++c) {
            short8v tv;
            #pragma unroll
            for (int j = 0; j < 8; ++j)
                tv[j] = tb[(c * 8 + j) * 65 + lane];
            const int off = (lane * 64 + c * 8) ^ ((lane & 7) << 3);   // shorts
            *(short8v*)(vout + off) = tv;
        }
    }
}

// Block-scores + top-2 mask. 32 blocks (projw branch retained but unused).
__global__ __launch_bounds__(256) void scores_splitw_kernel(
    const float* __restrict__ qbf, const float* __restrict__ kbf,
    unsigned int* __restrict__ maskbits, float scale,
    const float* __restrict__ projw, short* __restrict__ Wdst)
{
    __shared__ float qs_[32][64];
    __shared__ float ks_[32][64];
    __shared__ float cb[32][32];
    const int bid = blockIdx.x;
    const int tid = threadIdx.x;

    if (bid >= 32) {
        int idx = (bid - 32) * 256 + tid;
        int e = idx * 4;
        float4 v = *(const float4*)(projw + e);
        ushort4 o = make_ushort4((unsigned short)f16_bits(v.x), (unsigned short)f16_bits(v.y),
                                 (unsigned short)f16_bits(v.z), (unsigned short)f16_bits(v.w));
        *(ushort4*)(Wdst + e) = o;
        return;
    }

    #pragma unroll
    for (int i = 0; i < 8; ++i) {
        int e = tid + i * 256;
        qs_[e >> 6][e & 63] = qbf[(size_t)bid * 2048 + e];
        ks_[e >> 6][e & 63] = kbf[(size_t)bid * 2048 + e];
    }
    __syncthreads();

    #pragma unroll
    for (int i = 0; i < 4; ++i) {
        int idx = tid + i * 256;
        int r = idx >> 5, c = idx & 31;
        float s = 0.f;
        #pragma unroll
        for (int d = 0; d < 64; ++d) s += qs_[r][d] * ks_[c][d];
        cb[r][c] = s * scale;
    }
    __syncthreads();

    if (tid < 32) {
        float m1 = -INFINITY, m2 = -INFINITY;
        for (int n = 0; n < 32; ++n) {
            float v = cb[tid][n];
            if (v > m1) { m2 = m1; m1 = v; }
            else if (v > m2) { m2 = v; }
        }
        unsigned int bits = 1u << tid;
        for (int n = 0; n < 32; ++n)
            if (cb[tid][n] >= m2) bits |= 1u << n;
        maskbits[bid * 32 + tid] = bits;
    }
}

// Proj GEMM, f16 single-product + bias. A [4096][1024] f16 (attn out),
// W [1024][1024] f16. XCD-chunked swizzle kept (Wp 2 MB fits XCD L2).
__global__ __launch_bounds__(256) void proj_mfma_kernel(
    const short* __restrict__ A, const short* __restrict__ W,
    const float* __restrict__ bias, float* __restrict__ out)
{
    __shared__ short Ahs[2][128 * 32];
    __shared__ short Whs[2][64 * 32];
    const int bid = blockIdx.x;
    const int wg = (bid & 7) * 64 + (bid >> 3);   // bijective (512 % 8 == 0)
    const int row0 = (wg >> 4) * 128;
    const int col0 = (wg & 15) * 64;
    const int tid = threadIdx.x;
    const int lane = tid & 63;
    const int wave = tid >> 6;

    f32x4 acc[2][4];
    const f32x4 zero = {0.f, 0.f, 0.f, 0.f};
    #pragma unroll
    for (int i = 0; i < 2; ++i)
        #pragma unroll
        for (int j = 0; j < 4; ++j) acc[i][j] = zero;

    const int ldr = lane >> 2;
    const int lko = (((lane & 3) ^ ((lane >> 3) & 3))) * 8;
    const int rsl = ((lane >> 4) ^ ((lane >> 1) & 3)) * 8;

    // 3 global_load_lds per wave per call
    auto stage = [&](int bufi, int ktn) {
        const int kk = ktn << 5;
        #pragma unroll
        for (int i = 0; i < 2; ++i) {
            const int chunk = wave * 2 + i;
            const short* gA = A + (size_t)(row0 + chunk * 16 + ldr) * 1024 + kk + lko;
            async_copy16(gA, (char*)&Ahs[bufi][0] + chunk * 1024);
        }
        {
            const short* gW = W + (size_t)(col0 + wave * 16 + ldr) * 1024 + kk + lko;
            async_copy16(gW, (char*)&Whs[bufi][0] + wave * 1024);
        }
    };

    auto compute = [&](int bufi) {
        const short* Ah = Ahs[bufi];
        const short* Wh = Whs[bufi];
        f16x8 ah[2], wh[4];
        #pragma unroll
        for (int mi = 0; mi < 2; ++mi)
            ah[mi] = *(const f16x8*)(Ah + (wave * 32 + mi * 16 + (lane & 15)) * 32 + rsl);
        #pragma unroll
        for (int ni = 0; ni < 4; ++ni)
            wh[ni] = *(const f16x8*)(Wh + (ni * 16 + (lane & 15)) * 32 + rsl);
        #pragma unroll
        for (int mi = 0; mi < 2; ++mi)
            #pragma unroll
            for (int ni = 0; ni < 4; ++ni)
                acc[mi][ni] = __builtin_amdgcn_mfma_f32_16x16x32_f16(ah[mi], wh[ni], acc[mi][ni], 0, 0, 0);
    };

    stage(0, 0);
    for (int kt = 0; kt < 30; kt += 2) {
        stage(1, kt + 1);
        VM_WAIT3; SBAR; SCHED0;
        compute(0);
        SBAR;
        stage(0, kt + 2);
        VM_WAIT3; SBAR; SCHED0;
        compute(1);
        SBAR;
    }
    stage(1, 31);
    VM_WAIT3; SBAR; SCHED0;
    compute(0);
    SBAR;
    VM_WAIT0; SBAR; SCHED0;
    compute(1);

    #pragma unroll
    for (int ni = 0; ni < 4; ++ni) {
        int gc = col0 + ni * 16 + (lane & 15);
        float bv = bias[gc];
        #pragma unroll
        for (int mi = 0; mi < 2; ++mi) {
            int gr0 = row0 + wave * 32 + mi * 16 + (lane >> 4) * 4;
            #pragma unroll
            for (int r = 0; r < 4; ++r)
                out[(size_t)(gr0 + r) * 1024 + gc] = acc[mi][ni][r] + bv;
        }
    }
}

// ---------------------------------------------------------------------------
// Sparse block attention — f16 single-product QK, image consumer.
// XCD-chunked swizzle kept (per-bh K/V image pool now 512 KB, fits XCD L2).
// LDS 49 KB -> 3 blocks/CU (was 2).
// ---------------------------------------------------------------------------
__global__ __launch_bounds__(256) void sparse_attn_mfma_kernel(
    const short* __restrict__ QhI, const short* __restrict__ KhI,
    const short* __restrict__ VtI, const unsigned int* __restrict__ maskbits,
    short* __restrict__ aout)
{
    __shared__ f16 Qh[4096];                  // [64][64] swizzled
    __shared__ f16 Kh[2][4096];               // dbuf
    __shared__ f16 Vt[2][4096];               // dbuf, [d][kk] swizzled
    __shared__ f16 Pb[64 * LSTR];             // P[q][kk], wave-private rows

    const int bid = blockIdx.x;
    const int wg = (bid & 7) * 128 + (bid >> 3);  // bijective (1024 % 8 == 0)
    const int m  = wg & 31;
    const int bh = wg >> 5;
    const int b  = bh >> 4, h = bh & 15;
    const int tid = threadIdx.x;
    const int lane = tid & 63;
    const int wave = tid >> 6;
    const f32x4 zero = {0.f, 0.f, 0.f, 0.f};

    const unsigned int mask = maskbits[bh * 32 + m];

    // ---- stage Q (once): 2 issues/wave
    {
        const size_t qt = (size_t)(bh * 32 + m) * 4096;
        const int so = wave * 1024 + lane * 8;
        async_copy16(QhI + qt + so,       (char*)Qh + wave * 2048);
        async_copy16(QhI + qt + so + 512, (char*)Qh + wave * 2048 + 1024);
    }

    // ---- K/V tile stage: 4 issues/wave (the vmcnt quantum)
    auto stageKV = [&](int bufi, int nb) {
        const size_t t4 = (size_t)(bh * 32 + nb) * 4096;
        const int so = wave * 1024 + lane * 8;
        async_copy16(KhI + t4 + so,       (char*)&Kh[bufi][0] + wave * 2048);
        async_copy16(KhI + t4 + so + 512, (char*)&Kh[bufi][0] + wave * 2048 + 1024);
        async_copy16(VtI + t4 + so,       (char*)&Vt[bufi][0] + wave * 2048);
        async_copy16(VtI + t4 + so + 512, (char*)&Vt[bufi][0] + wave * 2048 + 1024);
    };

    f32x4 o_acc[4];
    float macc[4], lacc[4];
    #pragma unroll
    for (int r = 0; r < 4; ++r) { macc[r] = -INFINITY; lacc[r] = 0.f; }
    #pragma unroll
    for (int t = 0; t < 4; ++t) o_acc[t] = zero;

    const int arow = wave * 16 + (lane & 15);
    const int kofs = (lane >> 4) * 8;      // shorts (for Pb)
    const int colb = (lane >> 4) * 16;     // bytes (for swizzled images)

    auto computeTile = [&](int bi) {
        const f16* KhB = &Kh[bi][0];
        // ---- QK^T: f16 single product (swizzled reads)
        f32x4 s_acc[4];
        #pragma unroll
        for (int t = 0; t < 4; ++t) s_acc[t] = zero;
        #pragma unroll
        for (int c = 0; c < 2; ++c) {
            const int qoff = (arow * 128 + c * 64 + colb) ^ ((arow & 7) << 4);
            f16x8 ah = *(const f16x8*)((const char*)Qh + qoff);
            #pragma unroll
            for (int t = 0; t < 4; ++t) {
                const int krow = t * 16 + (lane & 15);
                const int koff = (krow * 128 + c * 64 + colb) ^ ((krow & 7) << 4);
                f16x8 bh_ = *(const f16x8*)((const char*)KhB + koff);
                s_acc[t] = __builtin_amdgcn_mfma_f32_16x16x32_f16(ah, bh_, s_acc[t], 0, 0, 0);
            }
        }

        // ---- online softmax
        float alpha[4], psum[4];
        #pragma unroll
        for (int r = 0; r < 4; ++r) {
            float v0 = fmaxf(fmaxf(s_acc[0][r], s_acc[1][r]), fmaxf(s_acc[2][r], s_acc[3][r]));
            #pragma unroll
            for (int off = 1; off < 16; off <<= 1)
                v0 = fmaxf(v0, __shfl_xor(v0, off));
            float mnew = fmaxf(macc[r], v0);
            alpha[r] = expf(macc[r] - mnew);
            macc[r] = mnew;
            psum[r] = 0.f;
        }
        #pragma unroll
        for (int t = 0; t < 4; ++t) {
            #pragma unroll
            for (int r = 0; r < 4; ++r) {
                float p = expf(s_acc[t][r] - macc[r]);
                psum[r] += p;
                Pb[(wave * 16 + (lane >> 4) * 4 + r) * LSTR + t * 16 + (lane & 15)] = (f16)p;
            }
        }
        #pragma unroll
        for (int r = 0; r < 4; ++r) {
            float v0 = psum[r];
            #pragma unroll
            for (int off = 1; off < 16; off <<= 1) v0 += __shfl_xor(v0, off);
            lacc[r] = lacc[r] * alpha[r] + v0;
            #pragma unroll
            for (int t = 0; t < 4; ++t) o_acc[t][r] *= alpha[r];
        }

        // ---- PV (Pb rows are wave-private; Vt stable until trailing barrier)
        const f16* VtB = &Vt[bi][0];
        #pragma unroll
        for (int c = 0; c < 2; ++c) {
            f16x8 af = *(const f16x8*)(Pb + arow * LSTR + c * 32 + kofs);
            #pragma unroll
            for (int t = 0; t < 4; ++t) {
                const int vrow = t * 16 + (lane & 15);
                const int voff = (vrow * 128 + c * 64 + colb) ^ ((vrow & 7) << 4);
                f16x8 bf = *(const f16x8*)((const char*)VtB + voff);
                o_acc[t] = __builtin_amdgcn_mfma_f32_16x16x32_f16(af, bf, o_acc[t], 0, 0, 0);
            }
        }
    };

    // ---- pipelined masked loop (mask always has the diagonal bit set)
    unsigned int mm = mask;
    int nb0 = __builtin_ctz(mm); mm &= mm - 1;
    stageKV(0, nb0);
    int cur = 0;
    for (;;) {
        int nb_nxt = -1;
        if (mm) { nb_nxt = __builtin_ctz(mm); mm &= mm - 1; stageKV(cur ^ 1, nb_nxt); }
        if (nb_nxt >= 0) { VM_WAIT4; } else { VM_WAIT0; }
        SBAR; SCHED0;
        computeTile(cur);
        SBAR;
        if (nb_nxt < 0) break;
        cur ^= 1;
    }

    // ---- epilogue: normalize, write single-f16 attn output [4096][1024]
    float inv[4];
    #pragma unroll
    for (int r = 0; r < 4; ++r) inv[r] = (lacc[r] > 0.f) ? (1.f / lacc[r]) : 0.f;
    #pragma unroll
    for (int t = 0; t < 4; ++t) {
        int gc = h * 64 + t * 16 + (lane & 15);
        #pragma unroll
        for (int r = 0; r < 4; ++r) {
            int grow = b * NN + m * 64 + wave * 16 + (lane >> 4) * 4 + r;
            float v = o_acc[t][r] * inv[r];
            aout[(size_t)grow * 1024 + gc] = f16_bits(v);
        }
    }
}

// ===========================================================================
// FALLBACK KERNELS (round-2 proven fp32 path)
// ===========================================================================

__global__ __launch_bounds__(256) void block_mean_kernel(
    const float* __restrict__ qf, const float* __restrict__ kf,
    float* __restrict__ qbf, float* __restrict__ kbf)
{
    int idx = blockIdx.x * 256 + threadIdx.x;
    const float* src = (idx < 65536) ? qf : kf;
    float* dst       = (idx < 65536) ? qbf : kbf;
    int e = idx & 65535;
    int d = e & 63;
    int r = e >> 6;
    size_t base = (size_t)r * 4096 + d;
    float s = 0.f;
    #pragma unroll
    for (int i = 0; i < 64; ++i) s += src[base + (size_t)i * 64];
    dst[e] = s * (1.f / 64.f);
}

__global__ __launch_bounds__(256) void qkv_gemm_fb(
    const float* __restrict__ x, const float* __restrict__ w,
    float* __restrict__ qf, float* __restrict__ kf, float* __restrict__ vf)
{
    __shared__ float As[64][33];
    __shared__ float Bs[64][33];
    const int tid = threadIdx.x;
    const int row0 = blockIdx.y * 64;
    const int col0 = blockIdx.x * 64;
    const int ty = tid >> 4, tx = tid & 15;

    float acc[4][4] = {};
    for (int k0 = 0; k0 < 1024; k0 += 32) {
        #pragma unroll
        for (int i = 0; i < 8; ++i) {
            int e = tid + i * 256;
            int r = e >> 5, c = e & 31;
            As[r][c] = x[(size_t)(row0 + r) * 1024 + k0 + c];
            Bs[r][c] = w[(size_t)(col0 + r) * 1024 + k0 + c];
        }
        __syncthreads();
        #pragma unroll
        for (int kk = 0; kk < 32; ++kk) {
            float a[4], bq[4];
            #pragma unroll
            for (int i = 0; i < 4; ++i) a[i] = As[ty * 4 + i][kk];
            #pragma unroll
            for (int j = 0; j < 4; ++j) bq[j] = Bs[tx * 4 + j][kk];
            #pragma unroll
            for (int i = 0; i < 4; ++i)
                #pragma unroll
                for (int j = 0; j < 4; ++j)
                    acc[i][j] += a[i] * bq[j];
        }
        __syncthreads();
    }

    const int tsel = col0 >> 10;
    const int h    = (col0 & 1023) >> 6;
    float* dstbuf = (tsel == 0) ? qf : (tsel == 1) ? kf : vf;
    #pragma unroll
    for (int i = 0; i < 4; ++i) {
        int row = row0 + ty * 4 + i;
        int b   = row >> 11, n = row & 2047;
        size_t rb = ((size_t)(b * HH + h) * NN + n) * HD64;
        #pragma unroll
        for (int j = 0; j < 4; ++j)
            dstbuf[rb + tx * 4 + j] = acc[i][j];
    }
}

__global__ __launch_bounds__(256) void proj_gemm_fb(
    const float* __restrict__ attn, const float* __restrict__ w,
    const float* __restrict__ bias, float* __restrict__ out)
{
    __shared__ float As[64][33];
    __shared__ float Bs[64][33];
    const int tid = threadIdx.x;
    const int row0 = blockIdx.y * 64;
    const int col0 = blockIdx.x * 64;
    const int ty = tid >> 4, tx = tid & 15;

    float acc[4][4] = {};
    for (int k0 = 0; k0 < 1024; k0 += 32) {
        #pragma unroll
        for (int i = 0; i < 8; ++i) {
            int e = tid + i * 256;
            int r = e >> 5, c = e & 31;
            As[r][c] = attn[(size_t)(row0 + r) * 1024 + k0 + c];
            Bs[r][c] = w[(size_t)(col0 + r) * 1024 + k0 + c];
        }
        __syncthreads();
        #pragma unroll
        for (int kk = 0; kk < 32; ++kk) {
            float a[4], bq[4];
            #pragma unroll
            for (int i = 0; i < 4; ++i) a[i] = As[ty * 4 + i][kk];
            #pragma unroll
            for (int j = 0; j < 4; ++j) bq[j] = Bs[tx * 4 + j][kk];
            #pragma unroll
            for (int i = 0; i < 4; ++i)
                #pragma unroll
                for (int j = 0; j < 4; ++j)
                    acc[i][j] += a[i] * bq[j];
        }
        __syncthreads();
    }

    #pragma unroll
    for (int j = 0; j < 4; ++j) {
        int col = col0 + tx * 4 + j;
        float bv = bias[col];
        #pragma unroll
        for (int i = 0; i < 4; ++i) {
            int row = row0 + ty * 4 + i;
            out[(size_t)row * 1024 + col] = acc[i][j] + bv;
        }
    }
}

__global__ __launch_bounds__(256) void sparse_attn_fb(
    const float* __restrict__ qf, const float* __restrict__ kf,
    const float* __restrict__ vf, const unsigned int* __restrict__ maskbits,
    float* __restrict__ attnf)
{
    __shared__ float kbuf[64][64];
    __shared__ float vbuf[64][64];
    __shared__ float sbuf[64][65];
    const int m  = blockIdx.x & 31;
    const int bh = blockIdx.x >> 5;
    const int b  = bh >> 4, h = bh & 15;
    const int t  = threadIdx.x;
    const int qr = t >> 2;
    const int dg = t & 3;
    const int d0 = dg * 16;

    float qreg[16];
    {
        const float* qp = qf + ((size_t)bh * NN + m * 64 + qr) * HD64 + d0;
        #pragma unroll
        for (int j = 0; j < 16; j += 4) {
            float4 v = *(const float4*)(qp + j);
            qreg[j] = v.x; qreg[j+1] = v.y; qreg[j+2] = v.z; qreg[j+3] = v.w;
        }
    }

    const unsigned int mask = maskbits[bh * 32 + m];
    float macc = -INFINITY, lacc = 0.f;
    float oacc[16];
    #pragma unroll
    for (int j = 0; j < 16; ++j) oacc[j] = 0.f;

    for (int nb = 0; nb < 32; ++nb) {
        if (!((mask >> nb) & 1u)) continue;
        __syncthreads();
        {
            const float* gk = kf + ((size_t)bh * NN + nb * 64) * HD64;
            const float* gv = vf + ((size_t)bh * NN + nb * 64) * HD64;
            #pragma unroll
            for (int i = 0; i < 4; ++i) {
                async_copy16(gk + t * 4 + i * 1024, (char*)kbuf + t * 16 + i * 4096);
                async_copy16(gv + t * 4 + i * 1024, (char*)vbuf + t * 16 + i * 4096);
            }
        }
        __syncthreads();

        float bmax = -INFINITY;
        for (int kk = 0; kk < 64; ++kk) {
            float s = 0.f;
            #pragma unroll
            for (int j = 0; j < 16; ++j) s += qreg[j] * kbuf[kk][d0 + j];
            s += __shfl_xor(s, 1);
            s += __shfl_xor(s, 2);
            s *= SCALE_F;
            if (dg == 0) sbuf[qr][kk] = s;
            bmax = fmaxf(bmax, s);
        }
        float mnew  = fmaxf(macc, bmax);
        float alpha = expf(macc - mnew);
        lacc *= alpha;
        #pragma unroll
        for (int j = 0; j < 16; ++j) oacc[j] *= alpha;
        for (int kk = 0; kk < 64; ++kk) {
            float p = expf(sbuf[qr][kk] - mnew);
            lacc += p;
            #pragma unroll
            for (int j = 0; j < 16; ++j) oacc[j] += p * vbuf[kk][d0 + j];
        }
        macc = mnew;
    }

    float inv = (lacc > 0.f) ? (1.f / lacc) : 0.f;
    size_t orow = ((size_t)(b * NN + m * 64 + qr)) * DIMD + h * 64 + d0;
    #pragma unroll
    for (int j = 0; j < 16; ++j) attnf[orow + j] = oacc[j] * inv;
}

// ---------------------------------------------------------------------------
extern "C" void kernel_launch(void* const* d_in, const int* in_sizes, int n_in,
                              void* d_out, int out_size, void* d_ws, size_t ws_size,
                              hipStream_t stream)
{
    const float* x      = (const float*)d_in[0];
    const float* qkv_w  = (const float*)d_in[1];
    const float* proj_w = (const float*)d_in[2];
    const float* proj_b = (const float*)d_in[3];
    float* out = (float*)d_out;

    // Carve (fast path, ~41 MB):
    //   Qh/Kh/Vt images: 3 x 8 MB f16 tiles [1024 tiles][4096 shorts]
    //   qbf/kbf 512K | mask 4K
    //   Axs 8M f16 [4096][1024] (x-split; reused as attention output)
    //   Wqs 6M f16 [3072][1024] | Wp 2M f16 [1024][1024]
    short* QhI = (short*)d_ws;
    short* KhI = QhI + 4194304;
    short* VtI = KhI + 4194304;
    float* qbf = (float*)(VtI + 4194304);
    float* kbf = qbf + 65536;
    unsigned int* maskb = (unsigned int*)(kbf + 65536);
    short* Axs = (short*)(maskb + 1024);
    short* Wqs = Axs + (size_t)4096 * 1024;
    short* Wp  = Wqs + (size_t)3072 * 1024;
    const size_t need_fast = (size_t)((char*)(Wp + (size_t)1024 * 1024) - (char*)d_ws);

    if (ws_size >= need_fast) {
        split_in_fused_kernel<<<8192, 256, 0, stream>>>(x, Axs, qkv_w, Wqs, proj_w, Wp);
        qkv_mfma_kernel<<<768, 256, 0, stream>>>(Axs, Wqs, QhI, KhI, VtI, qbf, kbf);
        scores_splitw_kernel<<<32, 256, 0, stream>>>(qbf, kbf, maskb, 1.0f,
                                                     (const float*)nullptr, (short*)nullptr);
        sparse_attn_mfma_kernel<<<1024, 256, 0, stream>>>(QhI, KhI, VtI, maskb, Axs);
        proj_mfma_kernel<<<512, 256, 0, stream>>>(Axs, Wp, proj_b, out);
    } else {
        float* qf2  = (float*)d_ws;
        float* kf2  = qf2 + 4194304;
        float* vf2  = kf2 + 4194304;
        float* qbf2 = vf2 + 4194304;
        float* kbf2 = qbf2 + 65536;
        unsigned int* maskb2 = (unsigned int*)(kbf2 + 65536);
        float* attnf = (float*)(maskb2 + 1024);
        qkv_gemm_fb<<<dim3(48, 64), 256, 0, stream>>>(x, qkv_w, qf2, kf2, vf2);
        block_mean_kernel<<<512, 256, 0, stream>>>(qf2, kf2, qbf2, kbf2);
        scores_splitw_kernel<<<32, 256, 0, stream>>>(qbf2, kbf2, maskb2, SCALE_F,
                                                     (const float*)nullptr, (short*)nullptr);
        sparse_attn_fb<<<1024, 256, 0, stream>>>(qf2, kf2, vf2, maskb2, attnf);
        proj_gemm_fb<<<dim3(16, 64), 256, 0, stream>>>(attnf, proj_w, proj_b, out);
    }
}

// Round 11
// 160.572 us; speedup vs baseline: 1.5439x; 1.1452x over previous
//
#include <hip/hip_runtime.h>
#include <hip/hip_bf16.h>

// Problem constants (B=2, N=2048, DIM=1024, H=16, HD=64, BS=64, M=32)
#define BB 2
#define NN 2048
#define DIMD 1024
#define HH 16
#define HD64 64
#define MB 32
#define SCALE_F 0.125f   // HD^-0.5

typedef __attribute__((ext_vector_type(8))) short bf16x8;
typedef __attribute__((ext_vector_type(8))) short short8v;
typedef __attribute__((ext_vector_type(4))) float f32x4;
typedef _Float16 f16;
typedef __attribute__((ext_vector_type(8))) _Float16 f16x8;

#define LSTR 72   // padded LDS row stride (f16) for Pb

// counted-vmcnt barrier discipline (T4) — R8-proven 1-ahead quanta only.
#define VM_WAIT4 asm volatile("s_waitcnt vmcnt(4)" ::: "memory")
#define VM_WAIT3 asm volatile("s_waitcnt vmcnt(3)" ::: "memory")
#define VM_WAIT0 asm volatile("s_waitcnt vmcnt(0)" ::: "memory")
#define SBAR __builtin_amdgcn_s_barrier()
#define SCHED0 __builtin_amdgcn_sched_barrier(0)

__device__ __forceinline__ unsigned short bf16_hi(float f) {
    return __builtin_bit_cast(unsigned short, __float2bfloat16(f));
}
__device__ __forceinline__ float bf16_val(unsigned short u) {
    return __bfloat162float(__builtin_bit_cast(__hip_bfloat16, u));
}
__device__ __forceinline__ short f16_bits(float f) {
    return __builtin_bit_cast(short, (f16)f);
}
__device__ __forceinline__ void async_copy16(const void* g, void* l) {
    __builtin_amdgcn_global_load_lds((const __attribute__((address_space(1))) void*)g,
                                     (__attribute__((address_space(3))) void*)l, 16, 0, 0);
}

// ===========================================================================
// FAST PATH — single-product f16, R8-proven sync structure (2-buf, 1-ahead).
// R11: bisect half #2 — ONLY the in-kernel mask fusion added to attn; the
// 3-buffer pipelines from R9/R10 are RETIRED (R10 proved them broken).
// ===========================================================================

// Fused input split: [0,4096) x -> Axs; [4096,7168) qkv_w -> Wqs;
// [7168,8192) proj_w -> Wp.  Single-plane f16.
__global__ __launch_bounds__(256) void split_in_fused_kernel(
    const float* __restrict__ x, short* __restrict__ Axs,
    const float* __restrict__ w, short* __restrict__ Wqs,
    const float* __restrict__ pw, short* __restrict__ Wp)
{
    const int bid = blockIdx.x;
    const float* src; short* dst; int idx;
    if (bid < 4096)      { src = x;  dst = Axs; idx = bid * 256 + threadIdx.x; }
    else if (bid < 7168) { src = w;  dst = Wqs; idx = (bid - 4096) * 256 + threadIdx.x; }
    else                 { src = pw; dst = Wp;  idx = (bid - 7168) * 256 + threadIdx.x; }
    int e = idx * 4;
    float4 v = *(const float4*)(src + e);
    ushort4 o = make_ushort4((unsigned short)f16_bits(v.x), (unsigned short)f16_bits(v.y),
                             (unsigned short)f16_bits(v.z), (unsigned short)f16_bits(v.w));
    *(ushort4*)(dst + e) = o;
}

// QKV GEMM, f16 single-product — R8 VERBATIM (2-buf, 1-ahead, vmcnt(4)).
// Epilogue writes producer-formatted f16 images + fused block-mean.
__global__ __launch_bounds__(256) void qkv_mfma_kernel(
    const short* __restrict__ A, const short* __restrict__ W,
    short* __restrict__ QhI, short* __restrict__ KhI, short* __restrict__ VtI,
    float* __restrict__ qbf, float* __restrict__ kbf)
{
    __shared__ short SM[16640];   // 2 planes x 2 bufs x 4096 (+ V-transpose tail)
    const int wg = blockIdx.x;
    const int row0 = (wg / 24) * 128;
    const int col0 = (wg % 24) * 128;
    const int tid = threadIdx.x;
    const int lane = tid & 63;
    const int wave = tid >> 6;
    const int wm = wave & 1, wn = wave >> 1;

    auto AHS = [&](int b) { return SM + b * 4096; };
    auto WHS = [&](int b) { return SM + 8192 + b * 4096; };

    f32x4 acc[4][4];
    const f32x4 zero = {0.f, 0.f, 0.f, 0.f};
    #pragma unroll
    for (int i = 0; i < 4; ++i)
        #pragma unroll
        for (int j = 0; j < 4; ++j) acc[i][j] = zero;

    const int ldr = lane >> 2;                              // row in 16-row chunk
    const int lko = (((lane & 3) ^ ((lane >> 3) & 3))) * 8; // swizzled k-chunk
    const int rsl = ((lane >> 4) ^ ((lane >> 1) & 3)) * 8;  // frag-read slot

    // 4 global_load_lds per wave per call (the vmcnt quantum)
    auto stage = [&](int bufi, int ktn) {
        const int kk = ktn << 5;
        #pragma unroll
        for (int i = 0; i < 2; ++i) {
            const int chunk = wave * 2 + i;
            const short* gA = A + (size_t)(row0 + chunk * 16 + ldr) * 1024 + kk + lko;
            const short* gW = W + (size_t)(col0 + chunk * 16 + ldr) * 1024 + kk + lko;
            async_copy16(gA, (char*)AHS(bufi) + chunk * 1024);
            async_copy16(gW, (char*)WHS(bufi) + chunk * 1024);
        }
    };

    auto compute = [&](int bufi) {
        const short* Ah = AHS(bufi);
        const short* Wh = WHS(bufi);
        f16x8 ah[4], wh[4];
        #pragma unroll
        for (int mi = 0; mi < 4; ++mi)
            ah[mi] = *(const f16x8*)(Ah + (wm * 64 + mi * 16 + (lane & 15)) * 32 + rsl);
        #pragma unroll
        for (int ni = 0; ni < 4; ++ni)
            wh[ni] = *(const f16x8*)(Wh + (wn * 64 + ni * 16 + (lane & 15)) * 32 + rsl);
        #pragma unroll
        for (int mi = 0; mi < 4; ++mi)
            #pragma unroll
            for (int ni = 0; ni < 4; ++ni)
                acc[mi][ni] = __builtin_amdgcn_mfma_f32_16x16x32_f16(ah[mi], wh[ni], acc[mi][ni], 0, 0, 0);
    };

    stage(0, 0);
    for (int kt = 0; kt < 30; kt += 2) {
        stage(1, kt + 1);
        VM_WAIT4; SBAR; SCHED0;
        compute(0);
        SBAR;
        stage(0, kt + 2);
        VM_WAIT4; SBAR; SCHED0;
        compute(1);
        SBAR;
    }
    stage(1, 31);
    VM_WAIT4; SBAR; SCHED0;
    compute(0);
    SBAR;
    VM_WAIT0; SBAR; SCHED0;
    compute(1);
    SBAR;   // protect LDS reuse by V-wave transpose below

    // ---- epilogue: write f16 image tiles (+ fused block-mean for q/k)
    const int gr_first = row0 + wm * 64;          // wave's 64-row token block
    const int bb = gr_first >> 11;
    const int mblk = (gr_first & 2047) >> 6;
    const int gc0 = col0 + wn * 64;               // wave's 64-col band (one head)
    const int tsel = gc0 >> 10;
    const int h = (gc0 >> 6) & 15;
    const int tile = ((bb << 4) + h) * 32 + mblk;
    const float sc = (tsel == 0) ? SCALE_F : 1.0f;

    if (tsel != 2) {
        short* baseH = ((tsel == 0) ? QhI : KhI) + (size_t)tile * 4096;
        float* mdst  = ((tsel == 0) ? qbf : kbf) + ((size_t)((bb << 4) + h) * 32 + mblk) * 64;
        #pragma unroll
        for (int ni = 0; ni < 4; ++ni) {
            const int d = ni * 16 + (lane & 15);
            float colsum = 0.f;
            #pragma unroll
            for (int mi = 0; mi < 4; ++mi) {
                #pragma unroll
                for (int r = 0; r < 4; ++r) {
                    const int row = mi * 16 + (lane >> 4) * 4 + r;
                    float v = acc[mi][ni][r] * sc;
                    colsum += v;
                    const int off = (row * 64 + d) ^ ((row & 7) << 3);   // shorts
                    baseH[off] = f16_bits(v);
                }
            }
            colsum += __shfl_xor(colsum, 16);
            colsum += __shfl_xor(colsum, 32);
            if ((lane >> 4) == 0) mdst[d] = colsum * (1.f / 64.f);
        }
    } else {
        // V: transpose 64x64 tile in per-wave LDS region, write Vt[d][kk] image
        short* tb = SM + wave * 4160;   // 64x65 shorts, per-wave exclusive
        #pragma unroll
        for (int ni = 0; ni < 4; ++ni)
            #pragma unroll
            for (int mi = 0; mi < 4; ++mi)
                #pragma unroll
                for (int r = 0; r < 4; ++r) {
                    const int row = mi * 16 + (lane >> 4) * 4 + r;   // kk
                    const int d = ni * 16 + (lane & 15);
                    tb[row * 65 + d] = f16_bits(acc[mi][ni][r]);
                }
        short* vout = VtI + (size_t)tile * 4096;
        #pragma unroll
        for (int c = 0; c < 8; ++c) {
            short8v tv;
            #pragma unroll
            for (int j = 0; j < 8; ++j)
                tv[j] = tb[(c * 8 + j) * 65 + lane];
            const int off = (lane * 64 + c * 8) ^ ((lane & 7) << 3);   // shorts
            *(short8v*)(vout + off) = tv;
        }
    }
}

// Block-scores + top-2 mask (FALLBACK PATH ONLY).
__global__ __launch_bounds__(256) void scores_splitw_kernel(
    const float* __restrict__ qbf, const float* __restrict__ kbf,
    unsigned int* __restrict__ maskbits, float scale,
    const float* __restrict__ projw, short* __restrict__ Wdst)
{
    __shared__ float qs_[32][64];
    __shared__ float ks_[32][64];
    __shared__ float cb[32][32];
    const int bid = blockIdx.x;
    const int tid = threadIdx.x;

    if (bid >= 32) {
        int idx = (bid - 32) * 256 + tid;
        int e = idx * 4;
        float4 v = *(const float4*)(projw + e);
        ushort4 o = make_ushort4((unsigned short)f16_bits(v.x), (unsigned short)f16_bits(v.y),
                                 (unsigned short)f16_bits(v.z), (unsigned short)f16_bits(v.w));
        *(ushort4*)(Wdst + e) = o;
        return;
    }

    #pragma unroll
    for (int i = 0; i < 8; ++i) {
        int e = tid + i * 256;
        qs_[e >> 6][e & 63] = qbf[(size_t)bid * 2048 + e];
        ks_[e >> 6][e & 63] = kbf[(size_t)bid * 2048 + e];
    }
    __syncthreads();

    #pragma unroll
    for (int i = 0; i < 4; ++i) {
        int idx = tid + i * 256;
        int r = idx >> 5, c = idx & 31;
        float s = 0.f;
        #pragma unroll
        for (int d = 0; d < 64; ++d) s += qs_[r][d] * ks_[c][d];
        cb[r][c] = s * scale;
    }
    __syncthreads();

    if (tid < 32) {
        float m1 = -INFINITY, m2 = -INFINITY;
        for (int n = 0; n < 32; ++n) {
            float v = cb[tid][n];
            if (v > m1) { m2 = m1; m1 = v; }
            else if (v > m2) { m2 = v; }
        }
        unsigned int bits = 1u << tid;
        for (int n = 0; n < 32; ++n)
            if (cb[tid][n] >= m2) bits |= 1u << n;
        maskbits[bid * 32 + tid] = bits;
    }
}

// Proj GEMM, f16 single-product + bias — R8 VERBATIM (2-buf, vmcnt(3)).
__global__ __launch_bounds__(256) void proj_mfma_kernel(
    const short* __restrict__ A, const short* __restrict__ W,
    const float* __restrict__ bias, float* __restrict__ out)
{
    __shared__ short Ahs[2][128 * 32];
    __shared__ short Whs[2][64 * 32];
    const int bid = blockIdx.x;
    const int wg = (bid & 7) * 64 + (bid >> 3);   // bijective (512 % 8 == 0)
    const int row0 = (wg >> 4) * 128;
    const int col0 = (wg & 15) * 64;
    const int tid = threadIdx.x;
    const int lane = tid & 63;
    const int wave = tid >> 6;

    f32x4 acc[2][4];
    const f32x4 zero = {0.f, 0.f, 0.f, 0.f};
    #pragma unroll
    for (int i = 0; i < 2; ++i)
        #pragma unroll
        for (int j = 0; j < 4; ++j) acc[i][j] = zero;

    const int ldr = lane >> 2;
    const int lko = (((lane & 3) ^ ((lane >> 3) & 3))) * 8;
    const int rsl = ((lane >> 4) ^ ((lane >> 1) & 3)) * 8;

    // 3 global_load_lds per wave per call
    auto stage = [&](int bufi, int ktn) {
        const int kk = ktn << 5;
        #pragma unroll
        for (int i = 0; i < 2; ++i) {
            const int chunk = wave * 2 + i;
            const short* gA = A + (size_t)(row0 + chunk * 16 + ldr) * 1024 + kk + lko;
            async_copy16(gA, (char*)&Ahs[bufi][0] + chunk * 1024);
        }
        {
            const short* gW = W + (size_t)(col0 + wave * 16 + ldr) * 1024 + kk + lko;
            async_copy16(gW, (char*)&Whs[bufi][0] + wave * 1024);
        }
    };

    auto compute = [&](int bufi) {
        const short* Ah = Ahs[bufi];
        const short* Wh = Whs[bufi];
        f16x8 ah[2], wh[4];
        #pragma unroll
        for (int mi = 0; mi < 2; ++mi)
            ah[mi] = *(const f16x8*)(Ah + (wave * 32 + mi * 16 + (lane & 15)) * 32 + rsl);
        #pragma unroll
        for (int ni = 0; ni < 4; ++ni)
            wh[ni] = *(const f16x8*)(Wh + (ni * 16 + (lane & 15)) * 32 + rsl);
        #pragma unroll
        for (int mi = 0; mi < 2; ++mi)
            #pragma unroll
            for (int ni = 0; ni < 4; ++ni)
                acc[mi][ni] = __builtin_amdgcn_mfma_f32_16x16x32_f16(ah[mi], wh[ni], acc[mi][ni], 0, 0, 0);
    };

    stage(0, 0);
    for (int kt = 0; kt < 30; kt += 2) {
        stage(1, kt + 1);
        VM_WAIT3; SBAR; SCHED0;
        compute(0);
        SBAR;
        stage(0, kt + 2);
        VM_WAIT3; SBAR; SCHED0;
        compute(1);
        SBAR;
    }
    stage(1, 31);
    VM_WAIT3; SBAR; SCHED0;
    compute(0);
    SBAR;
    VM_WAIT0; SBAR; SCHED0;
    compute(1);

    #pragma unroll
    for (int ni = 0; ni < 4; ++ni) {
        int gc = col0 + ni * 16 + (lane & 15);
        float bv = bias[gc];
        #pragma unroll
        for (int mi = 0; mi < 2; ++mi) {
            int gr0 = row0 + wave * 32 + mi * 16 + (lane >> 4) * 4;
            #pragma unroll
            for (int r = 0; r < 4; ++r)
                out[(size_t)(gr0 + r) * 1024 + gc] = acc[mi][ni][r] + bv;
        }
    }
}

// ---------------------------------------------------------------------------
// Sparse block attention — R8 core + R11 in-kernel mask (scores launch gone).
// Diagonal tile (always in mask) staged BEFORE the mask calc; mask dot-product
// FP order replicated exactly (serial d=0..63, scale 1.0 elided) so block
// selection matches the scores kernel bit-for-bit. Only delta: diag tile
// processed first (online-softmax rounding order, ~1e-6).
// ---------------------------------------------------------------------------
__global__ __launch_bounds__(256) void sparse_attn_mfma_kernel(
    const short* __restrict__ QhI, const short* __restrict__ KhI,
    const short* __restrict__ VtI,
    const float* __restrict__ qbf, const float* __restrict__ kbf,
    short* __restrict__ aout)
{
    __shared__ f16 Qh[4096];                  // [64][64] swizzled
    __shared__ f16 Kh[2][4096];               // dbuf
    __shared__ f16 Vt[2][4096];               // dbuf, [d][kk] swizzled
    __shared__ f16 Pb[64 * LSTR];             // P[q][kk], wave-private rows

    const int bid = blockIdx.x;
    const int wg = (bid & 7) * 128 + (bid >> 3);  // bijective (1024 % 8 == 0)
    const int m  = wg & 31;
    const int bh = wg >> 5;
    const int b  = bh >> 4, h = bh & 15;
    const int tid = threadIdx.x;
    const int lane = tid & 63;
    const int wave = tid >> 6;
    const f32x4 zero = {0.f, 0.f, 0.f, 0.f};

    // ---- stage Q (once): 2 issues/wave
    {
        const size_t qt = (size_t)(bh * 32 + m) * 4096;
        const int so = wave * 1024 + lane * 8;
        async_copy16(QhI + qt + so,       (char*)Qh + wave * 2048);
        async_copy16(QhI + qt + so + 512, (char*)Qh + wave * 2048 + 1024);
    }

    // ---- K/V tile stage: 4 issues/wave (the vmcnt quantum)
    auto stageKV = [&](int bufi, int nb) {
        const size_t t4 = (size_t)(bh * 32 + nb) * 4096;
        const int so = wave * 1024 + lane * 8;
        async_copy16(KhI + t4 + so,       (char*)&Kh[bufi][0] + wave * 2048);
        async_copy16(KhI + t4 + so + 512, (char*)&Kh[bufi][0] + wave * 2048 + 1024);
        async_copy16(VtI + t4 + so,       (char*)&Vt[bufi][0] + wave * 2048);
        async_copy16(VtI + t4 + so + 512, (char*)&Vt[bufi][0] + wave * 2048 + 1024);
    };

    // ---- diagonal tile is ALWAYS in the mask: stage it before the mask calc
    stageKV(0, m);

    // ---- in-kernel mask (all waves redundantly; FP order == scores kernel).
    // The 128 qbf/kbf loads retire in-order AFTER the 6 stage loads above, so
    // by the time `mask` is materialized the Q + diag tiles have landed.
    unsigned int mask;
    {
        float c = -INFINITY;
        if (lane < 32) {
            const float* qrow = qbf + ((size_t)bh * 32 + m) * 64;
            const float* krow = kbf + ((size_t)bh * 32 + lane) * 64;
            float s = 0.f;
            for (int d = 0; d < 64; ++d) s += qrow[d] * krow[d];
            c = s;
        }
        float m1 = c;
        #pragma unroll
        for (int off = 1; off < 64; off <<= 1) m1 = fmaxf(m1, __shfl_xor(m1, off));
        unsigned long long eq = __ballot(c == m1);
        float cx = (c == m1) ? -INFINITY : c;
        #pragma unroll
        for (int off = 1; off < 64; off <<= 1) cx = fmaxf(cx, __shfl_xor(cx, off));
        float m2 = (__popcll(eq) >= 2) ? m1 : cx;
        unsigned long long ge = __ballot(c >= m2);
        mask = (unsigned int)(ge & 0xffffffffULL) | (1u << m);
    }

    f32x4 o_acc[4];
    float macc[4], lacc[4];
    #pragma unroll
    for (int r = 0; r < 4; ++r) { macc[r] = -INFINITY; lacc[r] = 0.f; }
    #pragma unroll
    for (int t = 0; t < 4; ++t) o_acc[t] = zero;

    const int arow = wave * 16 + (lane & 15);
    const int kofs = (lane >> 4) * 8;      // shorts (for Pb)
    const int colb = (lane >> 4) * 16;     // bytes (for swizzled images)

    auto computeTile = [&](int bi) {
        const f16* KhB = &Kh[bi][0];
        // ---- QK^T: f16 single product (swizzled reads)
        f32x4 s_acc[4];
        #pragma unroll
        for (int t = 0; t < 4; ++t) s_acc[t] = zero;
        #pragma unroll
        for (int c = 0; c < 2; ++c) {
            const int qoff = (arow * 128 + c * 64 + colb) ^ ((arow & 7) << 4);
            f16x8 ah = *(const f16x8*)((const char*)Qh + qoff);
            #pragma unroll
            for (int t = 0; t < 4; ++t) {
                const int krow = t * 16 + (lane & 15);
                const int koff = (krow * 128 + c * 64 + colb) ^ ((krow & 7) << 4);
                f16x8 bh_ = *(const f16x8*)((const char*)KhB + koff);
                s_acc[t] = __builtin_amdgcn_mfma_f32_16x16x32_f16(ah, bh_, s_acc[t], 0, 0, 0);
            }
        }

        // ---- online softmax
        float alpha[4], psum[4];
        #pragma unroll
        for (int r = 0; r < 4; ++r) {
            float v0 = fmaxf(fmaxf(s_acc[0][r], s_acc[1][r]), fmaxf(s_acc[2][r], s_acc[3][r]));
            #pragma unroll
            for (int off = 1; off < 16; off <<= 1)
                v0 = fmaxf(v0, __shfl_xor(v0, off));
            float mnew = fmaxf(macc[r], v0);
            alpha[r] = expf(macc[r] - mnew);
            macc[r] = mnew;
            psum[r] = 0.f;
        }
        #pragma unroll
        for (int t = 0; t < 4; ++t) {
            #pragma unroll
            for (int r = 0; r < 4; ++r) {
                float p = expf(s_acc[t][r] - macc[r]);
                psum[r] += p;
                Pb[(wave * 16 + (lane >> 4) * 4 + r) * LSTR + t * 16 + (lane & 15)] = (f16)p;
            }
        }
        #pragma unroll
        for (int r = 0; r < 4; ++r) {
            float v0 = psum[r];
            #pragma unroll
            for (int off = 1; off < 16; off <<= 1) v0 += __shfl_xor(v0, off);
            lacc[r] = lacc[r] * alpha[r] + v0;
            #pragma unroll
            for (int t = 0; t < 4; ++t) o_acc[t][r] *= alpha[r];
        }

        // ---- PV (Pb rows are wave-private; Vt stable until trailing barrier)
        const f16* VtB = &Vt[bi][0];
        #pragma unroll
        for (int c = 0; c < 2; ++c) {
            f16x8 af = *(const f16x8*)(Pb + arow * LSTR + c * 32 + kofs);
            #pragma unroll
            for (int t = 0; t < 4; ++t) {
                const int vrow = t * 16 + (lane & 15);
                const int voff = (vrow * 128 + c * 64 + colb) ^ ((vrow & 7) << 4);
                f16x8 bf = *(const f16x8*)((const char*)VtB + voff);
                o_acc[t] = __builtin_amdgcn_mfma_f32_16x16x32_f16(af, bf, o_acc[t], 0, 0, 0);
            }
        }
    };

    // ---- pipelined masked loop: diagonal first (staged above), then the
    // remaining set bits ascending. R8 sync structure (1-ahead, vmcnt(4)).
    unsigned int mm = mask & ~(1u << m);
    int cur = 0;
    for (;;) {
        int nb_nxt = -1;
        if (mm) { nb_nxt = __builtin_ctz(mm); mm &= mm - 1; stageKV(cur ^ 1, nb_nxt); }
        if (nb_nxt >= 0) { VM_WAIT4; } else { VM_WAIT0; }
        SBAR; SCHED0;
        computeTile(cur);
        SBAR;
        if (nb_nxt < 0) break;
        cur ^= 1;
    }

    // ---- epilogue: normalize, write single-f16 attn output [4096][1024]
    float inv[4];
    #pragma unroll
    for (int r = 0; r < 4; ++r) inv[r] = (lacc[r] > 0.f) ? (1.f / lacc[r]) : 0.f;
    #pragma unroll
    for (int t = 0; t < 4; ++t) {
        int gc = h * 64 + t * 16 + (lane & 15);
        #pragma unroll
        for (int r = 0; r < 4; ++r) {
            int grow = b * NN + m * 64 + wave * 16 + (lane >> 4) * 4 + r;
            float v = o_acc[t][r] * inv[r];
            aout[(size_t)grow * 1024 + gc] = f16_bits(v);
        }
    }
}

// ===========================================================================
// FALLBACK KERNELS (round-2 proven fp32 path)
// ===========================================================================

__global__ __launch_bounds__(256) void block_mean_kernel(
    const float* __restrict__ qf, const float* __restrict__ kf,
    float* __restrict__ qbf, float* __restrict__ kbf)
{
    int idx = blockIdx.x * 256 + threadIdx.x;
    const float* src = (idx < 65536) ? qf : kf;
    float* dst       = (idx < 65536) ? qbf : kbf;
    int e = idx & 65535;
    int d = e & 63;
    int r = e >> 6;
    size_t base = (size_t)r * 4096 + d;
    float s = 0.f;
    #pragma unroll
    for (int i = 0; i < 64; ++i) s += src[base + (size_t)i * 64];
    dst[e] = s * (1.f / 64.f);
}

__global__ __launch_bounds__(256) void qkv_gemm_fb(
    const float* __restrict__ x, const float* __restrict__ w,
    float* __restrict__ qf, float* __restrict__ kf, float* __restrict__ vf)
{
    __shared__ float As[64][33];
    __shared__ float Bs[64][33];
    const int tid = threadIdx.x;
    const int row0 = blockIdx.y * 64;
    const int col0 = blockIdx.x * 64;
    const int ty = tid >> 4, tx = tid & 15;

    float acc[4][4] = {};
    for (int k0 = 0; k0 < 1024; k0 += 32) {
        #pragma unroll
        for (int i = 0; i < 8; ++i) {
            int e = tid + i * 256;
            int r = e >> 5, c = e & 31;
            As[r][c] = x[(size_t)(row0 + r) * 1024 + k0 + c];
            Bs[r][c] = w[(size_t)(col0 + r) * 1024 + k0 + c];
        }
        __syncthreads();
        #pragma unroll
        for (int kk = 0; kk < 32; ++kk) {
            float a[4], bq[4];
            #pragma unroll
            for (int i = 0; i < 4; ++i) a[i] = As[ty * 4 + i][kk];
            #pragma unroll
            for (int j = 0; j < 4; ++j) bq[j] = Bs[tx * 4 + j][kk];
            #pragma unroll
            for (int i = 0; i < 4; ++i)
                #pragma unroll
                for (int j = 0; j < 4; ++j)
                    acc[i][j] += a[i] * bq[j];
        }
        __syncthreads();
    }

    const int tsel = col0 >> 10;
    const int h    = (col0 & 1023) >> 6;
    float* dstbuf = (tsel == 0) ? qf : (tsel == 1) ? kf : vf;
    #pragma unroll
    for (int i = 0; i < 4; ++i) {
        int row = row0 + ty * 4 + i;
        int b   = row >> 11, n = row & 2047;
        size_t rb = ((size_t)(b * HH + h) * NN + n) * HD64;
        #pragma unroll
        for (int j = 0; j < 4; ++j)
            dstbuf[rb + tx * 4 + j] = acc[i][j];
    }
}

__global__ __launch_bounds__(256) void proj_gemm_fb(
    const float* __restrict__ attn, const float* __restrict__ w,
    const float* __restrict__ bias, float* __restrict__ out)
{
    __shared__ float As[64][33];
    __shared__ float Bs[64][33];
    const int tid = threadIdx.x;
    const int row0 = blockIdx.y * 64;
    const int col0 = blockIdx.x * 64;
    const int ty = tid >> 4, tx = tid & 15;

    float acc[4][4] = {};
    for (int k0 = 0; k0 < 1024; k0 += 32) {
        #pragma unroll
        for (int i = 0; i < 8; ++i) {
            int e = tid + i * 256;
            int r = e >> 5, c = e & 31;
            As[r][c] = attn[(size_t)(row0 + r) * 1024 + k0 + c];
            Bs[r][c] = w[(size_t)(col0 + r) * 1024 + k0 + c];
        }
        __syncthreads();
        #pragma unroll
        for (int kk = 0; kk < 32; ++kk) {
            float a[4], bq[4];
            #pragma unroll
            for (int i = 0; i < 4; ++i) a[i] = As[ty * 4 + i][kk];
            #pragma unroll
            for (int j = 0; j < 4; ++j) bq[j] = Bs[tx * 4 + j][kk];
            #pragma unroll
            for (int i = 0; i < 4; ++i)
                #pragma unroll
                for (int j = 0; j < 4; ++j)
                    acc[i][j] += a[i] * bq[j];
        }
        __syncthreads();
    }

    #pragma unroll
    for (int j = 0; j < 4; ++j) {
        int col = col0 + tx * 4 + j;
        float bv = bias[col];
        #pragma unroll
        for (int i = 0; i < 4; ++i) {
            int row = row0 + ty * 4 + i;
            out[(size_t)row * 1024 + col] = acc[i][j] + bv;
        }
    }
}

__global__ __launch_bounds__(256) void sparse_attn_fb(
    const float* __restrict__ qf, const float* __restrict__ kf,
    const float* __restrict__ vf, const unsigned int* __restrict__ maskbits,
    float* __restrict__ attnf)
{
    __shared__ float kbuf[64][64];
    __shared__ float vbuf[64][64];
    __shared__ float sbuf[64][65];
    const int m  = blockIdx.x & 31;
    const int bh = blockIdx.x >> 5;
    const int b  = bh >> 4, h = bh & 15;
    const int t  = threadIdx.x;
    const int qr = t >> 2;
    const int dg = t & 3;
    const int d0 = dg * 16;

    float qreg[16];
    {
        const float* qp = qf + ((size_t)bh * NN + m * 64 + qr) * HD64 + d0;
        #pragma unroll
        for (int j = 0; j < 16; j += 4) {
            float4 v = *(const float4*)(qp + j);
            qreg[j] = v.x; qreg[j+1] = v.y; qreg[j+2] = v.z; qreg[j+3] = v.w;
        }
    }

    const unsigned int mask = maskbits[bh * 32 + m];
    float macc = -INFINITY, lacc = 0.f;
    float oacc[16];
    #pragma unroll
    for (int j = 0; j < 16; ++j) oacc[j] = 0.f;

    for (int nb = 0; nb < 32; ++nb) {
        if (!((mask >> nb) & 1u)) continue;
        __syncthreads();
        {
            const float* gk = kf + ((size_t)bh * NN + nb * 64) * HD64;
            const float* gv = vf + ((size_t)bh * NN + nb * 64) * HD64;
            #pragma unroll
            for (int i = 0; i < 4; ++i) {
                async_copy16(gk + t * 4 + i * 1024, (char*)kbuf + t * 16 + i * 4096);
                async_copy16(gv + t * 4 + i * 1024, (char*)vbuf + t * 16 + i * 4096);
            }
        }
        __syncthreads();

        float bmax = -INFINITY;
        for (int kk = 0; kk < 64; ++kk) {
            float s = 0.f;
            #pragma unroll
            for (int j = 0; j < 16; ++j) s += qreg[j] * kbuf[kk][d0 + j];
            s += __shfl_xor(s, 1);
            s += __shfl_xor(s, 2);
            s *= SCALE_F;
            if (dg == 0) sbuf[qr][kk] = s;
            bmax = fmaxf(bmax, s);
        }
        float mnew  = fmaxf(macc, bmax);
        float alpha = expf(macc - mnew);
        lacc *= alpha;
        #pragma unroll
        for (int j = 0; j < 16; ++j) oacc[j] *= alpha;
        for (int kk = 0; kk < 64; ++kk) {
            float p = expf(sbuf[qr][kk] - mnew);
            lacc += p;
            #pragma unroll
            for (int j = 0; j < 16; ++j) oacc[j] += p * vbuf[kk][d0 + j];
        }
        macc = mnew;
    }

    float inv = (lacc > 0.f) ? (1.f / lacc) : 0.f;
    size_t orow = ((size_t)(b * NN + m * 64 + qr)) * DIMD + h * 64 + d0;
    #pragma unroll
    for (int j = 0; j < 16; ++j) attnf[orow + j] = oacc[j] * inv;
}

// ---------------------------------------------------------------------------
extern "C" void kernel_launch(void* const* d_in, const int* in_sizes, int n_in,
                              void* d_out, int out_size, void* d_ws, size_t ws_size,
                              hipStream_t stream)
{
    const float* x      = (const float*)d_in[0];
    const float* qkv_w  = (const float*)d_in[1];
    const float* proj_w = (const float*)d_in[2];
    const float* proj_b = (const float*)d_in[3];
    float* out = (float*)d_out;

    // Carve (fast path, ~41 MB):
    //   Qh/Kh/Vt images: 3 x 8 MB f16 tiles [1024 tiles][4096 shorts]
    //   qbf/kbf 512K | mask 4K (fallback only)
    //   Axs 8M f16 [4096][1024] (x-split; reused as attention output)
    //   Wqs 6M f16 [3072][1024] | Wp 2M f16 [1024][1024]
    short* QhI = (short*)d_ws;
    short* KhI = QhI + 4194304;
    short* VtI = KhI + 4194304;
    float* qbf = (float*)(VtI + 4194304);
    float* kbf = qbf + 65536;
    unsigned int* maskb = (unsigned int*)(kbf + 65536);
    short* Axs = (short*)(maskb + 1024);
    short* Wqs = Axs + (size_t)4096 * 1024;
    short* Wp  = Wqs + (size_t)3072 * 1024;
    const size_t need_fast = (size_t)((char*)(Wp + (size_t)1024 * 1024) - (char*)d_ws);

    if (ws_size >= need_fast) {
        split_in_fused_kernel<<<8192, 256, 0, stream>>>(x, Axs, qkv_w, Wqs, proj_w, Wp);
        qkv_mfma_kernel<<<768, 256, 0, stream>>>(Axs, Wqs, QhI, KhI, VtI, qbf, kbf);
        sparse_attn_mfma_kernel<<<1024, 256, 0, stream>>>(QhI, KhI, VtI, qbf, kbf, Axs);
        proj_mfma_kernel<<<512, 256, 0, stream>>>(Axs, Wp, proj_b, out);
    } else {
        float* qf2  = (float*)d_ws;
        float* kf2  = qf2 + 4194304;
        float* vf2  = kf2 + 4194304;
        float* qbf2 = vf2 + 4194304;
        float* kbf2 = qbf2 + 65536;
        unsigned int* maskb2 = (unsigned int*)(kbf2 + 65536);
        float* attnf = (float*)(maskb2 + 1024);
        qkv_gemm_fb<<<dim3(48, 64), 256, 0, stream>>>(x, qkv_w, qf2, kf2, vf2);
        block_mean_kernel<<<512, 256, 0, stream>>>(qf2, kf2, qbf2, kbf2);
        scores_splitw_kernel<<<32, 256, 0, stream>>>(qbf2, kbf2, maskb2, SCALE_F,
                                                     (const float*)nullptr, (short*)nullptr);
        sparse_attn_fb<<<1024, 256, 0, stream>>>(qf2, kf2, vf2, maskb2, attnf);
        proj_gemm_fb<<<dim3(16, 64), 256, 0, stream>>>(attnf, proj_w, proj_b, out);
    }
}

// Round 12
// 154.708 us; speedup vs baseline: 1.6025x; 1.0379x over previous
//
#include <hip/hip_runtime.h>
#include <hip/hip_bf16.h>

// Problem constants (B=2, N=2048, DIM=1024, H=16, HD=64, BS=64, M=32)
#define BB 2
#define NN 2048
#define DIMD 1024
#define HH 16
#define HD64 64
#define MB 32
#define SCALE_F 0.125f   // HD^-0.5

typedef __attribute__((ext_vector_type(8))) short bf16x8;
typedef __attribute__((ext_vector_type(8))) short short8v;
typedef __attribute__((ext_vector_type(4))) float f32x4;
typedef _Float16 f16;
typedef __attribute__((ext_vector_type(8))) _Float16 f16x8;
typedef __attribute__((ext_vector_type(4))) _Float16 f16x4;

#define LSTR 72   // padded LDS row stride (f16) for Pb

// counted-vmcnt barrier discipline (T4) — R8-proven 1-ahead quanta only.
#define VM_WAIT4 asm volatile("s_waitcnt vmcnt(4)" ::: "memory")
#define VM_WAIT3 asm volatile("s_waitcnt vmcnt(3)" ::: "memory")
#define VM_WAIT0 asm volatile("s_waitcnt vmcnt(0)" ::: "memory")
#define SBAR __builtin_amdgcn_s_barrier()
#define SCHED0 __builtin_amdgcn_sched_barrier(0)

__device__ __forceinline__ unsigned short bf16_hi(float f) {
    return __builtin_bit_cast(unsigned short, __float2bfloat16(f));
}
__device__ __forceinline__ float bf16_val(unsigned short u) {
    return __bfloat162float(__builtin_bit_cast(__hip_bfloat16, u));
}
__device__ __forceinline__ short f16_bits(float f) {
    return __builtin_bit_cast(short, (f16)f);
}
__device__ __forceinline__ void async_copy16(const void* g, void* l) {
    __builtin_amdgcn_global_load_lds((const __attribute__((address_space(1))) void*)g,
                                     (__attribute__((address_space(3))) void*)l, 16, 0, 0);
}

// ===========================================================================
// FAST PATH — single-product f16, R8-proven sync structure (2-buf, 1-ahead),
// R11-proven in-kernel mask. R12: swapped-operand QK^T in attn -> per-lane
// softmax (8 shuffles/tile vs 32; P-store 4x ds_write_b64 vs 16x b16).
// ===========================================================================

// Fused input split: [0,4096) x -> Axs; [4096,7168) qkv_w -> Wqs;
// [7168,8192) proj_w -> Wp.  Single-plane f16.
__global__ __launch_bounds__(256) void split_in_fused_kernel(
    const float* __restrict__ x, short* __restrict__ Axs,
    const float* __restrict__ w, short* __restrict__ Wqs,
    const float* __restrict__ pw, short* __restrict__ Wp)
{
    const int bid = blockIdx.x;
    const float* src; short* dst; int idx;
    if (bid < 4096)      { src = x;  dst = Axs; idx = bid * 256 + threadIdx.x; }
    else if (bid < 7168) { src = w;  dst = Wqs; idx = (bid - 4096) * 256 + threadIdx.x; }
    else                 { src = pw; dst = Wp;  idx = (bid - 7168) * 256 + threadIdx.x; }
    int e = idx * 4;
    float4 v = *(const float4*)(src + e);
    ushort4 o = make_ushort4((unsigned short)f16_bits(v.x), (unsigned short)f16_bits(v.y),
                             (unsigned short)f16_bits(v.z), (unsigned short)f16_bits(v.w));
    *(ushort4*)(dst + e) = o;
}

// QKV GEMM, f16 single-product — R8 VERBATIM (2-buf, 1-ahead, vmcnt(4)).
// Epilogue writes producer-formatted f16 images + fused block-mean.
__global__ __launch_bounds__(256) void qkv_mfma_kernel(
    const short* __restrict__ A, const short* __restrict__ W,
    short* __restrict__ QhI, short* __restrict__ KhI, short* __restrict__ VtI,
    float* __restrict__ qbf, float* __restrict__ kbf)
{
    __shared__ short SM[16640];   // 2 planes x 2 bufs x 4096 (+ V-transpose tail)
    const int wg = blockIdx.x;
    const int row0 = (wg / 24) * 128;
    const int col0 = (wg % 24) * 128;
    const int tid = threadIdx.x;
    const int lane = tid & 63;
    const int wave = tid >> 6;
    const int wm = wave & 1, wn = wave >> 1;

    auto AHS = [&](int b) { return SM + b * 4096; };
    auto WHS = [&](int b) { return SM + 8192 + b * 4096; };

    f32x4 acc[4][4];
    const f32x4 zero = {0.f, 0.f, 0.f, 0.f};
    #pragma unroll
    for (int i = 0; i < 4; ++i)
        #pragma unroll
        for (int j = 0; j < 4; ++j) acc[i][j] = zero;

    const int ldr = lane >> 2;                              // row in 16-row chunk
    const int lko = (((lane & 3) ^ ((lane >> 3) & 3))) * 8; // swizzled k-chunk
    const int rsl = ((lane >> 4) ^ ((lane >> 1) & 3)) * 8;  // frag-read slot

    // 4 global_load_lds per wave per call (the vmcnt quantum)
    auto stage = [&](int bufi, int ktn) {
        const int kk = ktn << 5;
        #pragma unroll
        for (int i = 0; i < 2; ++i) {
            const int chunk = wave * 2 + i;
            const short* gA = A + (size_t)(row0 + chunk * 16 + ldr) * 1024 + kk + lko;
            const short* gW = W + (size_t)(col0 + chunk * 16 + ldr) * 1024 + kk + lko;
            async_copy16(gA, (char*)AHS(bufi) + chunk * 1024);
            async_copy16(gW, (char*)WHS(bufi) + chunk * 1024);
        }
    };

    auto compute = [&](int bufi) {
        const short* Ah = AHS(bufi);
        const short* Wh = WHS(bufi);
        f16x8 ah[4], wh[4];
        #pragma unroll
        for (int mi = 0; mi < 4; ++mi)
            ah[mi] = *(const f16x8*)(Ah + (wm * 64 + mi * 16 + (lane & 15)) * 32 + rsl);
        #pragma unroll
        for (int ni = 0; ni < 4; ++ni)
            wh[ni] = *(const f16x8*)(Wh + (wn * 64 + ni * 16 + (lane & 15)) * 32 + rsl);
        #pragma unroll
        for (int mi = 0; mi < 4; ++mi)
            #pragma unroll
            for (int ni = 0; ni < 4; ++ni)
                acc[mi][ni] = __builtin_amdgcn_mfma_f32_16x16x32_f16(ah[mi], wh[ni], acc[mi][ni], 0, 0, 0);
    };

    stage(0, 0);
    for (int kt = 0; kt < 30; kt += 2) {
        stage(1, kt + 1);
        VM_WAIT4; SBAR; SCHED0;
        compute(0);
        SBAR;
        stage(0, kt + 2);
        VM_WAIT4; SBAR; SCHED0;
        compute(1);
        SBAR;
    }
    stage(1, 31);
    VM_WAIT4; SBAR; SCHED0;
    compute(0);
    SBAR;
    VM_WAIT0; SBAR; SCHED0;
    compute(1);
    SBAR;   // protect LDS reuse by V-wave transpose below

    // ---- epilogue: write f16 image tiles (+ fused block-mean for q/k)
    const int gr_first = row0 + wm * 64;          // wave's 64-row token block
    const int bb = gr_first >> 11;
    const int mblk = (gr_first & 2047) >> 6;
    const int gc0 = col0 + wn * 64;               // wave's 64-col band (one head)
    const int tsel = gc0 >> 10;
    const int h = (gc0 >> 6) & 15;
    const int tile = ((bb << 4) + h) * 32 + mblk;
    const float sc = (tsel == 0) ? SCALE_F : 1.0f;

    if (tsel != 2) {
        short* baseH = ((tsel == 0) ? QhI : KhI) + (size_t)tile * 4096;
        float* mdst  = ((tsel == 0) ? qbf : kbf) + ((size_t)((bb << 4) + h) * 32 + mblk) * 64;
        #pragma unroll
        for (int ni = 0; ni < 4; ++ni) {
            const int d = ni * 16 + (lane & 15);
            float colsum = 0.f;
            #pragma unroll
            for (int mi = 0; mi < 4; ++mi) {
                #pragma unroll
                for (int r = 0; r < 4; ++r) {
                    const int row = mi * 16 + (lane >> 4) * 4 + r;
                    float v = acc[mi][ni][r] * sc;
                    colsum += v;
                    const int off = (row * 64 + d) ^ ((row & 7) << 3);   // shorts
                    baseH[off] = f16_bits(v);
                }
            }
            colsum += __shfl_xor(colsum, 16);
            colsum += __shfl_xor(colsum, 32);
            if ((lane >> 4) == 0) mdst[d] = colsum * (1.f / 64.f);
        }
    } else {
        // V: transpose 64x64 tile in per-wave LDS region, write Vt[d][kk] image
        short* tb = SM + wave * 4160;   // 64x65 shorts, per-wave exclusive
        #pragma unroll
        for (int ni = 0; ni < 4; ++ni)
            #pragma unroll
            for (int mi = 0; mi < 4; ++mi)
                #pragma unroll
                for (int r = 0; r < 4; ++r) {
                    const int row = mi * 16 + (lane >> 4) * 4 + r;   // kk
                    const int d = ni * 16 + (lane & 15);
                    tb[row * 65 + d] = f16_bits(acc[mi][ni][r]);
                }
        short* vout = VtI + (size_t)tile * 4096;
        #pragma unroll
        for (int c = 0; c < 8; ++c) {
            short8v tv;
            #pragma unroll
            for (int j = 0; j < 8; ++j)
                tv[j] = tb[(c * 8 + j) * 65 + lane];
            const int off = (lane * 64 + c * 8) ^ ((lane & 7) << 3);   // shorts
            *(short8v*)(vout + off) = tv;
        }
    }
}

// Block-scores + top-2 mask (FALLBACK PATH ONLY).
__global__ __launch_bounds__(256) void scores_splitw_kernel(
    const float* __restrict__ qbf, const float* __restrict__ kbf,
    unsigned int* __restrict__ maskbits, float scale,
    const float* __restrict__ projw, short* __restrict__ Wdst)
{
    __shared__ float qs_[32][64];
    __shared__ float ks_[32][64];
    __shared__ float cb[32][32];
    const int bid = blockIdx.x;
    const int tid = threadIdx.x;

    if (bid >= 32) {
        int idx = (bid - 32) * 256 + tid;
        int e = idx * 4;
        float4 v = *(const float4*)(projw + e);
        ushort4 o = make_ushort4((unsigned short)f16_bits(v.x), (unsigned short)f16_bits(v.y),
                                 (unsigned short)f16_bits(v.z), (unsigned short)f16_bits(v.w));
        *(ushort4*)(Wdst + e) = o;
        return;
    }

    #pragma unroll
    for (int i = 0; i < 8; ++i) {
        int e = tid + i * 256;
        qs_[e >> 6][e & 63] = qbf[(size_t)bid * 2048 + e];
        ks_[e >> 6][e & 63] = kbf[(size_t)bid * 2048 + e];
    }
    __syncthreads();

    #pragma unroll
    for (int i = 0; i < 4; ++i) {
        int idx = tid + i * 256;
        int r = idx >> 5, c = idx & 31;
        float s = 0.f;
        #pragma unroll
        for (int d = 0; d < 64; ++d) s += qs_[r][d] * ks_[c][d];
        cb[r][c] = s * scale;
    }
    __syncthreads();

    if (tid < 32) {
        float m1 = -INFINITY, m2 = -INFINITY;
        for (int n = 0; n < 32; ++n) {
            float v = cb[tid][n];
            if (v > m1) { m2 = m1; m1 = v; }
            else if (v > m2) { m2 = v; }
        }
        unsigned int bits = 1u << tid;
        for (int n = 0; n < 32; ++n)
            if (cb[tid][n] >= m2) bits |= 1u << n;
        maskbits[bid * 32 + tid] = bits;
    }
}

// Proj GEMM, f16 single-product + bias — R8 VERBATIM (2-buf, vmcnt(3)).
__global__ __launch_bounds__(256) void proj_mfma_kernel(
    const short* __restrict__ A, const short* __restrict__ W,
    const float* __restrict__ bias, float* __restrict__ out)
{
    __shared__ short Ahs[2][128 * 32];
    __shared__ short Whs[2][64 * 32];
    const int bid = blockIdx.x;
    const int wg = (bid & 7) * 64 + (bid >> 3);   // bijective (512 % 8 == 0)
    const int row0 = (wg >> 4) * 128;
    const int col0 = (wg & 15) * 64;
    const int tid = threadIdx.x;
    const int lane = tid & 63;
    const int wave = tid >> 6;

    f32x4 acc[2][4];
    const f32x4 zero = {0.f, 0.f, 0.f, 0.f};
    #pragma unroll
    for (int i = 0; i < 2; ++i)
        #pragma unroll
        for (int j = 0; j < 4; ++j) acc[i][j] = zero;

    const int ldr = lane >> 2;
    const int lko = (((lane & 3) ^ ((lane >> 3) & 3))) * 8;
    const int rsl = ((lane >> 4) ^ ((lane >> 1) & 3)) * 8;

    // 3 global_load_lds per wave per call
    auto stage = [&](int bufi, int ktn) {
        const int kk = ktn << 5;
        #pragma unroll
        for (int i = 0; i < 2; ++i) {
            const int chunk = wave * 2 + i;
            const short* gA = A + (size_t)(row0 + chunk * 16 + ldr) * 1024 + kk + lko;
            async_copy16(gA, (char*)&Ahs[bufi][0] + chunk * 1024);
        }
        {
            const short* gW = W + (size_t)(col0 + wave * 16 + ldr) * 1024 + kk + lko;
            async_copy16(gW, (char*)&Whs[bufi][0] + wave * 1024);
        }
    };

    auto compute = [&](int bufi) {
        const short* Ah = Ahs[bufi];
        const short* Wh = Whs[bufi];
        f16x8 ah[2], wh[4];
        #pragma unroll
        for (int mi = 0; mi < 2; ++mi)
            ah[mi] = *(const f16x8*)(Ah + (wave * 32 + mi * 16 + (lane & 15)) * 32 + rsl);
        #pragma unroll
        for (int ni = 0; ni < 4; ++ni)
            wh[ni] = *(const f16x8*)(Wh + (ni * 16 + (lane & 15)) * 32 + rsl);
        #pragma unroll
        for (int mi = 0; mi < 2; ++mi)
            #pragma unroll
            for (int ni = 0; ni < 4; ++ni)
                acc[mi][ni] = __builtin_amdgcn_mfma_f32_16x16x32_f16(ah[mi], wh[ni], acc[mi][ni], 0, 0, 0);
    };

    stage(0, 0);
    for (int kt = 0; kt < 30; kt += 2) {
        stage(1, kt + 1);
        VM_WAIT3; SBAR; SCHED0;
        compute(0);
        SBAR;
        stage(0, kt + 2);
        VM_WAIT3; SBAR; SCHED0;
        compute(1);
        SBAR;
    }
    stage(1, 31);
    VM_WAIT3; SBAR; SCHED0;
    compute(0);
    SBAR;
    VM_WAIT0; SBAR; SCHED0;
    compute(1);

    #pragma unroll
    for (int ni = 0; ni < 4; ++ni) {
        int gc = col0 + ni * 16 + (lane & 15);
        float bv = bias[gc];
        #pragma unroll
        for (int mi = 0; mi < 2; ++mi) {
            int gr0 = row0 + wave * 32 + mi * 16 + (lane >> 4) * 4;
            #pragma unroll
            for (int r = 0; r < 4; ++r)
                out[(size_t)(gr0 + r) * 1024 + gc] = acc[mi][ni][r] + bv;
        }
    }
}

// ---------------------------------------------------------------------------
// Sparse block attention — R11 core + R12 swapped-operand QK^T.
// mfma(K_frag, Q_frag): lane owns ONE q-row (col=lane&15), its 16 k-values in
// regs, remaining 48 in lanes differing in bits 4-5. Softmax: in-register max
// tree + 2 shfl (was 16), psum + 2 shfl, alpha broadcast 4 shfl. P-store:
// 4x ds_write_b64 (consecutive k) vs 16x ds_write_b16. PV/Pb/mask unchanged.
// ---------------------------------------------------------------------------
__global__ __launch_bounds__(256) void sparse_attn_mfma_kernel(
    const short* __restrict__ QhI, const short* __restrict__ KhI,
    const short* __restrict__ VtI,
    const float* __restrict__ qbf, const float* __restrict__ kbf,
    short* __restrict__ aout)
{
    __shared__ f16 Qh[4096];                  // [64][64] swizzled
    __shared__ f16 Kh[2][4096];               // dbuf
    __shared__ f16 Vt[2][4096];               // dbuf, [d][kk] swizzled
    __shared__ f16 Pb[64 * LSTR];             // P[q][kk], wave-private rows

    const int bid = blockIdx.x;
    const int wg = (bid & 7) * 128 + (bid >> 3);  // bijective (1024 % 8 == 0)
    const int m  = wg & 31;
    const int bh = wg >> 5;
    const int b  = bh >> 4, h = bh & 15;
    const int tid = threadIdx.x;
    const int lane = tid & 63;
    const int wave = tid >> 6;
    const f32x4 zero = {0.f, 0.f, 0.f, 0.f};

    // ---- stage Q (once): 2 issues/wave
    {
        const size_t qt = (size_t)(bh * 32 + m) * 4096;
        const int so = wave * 1024 + lane * 8;
        async_copy16(QhI + qt + so,       (char*)Qh + wave * 2048);
        async_copy16(QhI + qt + so + 512, (char*)Qh + wave * 2048 + 1024);
    }

    // ---- K/V tile stage: 4 issues/wave (the vmcnt quantum)
    auto stageKV = [&](int bufi, int nb) {
        const size_t t4 = (size_t)(bh * 32 + nb) * 4096;
        const int so = wave * 1024 + lane * 8;
        async_copy16(KhI + t4 + so,       (char*)&Kh[bufi][0] + wave * 2048);
        async_copy16(KhI + t4 + so + 512, (char*)&Kh[bufi][0] + wave * 2048 + 1024);
        async_copy16(VtI + t4 + so,       (char*)&Vt[bufi][0] + wave * 2048);
        async_copy16(VtI + t4 + so + 512, (char*)&Vt[bufi][0] + wave * 2048 + 1024);
    };

    // ---- diagonal tile is ALWAYS in the mask: stage it before the mask calc
    stageKV(0, m);

    // ---- in-kernel mask (R11-proven; FP order == old scores kernel)
    unsigned int mask;
    {
        float c = -INFINITY;
        if (lane < 32) {
            const float* qrow = qbf + ((size_t)bh * 32 + m) * 64;
            const float* krow = kbf + ((size_t)bh * 32 + lane) * 64;
            float s = 0.f;
            for (int d = 0; d < 64; ++d) s += qrow[d] * krow[d];
            c = s;
        }
        float m1 = c;
        #pragma unroll
        for (int off = 1; off < 64; off <<= 1) m1 = fmaxf(m1, __shfl_xor(m1, off));
        unsigned long long eq = __ballot(c == m1);
        float cx = (c == m1) ? -INFINITY : c;
        #pragma unroll
        for (int off = 1; off < 64; off <<= 1) cx = fmaxf(cx, __shfl_xor(cx, off));
        float m2 = (__popcll(eq) >= 2) ? m1 : cx;
        unsigned long long ge = __ballot(c >= m2);
        mask = (unsigned int)(ge & 0xffffffffULL) | (1u << m);
    }

    f32x4 o_acc[4];
    float macc_s = -INFINITY, lacc_s = 0.f;   // per-lane: q = wave*16+(lane&15)
    #pragma unroll
    for (int t = 0; t < 4; ++t) o_acc[t] = zero;

    const int arow = wave * 16 + (lane & 15);
    const int kofs = (lane >> 4) * 8;      // shorts (for Pb)
    const int colb = (lane >> 4) * 16;     // bytes (for swizzled images)

    auto computeTile = [&](int bi) {
        const f16* KhB = &Kh[bi][0];
        // ---- QK^T, SWAPPED operands: mfma(K, Q) -> D[k_local][q]
        // lane holds col=lane&15 = q, rows (lane>>4)*4+r (+16t) = k.
        f32x4 s_acc[4];
        #pragma unroll
        for (int t = 0; t < 4; ++t) s_acc[t] = zero;
        #pragma unroll
        for (int c = 0; c < 2; ++c) {
            const int qoff = (arow * 128 + c * 64 + colb) ^ ((arow & 7) << 4);
            f16x8 ah = *(const f16x8*)((const char*)Qh + qoff);
            #pragma unroll
            for (int t = 0; t < 4; ++t) {
                const int krow = t * 16 + (lane & 15);
                const int koff = (krow * 128 + c * 64 + colb) ^ ((krow & 7) << 4);
                f16x8 bh_ = *(const f16x8*)((const char*)KhB + koff);
                s_acc[t] = __builtin_amdgcn_mfma_f32_16x16x32_f16(bh_, ah, s_acc[t], 0, 0, 0);
            }
        }

        // ---- per-lane online softmax (q = arow)
        float vmax = s_acc[0][0];
        #pragma unroll
        for (int t = 0; t < 4; ++t)
            #pragma unroll
            for (int r = 0; r < 4; ++r) vmax = fmaxf(vmax, s_acc[t][r]);
        vmax = fmaxf(vmax, __shfl_xor(vmax, 16));
        vmax = fmaxf(vmax, __shfl_xor(vmax, 32));
        float mnew = fmaxf(macc_s, vmax);
        float alpha = expf(macc_s - mnew);
        macc_s = mnew;

        float psum = 0.f;
        #pragma unroll
        for (int t = 0; t < 4; ++t) {
            f16x4 pv;
            #pragma unroll
            for (int r = 0; r < 4; ++r) {
                float p = expf(s_acc[t][r] - mnew);
                psum += p;
                pv[r] = (f16)p;
            }
            // k = t*16 + (lane>>4)*4 + r  (consecutive r) -> packed 8B store
            *(f16x4*)(Pb + arow * LSTR + t * 16 + (lane >> 4) * 4) = pv;
        }
        psum += __shfl_xor(psum, 16);
        psum += __shfl_xor(psum, 32);
        lacc_s = lacc_s * alpha + psum;

        // broadcast alpha to o_acc's q-row mapping (row=(lane>>4)*4+r)
        float ab[4];
        #pragma unroll
        for (int r = 0; r < 4; ++r) ab[r] = __shfl(alpha, (lane >> 4) * 4 + r);
        #pragma unroll
        for (int t = 0; t < 4; ++t)
            #pragma unroll
            for (int r = 0; r < 4; ++r) o_acc[t][r] *= ab[r];

        // ---- PV (unchanged; Pb rows wave-private)
        const f16* VtB = &Vt[bi][0];
        #pragma unroll
        for (int c = 0; c < 2; ++c) {
            f16x8 af = *(const f16x8*)(Pb + arow * LSTR + c * 32 + kofs);
            #pragma unroll
            for (int t = 0; t < 4; ++t) {
                const int vrow = t * 16 + (lane & 15);
                const int voff = (vrow * 128 + c * 64 + colb) ^ ((vrow & 7) << 4);
                f16x8 bf = *(const f16x8*)((const char*)VtB + voff);
                o_acc[t] = __builtin_amdgcn_mfma_f32_16x16x32_f16(af, bf, o_acc[t], 0, 0, 0);
            }
        }
    };

    // ---- pipelined masked loop: diagonal first (staged above), then the
    // remaining set bits ascending. R8 sync structure (1-ahead, vmcnt(4)).
    unsigned int mm = mask & ~(1u << m);
    int cur = 0;
    for (;;) {
        int nb_nxt = -1;
        if (mm) { nb_nxt = __builtin_ctz(mm); mm &= mm - 1; stageKV(cur ^ 1, nb_nxt); }
        if (nb_nxt >= 0) { VM_WAIT4; } else { VM_WAIT0; }
        SBAR; SCHED0;
        computeTile(cur);
        SBAR;
        if (nb_nxt < 0) break;
        cur ^= 1;
    }

    // ---- epilogue: normalize (broadcast inv to o_acc rows), write f16 out
    float inv_s = (lacc_s > 0.f) ? (1.f / lacc_s) : 0.f;
    float invb[4];
    #pragma unroll
    for (int r = 0; r < 4; ++r) invb[r] = __shfl(inv_s, (lane >> 4) * 4 + r);
    #pragma unroll
    for (int t = 0; t < 4; ++t) {
        int gc = h * 64 + t * 16 + (lane & 15);
        #pragma unroll
        for (int r = 0; r < 4; ++r) {
            int grow = b * NN + m * 64 + wave * 16 + (lane >> 4) * 4 + r;
            float v = o_acc[t][r] * invb[r];
            aout[(size_t)grow * 1024 + gc] = f16_bits(v);
        }
    }
}

// ===========================================================================
// FALLBACK KERNELS (round-2 proven fp32 path)
// ===========================================================================

__global__ __launch_bounds__(256) void block_mean_kernel(
    const float* __restrict__ qf, const float* __restrict__ kf,
    float* __restrict__ qbf, float* __restrict__ kbf)
{
    int idx = blockIdx.x * 256 + threadIdx.x;
    const float* src = (idx < 65536) ? qf : kf;
    float* dst       = (idx < 65536) ? qbf : kbf;
    int e = idx & 65535;
    int d = e & 63;
    int r = e >> 6;
    size_t base = (size_t)r * 4096 + d;
    float s = 0.f;
    #pragma unroll
    for (int i = 0; i < 64; ++i) s += src[base + (size_t)i * 64];
    dst[e] = s * (1.f / 64.f);
}

__global__ __launch_bounds__(256) void qkv_gemm_fb(
    const float* __restrict__ x, const float* __restrict__ w,
    float* __restrict__ qf, float* __restrict__ kf, float* __restrict__ vf)
{
    __shared__ float As[64][33];
    __shared__ float Bs[64][33];
    const int tid = threadIdx.x;
    const int row0 = blockIdx.y * 64;
    const int col0 = blockIdx.x * 64;
    const int ty = tid >> 4, tx = tid & 15;

    float acc[4][4] = {};
    for (int k0 = 0; k0 < 1024; k0 += 32) {
        #pragma unroll
        for (int i = 0; i < 8; ++i) {
            int e = tid + i * 256;
            int r = e >> 5, c = e & 31;
            As[r][c] = x[(size_t)(row0 + r) * 1024 + k0 + c];
            Bs[r][c] = w[(size_t)(col0 + r) * 1024 + k0 + c];
        }
        __syncthreads();
        #pragma unroll
        for (int kk = 0; kk < 32; ++kk) {
            float a[4], bq[4];
            #pragma unroll
            for (int i = 0; i < 4; ++i) a[i] = As[ty * 4 + i][kk];
            #pragma unroll
            for (int j = 0; j < 4; ++j) bq[j] = Bs[tx * 4 + j][kk];
            #pragma unroll
            for (int i = 0; i < 4; ++i)
                #pragma unroll
                for (int j = 0; j < 4; ++j)
                    acc[i][j] += a[i] * bq[j];
        }
        __syncthreads();
    }

    const int tsel = col0 >> 10;
    const int h    = (col0 & 1023) >> 6;
    float* dstbuf = (tsel == 0) ? qf : (tsel == 1) ? kf : vf;
    #pragma unroll
    for (int i = 0; i < 4; ++i) {
        int row = row0 + ty * 4 + i;
        int b   = row >> 11, n = row & 2047;
        size_t rb = ((size_t)(b * HH + h) * NN + n) * HD64;
        #pragma unroll
        for (int j = 0; j < 4; ++j)
            dstbuf[rb + tx * 4 + j] = acc[i][j];
    }
}

__global__ __launch_bounds__(256) void proj_gemm_fb(
    const float* __restrict__ attn, const float* __restrict__ w,
    const float* __restrict__ bias, float* __restrict__ out)
{
    __shared__ float As[64][33];
    __shared__ float Bs[64][33];
    const int tid = threadIdx.x;
    const int row0 = blockIdx.y * 64;
    const int col0 = blockIdx.x * 64;
    const int ty = tid >> 4, tx = tid & 15;

    float acc[4][4] = {};
    for (int k0 = 0; k0 < 1024; k0 += 32) {
        #pragma unroll
        for (int i = 0; i < 8; ++i) {
            int e = tid + i * 256;
            int r = e >> 5, c = e & 31;
            As[r][c] = attn[(size_t)(row0 + r) * 1024 + k0 + c];
            Bs[r][c] = w[(size_t)(col0 + r) * 1024 + k0 + c];
        }
        __syncthreads();
        #pragma unroll
        for (int kk = 0; kk < 32; ++kk) {
            float a[4], bq[4];
            #pragma unroll
            for (int i = 0; i < 4; ++i) a[i] = As[ty * 4 + i][kk];
            #pragma unroll
            for (int j = 0; j < 4; ++j) bq[j] = Bs[tx * 4 + j][kk];
            #pragma unroll
            for (int i = 0; i < 4; ++i)
                #pragma unroll
                for (int j = 0; j < 4; ++j)
                    acc[i][j] += a[i] * bq[j];
        }
        __syncthreads();
    }

    #pragma unroll
    for (int j = 0; j < 4; ++j) {
        int col = col0 + tx * 4 + j;
        float bv = bias[col];
        #pragma unroll
        for (int i = 0; i < 4; ++i) {
            int row = row0 + ty * 4 + i;
            out[(size_t)row * 1024 + col] = acc[i][j] + bv;
        }
    }
}

__global__ __launch_bounds__(256) void sparse_attn_fb(
    const float* __restrict__ qf, const float* __restrict__ kf,
    const float* __restrict__ vf, const unsigned int* __restrict__ maskbits,
    float* __restrict__ attnf)
{
    __shared__ float kbuf[64][64];
    __shared__ float vbuf[64][64];
    __shared__ float sbuf[64][65];
    const int m  = blockIdx.x & 31;
    const int bh = blockIdx.x >> 5;
    const int b  = bh >> 4, h = bh & 15;
    const int t  = threadIdx.x;
    const int qr = t >> 2;
    const int dg = t & 3;
    const int d0 = dg * 16;

    float qreg[16];
    {
        const float* qp = qf + ((size_t)bh * NN + m * 64 + qr) * HD64 + d0;
        #pragma unroll
        for (int j = 0; j < 16; j += 4) {
            float4 v = *(const float4*)(qp + j);
            qreg[j] = v.x; qreg[j+1] = v.y; qreg[j+2] = v.z; qreg[j+3] = v.w;
        }
    }

    const unsigned int mask = maskbits[bh * 32 + m];
    float macc = -INFINITY, lacc = 0.f;
    float oacc[16];
    #pragma unroll
    for (int j = 0; j < 16; ++j) oacc[j] = 0.f;

    for (int nb = 0; nb < 32; ++nb) {
        if (!((mask >> nb) & 1u)) continue;
        __syncthreads();
        {
            const float* gk = kf + ((size_t)bh * NN + nb * 64) * HD64;
            const float* gv = vf + ((size_t)bh * NN + nb * 64) * HD64;
            #pragma unroll
            for (int i = 0; i < 4; ++i) {
                async_copy16(gk + t * 4 + i * 1024, (char*)kbuf + t * 16 + i * 4096);
                async_copy16(gv + t * 4 + i * 1024, (char*)vbuf + t * 16 + i * 4096);
            }
        }
        __syncthreads();

        float bmax = -INFINITY;
        for (int kk = 0; kk < 64; ++kk) {
            float s = 0.f;
            #pragma unroll
            for (int j = 0; j < 16; ++j) s += qreg[j] * kbuf[kk][d0 + j];
            s += __shfl_xor(s, 1);
            s += __shfl_xor(s, 2);
            s *= SCALE_F;
            if (dg == 0) sbuf[qr][kk] = s;
            bmax = fmaxf(bmax, s);
        }
        float mnew  = fmaxf(macc, bmax);
        float alpha = expf(macc - mnew);
        lacc *= alpha;
        #pragma unroll
        for (int j = 0; j < 16; ++j) oacc[j] *= alpha;
        for (int kk = 0; kk < 64; ++kk) {
            float p = expf(sbuf[qr][kk] - mnew);
            lacc += p;
            #pragma unroll
            for (int j = 0; j < 16; ++j) oacc[j] += p * vbuf[kk][d0 + j];
        }
        macc = mnew;
    }

    float inv = (lacc > 0.f) ? (1.f / lacc) : 0.f;
    size_t orow = ((size_t)(b * NN + m * 64 + qr)) * DIMD + h * 64 + d0;
    #pragma unroll
    for (int j = 0; j < 16; ++j) attnf[orow + j] = oacc[j] * inv;
}

// ---------------------------------------------------------------------------
extern "C" void kernel_launch(void* const* d_in, const int* in_sizes, int n_in,
                              void* d_out, int out_size, void* d_ws, size_t ws_size,
                              hipStream_t stream)
{
    const float* x      = (const float*)d_in[0];
    const float* qkv_w  = (const float*)d_in[1];
    const float* proj_w = (const float*)d_in[2];
    const float* proj_b = (const float*)d_in[3];
    float* out = (float*)d_out;

    // Carve (fast path, ~41 MB):
    //   Qh/Kh/Vt images: 3 x 8 MB f16 tiles [1024 tiles][4096 shorts]
    //   qbf/kbf 512K | mask 4K (fallback only)
    //   Axs 8M f16 [4096][1024] (x-split; reused as attention output)
    //   Wqs 6M f16 [3072][1024] | Wp 2M f16 [1024][1024]
    short* QhI = (short*)d_ws;
    short* KhI = QhI + 4194304;
    short* VtI = KhI + 4194304;
    float* qbf = (float*)(VtI + 4194304);
    float* kbf = qbf + 65536;
    unsigned int* maskb = (unsigned int*)(kbf + 65536);
    short* Axs = (short*)(maskb + 1024);
    short* Wqs = Axs + (size_t)4096 * 1024;
    short* Wp  = Wqs + (size_t)3072 * 1024;
    const size_t need_fast = (size_t)((char*)(Wp + (size_t)1024 * 1024) - (char*)d_ws);

    if (ws_size >= need_fast) {
        split_in_fused_kernel<<<8192, 256, 0, stream>>>(x, Axs, qkv_w, Wqs, proj_w, Wp);
        qkv_mfma_kernel<<<768, 256, 0, stream>>>(Axs, Wqs, QhI, KhI, VtI, qbf, kbf);
        sparse_attn_mfma_kernel<<<1024, 256, 0, stream>>>(QhI, KhI, VtI, qbf, kbf, Axs);
        proj_mfma_kernel<<<512, 256, 0, stream>>>(Axs, Wp, proj_b, out);
    } else {
        float* qf2  = (float*)d_ws;
        float* kf2  = qf2 + 4194304;
        float* vf2  = kf2 + 4194304;
        float* qbf2 = vf2 + 4194304;
        float* kbf2 = qbf2 + 65536;
        unsigned int* maskb2 = (unsigned int*)(kbf2 + 65536);
        float* attnf = (float*)(maskb2 + 1024);
        qkv_gemm_fb<<<dim3(48, 64), 256, 0, stream>>>(x, qkv_w, qf2, kf2, vf2);
        block_mean_kernel<<<512, 256, 0, stream>>>(qf2, kf2, qbf2, kbf2);
        scores_splitw_kernel<<<32, 256, 0, stream>>>(qbf2, kbf2, maskb2, SCALE_F,
                                                     (const float*)nullptr, (short*)nullptr);
        sparse_attn_fb<<<1024, 256, 0, stream>>>(qf2, kf2, vf2, maskb2, attnf);
        proj_gemm_fb<<<dim3(16, 64), 256, 0, stream>>>(attnf, proj_w, proj_b, out);
    }
}

// Round 13
// 150.132 us; speedup vs baseline: 1.6513x; 1.0305x over previous
//
#include <hip/hip_runtime.h>
#include <hip/hip_bf16.h>

// Problem constants (B=2, N=2048, DIM=1024, H=16, HD=64, BS=64, M=32)
#define BB 2
#define NN 2048
#define DIMD 1024
#define HH 16
#define HD64 64
#define MB 32
#define SCALE_F 0.125f   // HD^-0.5

typedef __attribute__((ext_vector_type(8))) short bf16x8;
typedef __attribute__((ext_vector_type(8))) short short8v;
typedef __attribute__((ext_vector_type(4))) float f32x4;
typedef _Float16 f16;
typedef __attribute__((ext_vector_type(8))) _Float16 f16x8;
typedef __attribute__((ext_vector_type(4))) _Float16 f16x4;

#define LSTR 72   // padded LDS row stride (f16) for Pb

// counted-vmcnt barrier discipline (T4) — 2-buf 1-ahead, proven quanta:
// vmcnt(8) = R4-R7 qkv; vmcnt(6) = R4-R7 proj; vmcnt(4)/(3) = R8.
#define VM_WAIT8 asm volatile("s_waitcnt vmcnt(8)" ::: "memory")
#define VM_WAIT6 asm volatile("s_waitcnt vmcnt(6)" ::: "memory")
#define VM_WAIT4 asm volatile("s_waitcnt vmcnt(4)" ::: "memory")
#define VM_WAIT3 asm volatile("s_waitcnt vmcnt(3)" ::: "memory")
#define VM_WAIT0 asm volatile("s_waitcnt vmcnt(0)" ::: "memory")
#define SBAR __builtin_amdgcn_s_barrier()
#define SCHED0 __builtin_amdgcn_sched_barrier(0)

__device__ __forceinline__ unsigned short bf16_hi(float f) {
    return __builtin_bit_cast(unsigned short, __float2bfloat16(f));
}
__device__ __forceinline__ float bf16_val(unsigned short u) {
    return __bfloat162float(__builtin_bit_cast(__hip_bfloat16, u));
}
__device__ __forceinline__ short f16_bits(float f) {
    return __builtin_bit_cast(short, (f16)f);
}
__device__ __forceinline__ void async_copy16(const void* g, void* l) {
    __builtin_amdgcn_global_load_lds((const __attribute__((address_space(1))) void*)g,
                                     (__attribute__((address_space(3))) void*)l, 16, 0, 0);
}

// ===========================================================================
// FAST PATH — single-product f16 (R8), in-kernel mask (R11), swapped-operand
// softmax (R12). R13: BK=64 in qkv/proj — two 32-k sub-planes staged per
// barrier pair (identical per-lane addressing), 32/16 MFMA per pair (2x),
// barrier count halved. Sync = proven 2-buf 1-ahead vmcnt(8)/vmcnt(6).
// ===========================================================================

// Fused input split: [0,4096) x -> Axs; [4096,7168) qkv_w -> Wqs;
// [7168,8192) proj_w -> Wp.  Single-plane f16.
__global__ __launch_bounds__(256) void split_in_fused_kernel(
    const float* __restrict__ x, short* __restrict__ Axs,
    const float* __restrict__ w, short* __restrict__ Wqs,
    const float* __restrict__ pw, short* __restrict__ Wp)
{
    const int bid = blockIdx.x;
    const float* src; short* dst; int idx;
    if (bid < 4096)      { src = x;  dst = Axs; idx = bid * 256 + threadIdx.x; }
    else if (bid < 7168) { src = w;  dst = Wqs; idx = (bid - 4096) * 256 + threadIdx.x; }
    else                 { src = pw; dst = Wp;  idx = (bid - 7168) * 256 + threadIdx.x; }
    int e = idx * 4;
    float4 v = *(const float4*)(src + e);
    ushort4 o = make_ushort4((unsigned short)f16_bits(v.x), (unsigned short)f16_bits(v.y),
                             (unsigned short)f16_bits(v.z), (unsigned short)f16_bits(v.w));
    *(ushort4*)(dst + e) = o;
}

// QKV GEMM, f16 single-product. R13: BK=64 (16 k-steps), 8 loads/wave/step,
// vmcnt(8), 32 MFMA per barrier pair. Accumulation order identical to R12.
// Epilogue writes producer-formatted f16 images + fused block-mean.
__global__ __launch_bounds__(256) void qkv_mfma_kernel(
    const short* __restrict__ A, const short* __restrict__ W,
    short* __restrict__ QhI, short* __restrict__ KhI, short* __restrict__ VtI,
    float* __restrict__ qbf, float* __restrict__ kbf)
{
    __shared__ short SM[32768];   // A: 2 bufs x 2 subs x 4096 | W same = 64 KB
    const int wg = blockIdx.x;
    const int row0 = (wg / 24) * 128;
    const int col0 = (wg % 24) * 128;
    const int tid = threadIdx.x;
    const int lane = tid & 63;
    const int wave = tid >> 6;
    const int wm = wave & 1, wn = wave >> 1;

    auto AHS = [&](int b) { return SM + b * 8192; };           // 2 subs x 4096
    auto WHS = [&](int b) { return SM + 16384 + b * 8192; };

    f32x4 acc[4][4];
    const f32x4 zero = {0.f, 0.f, 0.f, 0.f};
    #pragma unroll
    for (int i = 0; i < 4; ++i)
        #pragma unroll
        for (int j = 0; j < 4; ++j) acc[i][j] = zero;

    const int ldr = lane >> 2;                              // row in 16-row chunk
    const int lko = (((lane & 3) ^ ((lane >> 3) & 3))) * 8; // swizzled k-chunk
    const int rsl = ((lane >> 4) ^ ((lane >> 1) & 3)) * 8;  // frag-read slot

    // 8 global_load_lds per wave per call (2 chunks x 2 subs x {A,W})
    auto stage = [&](int bufi, int ktn) {
        const int kk = ktn << 6;                            // 64 k per step
        #pragma unroll
        for (int i = 0; i < 2; ++i) {
            const int chunk = wave * 2 + i;
            #pragma unroll
            for (int sub = 0; sub < 2; ++sub) {
                const short* gA = A + (size_t)(row0 + chunk * 16 + ldr) * 1024 + kk + sub * 32 + lko;
                const short* gW = W + (size_t)(col0 + chunk * 16 + ldr) * 1024 + kk + sub * 32 + lko;
                async_copy16(gA, (char*)AHS(bufi) + sub * 8192 + chunk * 1024);
                async_copy16(gW, (char*)WHS(bufi) + sub * 8192 + chunk * 1024);
            }
        }
    };

    auto compute = [&](int bufi) {
        #pragma unroll
        for (int sub = 0; sub < 2; ++sub) {
            const short* Ah = AHS(bufi) + sub * 4096;
            const short* Wh = WHS(bufi) + sub * 4096;
            f16x8 ah[4], wh[4];
            #pragma unroll
            for (int mi = 0; mi < 4; ++mi)
                ah[mi] = *(const f16x8*)(Ah + (wm * 64 + mi * 16 + (lane & 15)) * 32 + rsl);
            #pragma unroll
            for (int ni = 0; ni < 4; ++ni)
                wh[ni] = *(const f16x8*)(Wh + (wn * 64 + ni * 16 + (lane & 15)) * 32 + rsl);
            #pragma unroll
            for (int mi = 0; mi < 4; ++mi)
                #pragma unroll
                for (int ni = 0; ni < 4; ++ni)
                    acc[mi][ni] = __builtin_amdgcn_mfma_f32_16x16x32_f16(ah[mi], wh[ni], acc[mi][ni], 0, 0, 0);
        }
    };

    // 16 k-steps, 2-buf 1-ahead (R8 loop shape with NT=16)
    stage(0, 0);
    for (int kt = 0; kt < 14; kt += 2) {
        stage(1, kt + 1);
        VM_WAIT8; SBAR; SCHED0;
        compute(0);
        SBAR;
        stage(0, kt + 2);
        VM_WAIT8; SBAR; SCHED0;
        compute(1);
        SBAR;
    }
    stage(1, 15);
    VM_WAIT8; SBAR; SCHED0;
    compute(0);
    SBAR;
    VM_WAIT0; SBAR; SCHED0;
    compute(1);
    SBAR;   // protect LDS reuse by V-wave transpose below

    // ---- epilogue: write f16 image tiles (+ fused block-mean for q/k)
    const int gr_first = row0 + wm * 64;          // wave's 64-row token block
    const int bb = gr_first >> 11;
    const int mblk = (gr_first & 2047) >> 6;
    const int gc0 = col0 + wn * 64;               // wave's 64-col band (one head)
    const int tsel = gc0 >> 10;
    const int h = (gc0 >> 6) & 15;
    const int tile = ((bb << 4) + h) * 32 + mblk;
    const float sc = (tsel == 0) ? SCALE_F : 1.0f;

    if (tsel != 2) {
        short* baseH = ((tsel == 0) ? QhI : KhI) + (size_t)tile * 4096;
        float* mdst  = ((tsel == 0) ? qbf : kbf) + ((size_t)((bb << 4) + h) * 32 + mblk) * 64;
        #pragma unroll
        for (int ni = 0; ni < 4; ++ni) {
            const int d = ni * 16 + (lane & 15);
            float colsum = 0.f;
            #pragma unroll
            for (int mi = 0; mi < 4; ++mi) {
                #pragma unroll
                for (int r = 0; r < 4; ++r) {
                    const int row = mi * 16 + (lane >> 4) * 4 + r;
                    float v = acc[mi][ni][r] * sc;
                    colsum += v;
                    const int off = (row * 64 + d) ^ ((row & 7) << 3);   // shorts
                    baseH[off] = f16_bits(v);
                }
            }
            colsum += __shfl_xor(colsum, 16);
            colsum += __shfl_xor(colsum, 32);
            if ((lane >> 4) == 0) mdst[d] = colsum * (1.f / 64.f);
        }
    } else {
        // V: transpose 64x64 tile in per-wave LDS region, write Vt[d][kk] image
        short* tb = SM + wave * 4160;   // 64x65 shorts, per-wave exclusive
        #pragma unroll
        for (int ni = 0; ni < 4; ++ni)
            #pragma unroll
            for (int mi = 0; mi < 4; ++mi)
                #pragma unroll
                for (int r = 0; r < 4; ++r) {
                    const int row = mi * 16 + (lane >> 4) * 4 + r;   // kk
                    const int d = ni * 16 + (lane & 15);
                    tb[row * 65 + d] = f16_bits(acc[mi][ni][r]);
                }
        short* vout = VtI + (size_t)tile * 4096;
        #pragma unroll
        for (int c = 0; c < 8; ++c) {
            short8v tv;
            #pragma unroll
            for (int j = 0; j < 8; ++j)
                tv[j] = tb[(c * 8 + j) * 65 + lane];
            const int off = (lane * 64 + c * 8) ^ ((lane & 7) << 3);   // shorts
            *(short8v*)(vout + off) = tv;
        }
    }
}

// Block-scores + top-2 mask (FALLBACK PATH ONLY).
__global__ __launch_bounds__(256) void scores_splitw_kernel(
    const float* __restrict__ qbf, const float* __restrict__ kbf,
    unsigned int* __restrict__ maskbits, float scale,
    const float* __restrict__ projw, short* __restrict__ Wdst)
{
    __shared__ float qs_[32][64];
    __shared__ float ks_[32][64];
    __shared__ float cb[32][32];
    const int bid = blockIdx.x;
    const int tid = threadIdx.x;

    if (bid >= 32) {
        int idx = (bid - 32) * 256 + tid;
        int e = idx * 4;
        float4 v = *(const float4*)(projw + e);
        ushort4 o = make_ushort4((unsigned short)f16_bits(v.x), (unsigned short)f16_bits(v.y),
                                 (unsigned short)f16_bits(v.z), (unsigned short)f16_bits(v.w));
        *(ushort4*)(Wdst + e) = o;
        return;
    }

    #pragma unroll
    for (int i = 0; i < 8; ++i) {
        int e = tid + i * 256;
        qs_[e >> 6][e & 63] = qbf[(size_t)bid * 2048 + e];
        ks_[e >> 6][e & 63] = kbf[(size_t)bid * 2048 + e];
    }
    __syncthreads();

    #pragma unroll
    for (int i = 0; i < 4; ++i) {
        int idx = tid + i * 256;
        int r = idx >> 5, c = idx & 31;
        float s = 0.f;
        #pragma unroll
        for (int d = 0; d < 64; ++d) s += qs_[r][d] * ks_[c][d];
        cb[r][c] = s * scale;
    }
    __syncthreads();

    if (tid < 32) {
        float m1 = -INFINITY, m2 = -INFINITY;
        for (int n = 0; n < 32; ++n) {
            float v = cb[tid][n];
            if (v > m1) { m2 = m1; m1 = v; }
            else if (v > m2) { m2 = v; }
        }
        unsigned int bits = 1u << tid;
        for (int n = 0; n < 32; ++n)
            if (cb[tid][n] >= m2) bits |= 1u << n;
        maskbits[bid * 32 + tid] = bits;
    }
}

// Proj GEMM, f16 single-product + bias. R13: BK=64, 6 loads/wave/step,
// vmcnt(6), 16 MFMA per barrier pair. XCD-chunked swizzle kept.
__global__ __launch_bounds__(256) void proj_mfma_kernel(
    const short* __restrict__ A, const short* __restrict__ W,
    const float* __restrict__ bias, float* __restrict__ out)
{
    __shared__ short Ahs[2][8192];   // 2 subs x 4096
    __shared__ short Whs[2][4096];   // 2 subs x 2048
    const int bid = blockIdx.x;
    const int wg = (bid & 7) * 64 + (bid >> 3);   // bijective (512 % 8 == 0)
    const int row0 = (wg >> 4) * 128;
    const int col0 = (wg & 15) * 64;
    const int tid = threadIdx.x;
    const int lane = tid & 63;
    const int wave = tid >> 6;

    f32x4 acc[2][4];
    const f32x4 zero = {0.f, 0.f, 0.f, 0.f};
    #pragma unroll
    for (int i = 0; i < 2; ++i)
        #pragma unroll
        for (int j = 0; j < 4; ++j) acc[i][j] = zero;

    const int ldr = lane >> 2;
    const int lko = (((lane & 3) ^ ((lane >> 3) & 3))) * 8;
    const int rsl = ((lane >> 4) ^ ((lane >> 1) & 3)) * 8;

    // 6 global_load_lds per wave per call (A: 2 chunks x 2 subs; W: 2 subs)
    auto stage = [&](int bufi, int ktn) {
        const int kk = ktn << 6;
        #pragma unroll
        for (int i = 0; i < 2; ++i) {
            const int chunk = wave * 2 + i;
            #pragma unroll
            for (int sub = 0; sub < 2; ++sub) {
                const short* gA = A + (size_t)(row0 + chunk * 16 + ldr) * 1024 + kk + sub * 32 + lko;
                async_copy16(gA, (char*)&Ahs[bufi][0] + sub * 8192 + chunk * 1024);
            }
        }
        #pragma unroll
        for (int sub = 0; sub < 2; ++sub) {
            const short* gW = W + (size_t)(col0 + wave * 16 + ldr) * 1024 + kk + sub * 32 + lko;
            async_copy16(gW, (char*)&Whs[bufi][0] + sub * 4096 + wave * 1024);
        }
    };

    auto compute = [&](int bufi) {
        #pragma unroll
        for (int sub = 0; sub < 2; ++sub) {
            const short* Ah = &Ahs[bufi][0] + sub * 4096;
            const short* Wh = &Whs[bufi][0] + sub * 2048;
            f16x8 ah[2], wh[4];
            #pragma unroll
            for (int mi = 0; mi < 2; ++mi)
                ah[mi] = *(const f16x8*)(Ah + (wave * 32 + mi * 16 + (lane & 15)) * 32 + rsl);
            #pragma unroll
            for (int ni = 0; ni < 4; ++ni)
                wh[ni] = *(const f16x8*)(Wh + (ni * 16 + (lane & 15)) * 32 + rsl);
            #pragma unroll
            for (int mi = 0; mi < 2; ++mi)
                #pragma unroll
                for (int ni = 0; ni < 4; ++ni)
                    acc[mi][ni] = __builtin_amdgcn_mfma_f32_16x16x32_f16(ah[mi], wh[ni], acc[mi][ni], 0, 0, 0);
        }
    };

    stage(0, 0);
    for (int kt = 0; kt < 14; kt += 2) {
        stage(1, kt + 1);
        VM_WAIT6; SBAR; SCHED0;
        compute(0);
        SBAR;
        stage(0, kt + 2);
        VM_WAIT6; SBAR; SCHED0;
        compute(1);
        SBAR;
    }
    stage(1, 15);
    VM_WAIT6; SBAR; SCHED0;
    compute(0);
    SBAR;
    VM_WAIT0; SBAR; SCHED0;
    compute(1);

    #pragma unroll
    for (int ni = 0; ni < 4; ++ni) {
        int gc = col0 + ni * 16 + (lane & 15);
        float bv = bias[gc];
        #pragma unroll
        for (int mi = 0; mi < 2; ++mi) {
            int gr0 = row0 + wave * 32 + mi * 16 + (lane >> 4) * 4;
            #pragma unroll
            for (int r = 0; r < 4; ++r)
                out[(size_t)(gr0 + r) * 1024 + gc] = acc[mi][ni][r] + bv;
        }
    }
}

// ---------------------------------------------------------------------------
// Sparse block attention — R12 VERBATIM (swapped-operand QK^T, per-lane
// softmax, in-kernel mask, 1-ahead vmcnt(4)).
// ---------------------------------------------------------------------------
__global__ __launch_bounds__(256) void sparse_attn_mfma_kernel(
    const short* __restrict__ QhI, const short* __restrict__ KhI,
    const short* __restrict__ VtI,
    const float* __restrict__ qbf, const float* __restrict__ kbf,
    short* __restrict__ aout)
{
    __shared__ f16 Qh[4096];                  // [64][64] swizzled
    __shared__ f16 Kh[2][4096];               // dbuf
    __shared__ f16 Vt[2][4096];               // dbuf, [d][kk] swizzled
    __shared__ f16 Pb[64 * LSTR];             // P[q][kk], wave-private rows

    const int bid = blockIdx.x;
    const int wg = (bid & 7) * 128 + (bid >> 3);  // bijective (1024 % 8 == 0)
    const int m  = wg & 31;
    const int bh = wg >> 5;
    const int b  = bh >> 4, h = bh & 15;
    const int tid = threadIdx.x;
    const int lane = tid & 63;
    const int wave = tid >> 6;
    const f32x4 zero = {0.f, 0.f, 0.f, 0.f};

    // ---- stage Q (once): 2 issues/wave
    {
        const size_t qt = (size_t)(bh * 32 + m) * 4096;
        const int so = wave * 1024 + lane * 8;
        async_copy16(QhI + qt + so,       (char*)Qh + wave * 2048);
        async_copy16(QhI + qt + so + 512, (char*)Qh + wave * 2048 + 1024);
    }

    // ---- K/V tile stage: 4 issues/wave (the vmcnt quantum)
    auto stageKV = [&](int bufi, int nb) {
        const size_t t4 = (size_t)(bh * 32 + nb) * 4096;
        const int so = wave * 1024 + lane * 8;
        async_copy16(KhI + t4 + so,       (char*)&Kh[bufi][0] + wave * 2048);
        async_copy16(KhI + t4 + so + 512, (char*)&Kh[bufi][0] + wave * 2048 + 1024);
        async_copy16(VtI + t4 + so,       (char*)&Vt[bufi][0] + wave * 2048);
        async_copy16(VtI + t4 + so + 512, (char*)&Vt[bufi][0] + wave * 2048 + 1024);
    };

    // ---- diagonal tile is ALWAYS in the mask: stage it before the mask calc
    stageKV(0, m);

    // ---- in-kernel mask (R11-proven; FP order == old scores kernel)
    unsigned int mask;
    {
        float c = -INFINITY;
        if (lane < 32) {
            const float* qrow = qbf + ((size_t)bh * 32 + m) * 64;
            const float* krow = kbf + ((size_t)bh * 32 + lane) * 64;
            float s = 0.f;
            for (int d = 0; d < 64; ++d) s += qrow[d] * krow[d];
            c = s;
        }
        float m1 = c;
        #pragma unroll
        for (int off = 1; off < 64; off <<= 1) m1 = fmaxf(m1, __shfl_xor(m1, off));
        unsigned long long eq = __ballot(c == m1);
        float cx = (c == m1) ? -INFINITY : c;
        #pragma unroll
        for (int off = 1; off < 64; off <<= 1) cx = fmaxf(cx, __shfl_xor(cx, off));
        float m2 = (__popcll(eq) >= 2) ? m1 : cx;
        unsigned long long ge = __ballot(c >= m2);
        mask = (unsigned int)(ge & 0xffffffffULL) | (1u << m);
    }

    f32x4 o_acc[4];
    float macc_s = -INFINITY, lacc_s = 0.f;   // per-lane: q = wave*16+(lane&15)
    #pragma unroll
    for (int t = 0; t < 4; ++t) o_acc[t] = zero;

    const int arow = wave * 16 + (lane & 15);
    const int kofs = (lane >> 4) * 8;      // shorts (for Pb)
    const int colb = (lane >> 4) * 16;     // bytes (for swizzled images)

    auto computeTile = [&](int bi) {
        const f16* KhB = &Kh[bi][0];
        // ---- QK^T, SWAPPED operands: mfma(K, Q) -> D[k_local][q]
        f32x4 s_acc[4];
        #pragma unroll
        for (int t = 0; t < 4; ++t) s_acc[t] = zero;
        #pragma unroll
        for (int c = 0; c < 2; ++c) {
            const int qoff = (arow * 128 + c * 64 + colb) ^ ((arow & 7) << 4);
            f16x8 ah = *(const f16x8*)((const char*)Qh + qoff);
            #pragma unroll
            for (int t = 0; t < 4; ++t) {
                const int krow = t * 16 + (lane & 15);
                const int koff = (krow * 128 + c * 64 + colb) ^ ((krow & 7) << 4);
                f16x8 bh_ = *(const f16x8*)((const char*)KhB + koff);
                s_acc[t] = __builtin_amdgcn_mfma_f32_16x16x32_f16(bh_, ah, s_acc[t], 0, 0, 0);
            }
        }

        // ---- per-lane online softmax (q = arow)
        float vmax = s_acc[0][0];
        #pragma unroll
        for (int t = 0; t < 4; ++t)
            #pragma unroll
            for (int r = 0; r < 4; ++r) vmax = fmaxf(vmax, s_acc[t][r]);
        vmax = fmaxf(vmax, __shfl_xor(vmax, 16));
        vmax = fmaxf(vmax, __shfl_xor(vmax, 32));
        float mnew = fmaxf(macc_s, vmax);
        float alpha = expf(macc_s - mnew);
        macc_s = mnew;

        float psum = 0.f;
        #pragma unroll
        for (int t = 0; t < 4; ++t) {
            f16x4 pv;
            #pragma unroll
            for (int r = 0; r < 4; ++r) {
                float p = expf(s_acc[t][r] - mnew);
                psum += p;
                pv[r] = (f16)p;
            }
            *(f16x4*)(Pb + arow * LSTR + t * 16 + (lane >> 4) * 4) = pv;
        }
        psum += __shfl_xor(psum, 16);
        psum += __shfl_xor(psum, 32);
        lacc_s = lacc_s * alpha + psum;

        float ab[4];
        #pragma unroll
        for (int r = 0; r < 4; ++r) ab[r] = __shfl(alpha, (lane >> 4) * 4 + r);
        #pragma unroll
        for (int t = 0; t < 4; ++t)
            #pragma unroll
            for (int r = 0; r < 4; ++r) o_acc[t][r] *= ab[r];

        // ---- PV (Pb rows wave-private)
        const f16* VtB = &Vt[bi][0];
        #pragma unroll
        for (int c = 0; c < 2; ++c) {
            f16x8 af = *(const f16x8*)(Pb + arow * LSTR + c * 32 + kofs);
            #pragma unroll
            for (int t = 0; t < 4; ++t) {
                const int vrow = t * 16 + (lane & 15);
                const int voff = (vrow * 128 + c * 64 + colb) ^ ((vrow & 7) << 4);
                f16x8 bf = *(const f16x8*)((const char*)VtB + voff);
                o_acc[t] = __builtin_amdgcn_mfma_f32_16x16x32_f16(af, bf, o_acc[t], 0, 0, 0);
            }
        }
    };

    // ---- pipelined masked loop: diagonal first, then set bits ascending.
    unsigned int mm = mask & ~(1u << m);
    int cur = 0;
    for (;;) {
        int nb_nxt = -1;
        if (mm) { nb_nxt = __builtin_ctz(mm); mm &= mm - 1; stageKV(cur ^ 1, nb_nxt); }
        if (nb_nxt >= 0) { VM_WAIT4; } else { VM_WAIT0; }
        SBAR; SCHED0;
        computeTile(cur);
        SBAR;
        if (nb_nxt < 0) break;
        cur ^= 1;
    }

    // ---- epilogue: normalize (broadcast inv to o_acc rows), write f16 out
    float inv_s = (lacc_s > 0.f) ? (1.f / lacc_s) : 0.f;
    float invb[4];
    #pragma unroll
    for (int r = 0; r < 4; ++r) invb[r] = __shfl(inv_s, (lane >> 4) * 4 + r);
    #pragma unroll
    for (int t = 0; t < 4; ++t) {
        int gc = h * 64 + t * 16 + (lane & 15);
        #pragma unroll
        for (int r = 0; r < 4; ++r) {
            int grow = b * NN + m * 64 + wave * 16 + (lane >> 4) * 4 + r;
            float v = o_acc[t][r] * invb[r];
            aout[(size_t)grow * 1024 + gc] = f16_bits(v);
        }
    }
}

// ===========================================================================
// FALLBACK KERNELS (round-2 proven fp32 path)
// ===========================================================================

__global__ __launch_bounds__(256) void block_mean_kernel(
    const float* __restrict__ qf, const float* __restrict__ kf,
    float* __restrict__ qbf, float* __restrict__ kbf)
{
    int idx = blockIdx.x * 256 + threadIdx.x;
    const float* src = (idx < 65536) ? qf : kf;
    float* dst       = (idx < 65536) ? qbf : kbf;
    int e = idx & 65535;
    int d = e & 63;
    int r = e >> 6;
    size_t base = (size_t)r * 4096 + d;
    float s = 0.f;
    #pragma unroll
    for (int i = 0; i < 64; ++i) s += src[base + (size_t)i * 64];
    dst[e] = s * (1.f / 64.f);
}

__global__ __launch_bounds__(256) void qkv_gemm_fb(
    const float* __restrict__ x, const float* __restrict__ w,
    float* __restrict__ qf, float* __restrict__ kf, float* __restrict__ vf)
{
    __shared__ float As[64][33];
    __shared__ float Bs[64][33];
    const int tid = threadIdx.x;
    const int row0 = blockIdx.y * 64;
    const int col0 = blockIdx.x * 64;
    const int ty = tid >> 4, tx = tid & 15;

    float acc[4][4] = {};
    for (int k0 = 0; k0 < 1024; k0 += 32) {
        #pragma unroll
        for (int i = 0; i < 8; ++i) {
            int e = tid + i * 256;
            int r = e >> 5, c = e & 31;
            As[r][c] = x[(size_t)(row0 + r) * 1024 + k0 + c];
            Bs[r][c] = w[(size_t)(col0 + r) * 1024 + k0 + c];
        }
        __syncthreads();
        #pragma unroll
        for (int kk = 0; kk < 32; ++kk) {
            float a[4], bq[4];
            #pragma unroll
            for (int i = 0; i < 4; ++i) a[i] = As[ty * 4 + i][kk];
            #pragma unroll
            for (int j = 0; j < 4; ++j) bq[j] = Bs[tx * 4 + j][kk];
            #pragma unroll
            for (int i = 0; i < 4; ++i)
                #pragma unroll
                for (int j = 0; j < 4; ++j)
                    acc[i][j] += a[i] * bq[j];
        }
        __syncthreads();
    }

    const int tsel = col0 >> 10;
    const int h    = (col0 & 1023) >> 6;
    float* dstbuf = (tsel == 0) ? qf : (tsel == 1) ? kf : vf;
    #pragma unroll
    for (int i = 0; i < 4; ++i) {
        int row = row0 + ty * 4 + i;
        int b   = row >> 11, n = row & 2047;
        size_t rb = ((size_t)(b * HH + h) * NN + n) * HD64;
        #pragma unroll
        for (int j = 0; j < 4; ++j)
            dstbuf[rb + tx * 4 + j] = acc[i][j];
    }
}

__global__ __launch_bounds__(256) void proj_gemm_fb(
    const float* __restrict__ attn, const float* __restrict__ w,
    const float* __restrict__ bias, float* __restrict__ out)
{
    __shared__ float As[64][33];
    __shared__ float Bs[64][33];
    const int tid = threadIdx.x;
    const int row0 = blockIdx.y * 64;
    const int col0 = blockIdx.x * 64;
    const int ty = tid >> 4, tx = tid & 15;

    float acc[4][4] = {};
    for (int k0 = 0; k0 < 1024; k0 += 32) {
        #pragma unroll
        for (int i = 0; i < 8; ++i) {
            int e = tid + i * 256;
            int r = e >> 5, c = e & 31;
            As[r][c] = attn[(size_t)(row0 + r) * 1024 + k0 + c];
            Bs[r][c] = w[(size_t)(col0 + r) * 1024 + k0 + c];
        }
        __syncthreads();
        #pragma unroll
        for (int kk = 0; kk < 32; ++kk) {
            float a[4], bq[4];
            #pragma unroll
            for (int i = 0; i < 4; ++i) a[i] = As[ty * 4 + i][kk];
            #pragma unroll
            for (int j = 0; j < 4; ++j) bq[j] = Bs[tx * 4 + j][kk];
            #pragma unroll
            for (int i = 0; i < 4; ++i)
                #pragma unroll
                for (int j = 0; j < 4; ++j)
                    acc[i][j] += a[i] * bq[j];
        }
        __syncthreads();
    }

    #pragma unroll
    for (int j = 0; j < 4; ++j) {
        int col = col0 + tx * 4 + j;
        float bv = bias[col];
        #pragma unroll
        for (int i = 0; i < 4; ++i) {
            int row = row0 + ty * 4 + i;
            out[(size_t)row * 1024 + col] = acc[i][j] + bv;
        }
    }
}

__global__ __launch_bounds__(256) void sparse_attn_fb(
    const float* __restrict__ qf, const float* __restrict__ kf,
    const float* __restrict__ vf, const unsigned int* __restrict__ maskbits,
    float* __restrict__ attnf)
{
    __shared__ float kbuf[64][64];
    __shared__ float vbuf[64][64];
    __shared__ float sbuf[64][65];
    const int m  = blockIdx.x & 31;
    const int bh = blockIdx.x >> 5;
    const int b  = bh >> 4, h = bh & 15;
    const int t  = threadIdx.x;
    const int qr = t >> 2;
    const int dg = t & 3;
    const int d0 = dg * 16;

    float qreg[16];
    {
        const float* qp = qf + ((size_t)bh * NN + m * 64 + qr) * HD64 + d0;
        #pragma unroll
        for (int j = 0; j < 16; j += 4) {
            float4 v = *(const float4*)(qp + j);
            qreg[j] = v.x; qreg[j+1] = v.y; qreg[j+2] = v.z; qreg[j+3] = v.w;
        }
    }

    const unsigned int mask = maskbits[bh * 32 + m];
    float macc = -INFINITY, lacc = 0.f;
    float oacc[16];
    #pragma unroll
    for (int j = 0; j < 16; ++j) oacc[j] = 0.f;

    for (int nb = 0; nb < 32; ++nb) {
        if (!((mask >> nb) & 1u)) continue;
        __syncthreads();
        {
            const float* gk = kf + ((size_t)bh * NN + nb * 64) * HD64;
            const float* gv = vf + ((size_t)bh * NN + nb * 64) * HD64;
            #pragma unroll
            for (int i = 0; i < 4; ++i) {
                async_copy16(gk + t * 4 + i * 1024, (char*)kbuf + t * 16 + i * 4096);
                async_copy16(gv + t * 4 + i * 1024, (char*)vbuf + t * 16 + i * 4096);
            }
        }
        __syncthreads();

        float bmax = -INFINITY;
        for (int kk = 0; kk < 64; ++kk) {
            float s = 0.f;
            #pragma unroll
            for (int j = 0; j < 16; ++j) s += qreg[j] * kbuf[kk][d0 + j];
            s += __shfl_xor(s, 1);
            s += __shfl_xor(s, 2);
            s *= SCALE_F;
            if (dg == 0) sbuf[qr][kk] = s;
            bmax = fmaxf(bmax, s);
        }
        float mnew  = fmaxf(macc, bmax);
        float alpha = expf(macc - mnew);
        lacc *= alpha;
        #pragma unroll
        for (int j = 0; j < 16; ++j) oacc[j] *= alpha;
        for (int kk = 0; kk < 64; ++kk) {
            float p = expf(sbuf[qr][kk] - mnew);
            lacc += p;
            #pragma unroll
            for (int j = 0; j < 16; ++j) oacc[j] += p * vbuf[kk][d0 + j];
        }
        macc = mnew;
    }

    float inv = (lacc > 0.f) ? (1.f / lacc) : 0.f;
    size_t orow = ((size_t)(b * NN + m * 64 + qr)) * DIMD + h * 64 + d0;
    #pragma unroll
    for (int j = 0; j < 16; ++j) attnf[orow + j] = oacc[j] * inv;
}

// ---------------------------------------------------------------------------
extern "C" void kernel_launch(void* const* d_in, const int* in_sizes, int n_in,
                              void* d_out, int out_size, void* d_ws, size_t ws_size,
                              hipStream_t stream)
{
    const float* x      = (const float*)d_in[0];
    const float* qkv_w  = (const float*)d_in[1];
    const float* proj_w = (const float*)d_in[2];
    const float* proj_b = (const float*)d_in[3];
    float* out = (float*)d_out;

    // Carve (fast path, ~41 MB):
    //   Qh/Kh/Vt images: 3 x 8 MB f16 tiles [1024 tiles][4096 shorts]
    //   qbf/kbf 512K | mask 4K (fallback only)
    //   Axs 8M f16 [4096][1024] (x-split; reused as attention output)
    //   Wqs 6M f16 [3072][1024] | Wp 2M f16 [1024][1024]
    short* QhI = (short*)d_ws;
    short* KhI = QhI + 4194304;
    short* VtI = KhI + 4194304;
    float* qbf = (float*)(VtI + 4194304);
    float* kbf = qbf + 65536;
    unsigned int* maskb = (unsigned int*)(kbf + 65536);
    short* Axs = (short*)(maskb + 1024);
    short* Wqs = Axs + (size_t)4096 * 1024;
    short* Wp  = Wqs + (size_t)3072 * 1024;
    const size_t need_fast = (size_t)((char*)(Wp + (size_t)1024 * 1024) - (char*)d_ws);

    if (ws_size >= need_fast) {
        split_in_fused_kernel<<<8192, 256, 0, stream>>>(x, Axs, qkv_w, Wqs, proj_w, Wp);
        qkv_mfma_kernel<<<768, 256, 0, stream>>>(Axs, Wqs, QhI, KhI, VtI, qbf, kbf);
        sparse_attn_mfma_kernel<<<1024, 256, 0, stream>>>(QhI, KhI, VtI, qbf, kbf, Axs);
        proj_mfma_kernel<<<512, 256, 0, stream>>>(Axs, Wp, proj_b, out);
    } else {
        float* qf2  = (float*)d_ws;
        float* kf2  = qf2 + 4194304;
        float* vf2  = kf2 + 4194304;
        float* qbf2 = vf2 + 4194304;
        float* kbf2 = qbf2 + 65536;
        unsigned int* maskb2 = (unsigned int*)(kbf2 + 65536);
        float* attnf = (float*)(maskb2 + 1024);
        qkv_gemm_fb<<<dim3(48, 64), 256, 0, stream>>>(x, qkv_w, qf2, kf2, vf2);
        block_mean_kernel<<<512, 256, 0, stream>>>(qf2, kf2, qbf2, kbf2);
        scores_splitw_kernel<<<32, 256, 0, stream>>>(qbf2, kbf2, maskb2, SCALE_F,
                                                     (const float*)nullptr, (short*)nullptr);
        sparse_attn_fb<<<1024, 256, 0, stream>>>(qf2, kf2, vf2, maskb2, attnf);
        proj_gemm_fb<<<dim3(16, 64), 256, 0, stream>>>(attnf, proj_w, proj_b, out);
    }
}

// Round 14
// 147.632 us; speedup vs baseline: 1.6793x; 1.0169x over previous
//
#include <hip/hip_runtime.h>
#include <hip/hip_bf16.h>

// Problem constants (B=2, N=2048, DIM=1024, H=16, HD=64, BS=64, M=32)
#define BB 2
#define NN 2048
#define DIMD 1024
#define HH 16
#define HD64 64
#define MB 32
#define SCALE_F 0.125f   // HD^-0.5

typedef __attribute__((ext_vector_type(8))) short bf16x8;
typedef __attribute__((ext_vector_type(8))) short short8v;
typedef __attribute__((ext_vector_type(4))) float f32x4;
typedef _Float16 f16;
typedef __attribute__((ext_vector_type(8))) _Float16 f16x8;
typedef __attribute__((ext_vector_type(4))) _Float16 f16x4;

// counted-vmcnt barrier discipline (T4) — 2-buf 1-ahead, proven quanta:
// vmcnt(8) = qkv BK=64; vmcnt(6) = proj BK=64; vmcnt(4) = attn.
#define VM_WAIT8 asm volatile("s_waitcnt vmcnt(8)" ::: "memory")
#define VM_WAIT6 asm volatile("s_waitcnt vmcnt(6)" ::: "memory")
#define VM_WAIT4 asm volatile("s_waitcnt vmcnt(4)" ::: "memory")
#define VM_WAIT0 asm volatile("s_waitcnt vmcnt(0)" ::: "memory")
#define SBAR __builtin_amdgcn_s_barrier()
#define SCHED0 __builtin_amdgcn_sched_barrier(0)

__device__ __forceinline__ unsigned short bf16_hi(float f) {
    return __builtin_bit_cast(unsigned short, __float2bfloat16(f));
}
__device__ __forceinline__ float bf16_val(unsigned short u) {
    return __bfloat162float(__builtin_bit_cast(__hip_bfloat16, u));
}
__device__ __forceinline__ short f16_bits(float f) {
    return __builtin_bit_cast(short, (f16)f);
}
__device__ __forceinline__ void async_copy16(const void* g, void* l) {
    __builtin_amdgcn_global_load_lds((const __attribute__((address_space(1))) void*)g,
                                     (__attribute__((address_space(3))) void*)l, 16, 0, 0);
}

// ===========================================================================
// FAST PATH — single-product f16 (R8), in-kernel mask (R11), swapped-operand
// softmax (R12), BK=64 GEMMs (R13). R14: attn LDS diet — Q in registers,
// Pb LSTR 64 + XOR swizzle -> LDS 49.2 -> 40 KB -> 4 blocks/CU (1024 blocks
// = 256 CUs x 4 in ONE balanced round). Pure layout change, zero numerics.
// ===========================================================================

// Fused input split: [0,4096) x -> Axs; [4096,7168) qkv_w -> Wqs;
// [7168,8192) proj_w -> Wp.  Single-plane f16.
__global__ __launch_bounds__(256) void split_in_fused_kernel(
    const float* __restrict__ x, short* __restrict__ Axs,
    const float* __restrict__ w, short* __restrict__ Wqs,
    const float* __restrict__ pw, short* __restrict__ Wp)
{
    const int bid = blockIdx.x;
    const float* src; short* dst; int idx;
    if (bid < 4096)      { src = x;  dst = Axs; idx = bid * 256 + threadIdx.x; }
    else if (bid < 7168) { src = w;  dst = Wqs; idx = (bid - 4096) * 256 + threadIdx.x; }
    else                 { src = pw; dst = Wp;  idx = (bid - 7168) * 256 + threadIdx.x; }
    int e = idx * 4;
    float4 v = *(const float4*)(src + e);
    ushort4 o = make_ushort4((unsigned short)f16_bits(v.x), (unsigned short)f16_bits(v.y),
                             (unsigned short)f16_bits(v.z), (unsigned short)f16_bits(v.w));
    *(ushort4*)(dst + e) = o;
}

// QKV GEMM, f16 single-product — R13 VERBATIM (BK=64, vmcnt(8), 32 MFMA/pair).
// Epilogue writes producer-formatted f16 images + fused block-mean.
__global__ __launch_bounds__(256) void qkv_mfma_kernel(
    const short* __restrict__ A, const short* __restrict__ W,
    short* __restrict__ QhI, short* __restrict__ KhI, short* __restrict__ VtI,
    float* __restrict__ qbf, float* __restrict__ kbf)
{
    __shared__ short SM[32768];   // A: 2 bufs x 2 subs x 4096 | W same = 64 KB
    const int wg = blockIdx.x;
    const int row0 = (wg / 24) * 128;
    const int col0 = (wg % 24) * 128;
    const int tid = threadIdx.x;
    const int lane = tid & 63;
    const int wave = tid >> 6;
    const int wm = wave & 1, wn = wave >> 1;

    auto AHS = [&](int b) { return SM + b * 8192; };           // 2 subs x 4096
    auto WHS = [&](int b) { return SM + 16384 + b * 8192; };

    f32x4 acc[4][4];
    const f32x4 zero = {0.f, 0.f, 0.f, 0.f};
    #pragma unroll
    for (int i = 0; i < 4; ++i)
        #pragma unroll
        for (int j = 0; j < 4; ++j) acc[i][j] = zero;

    const int ldr = lane >> 2;                              // row in 16-row chunk
    const int lko = (((lane & 3) ^ ((lane >> 3) & 3))) * 8; // swizzled k-chunk
    const int rsl = ((lane >> 4) ^ ((lane >> 1) & 3)) * 8;  // frag-read slot

    // 8 global_load_lds per wave per call (2 chunks x 2 subs x {A,W})
    auto stage = [&](int bufi, int ktn) {
        const int kk = ktn << 6;                            // 64 k per step
        #pragma unroll
        for (int i = 0; i < 2; ++i) {
            const int chunk = wave * 2 + i;
            #pragma unroll
            for (int sub = 0; sub < 2; ++sub) {
                const short* gA = A + (size_t)(row0 + chunk * 16 + ldr) * 1024 + kk + sub * 32 + lko;
                const short* gW = W + (size_t)(col0 + chunk * 16 + ldr) * 1024 + kk + sub * 32 + lko;
                async_copy16(gA, (char*)AHS(bufi) + sub * 8192 + chunk * 1024);
                async_copy16(gW, (char*)WHS(bufi) + sub * 8192 + chunk * 1024);
            }
        }
    };

    auto compute = [&](int bufi) {
        #pragma unroll
        for (int sub = 0; sub < 2; ++sub) {
            const short* Ah = AHS(bufi) + sub * 4096;
            const short* Wh = WHS(bufi) + sub * 4096;
            f16x8 ah[4], wh[4];
            #pragma unroll
            for (int mi = 0; mi < 4; ++mi)
                ah[mi] = *(const f16x8*)(Ah + (wm * 64 + mi * 16 + (lane & 15)) * 32 + rsl);
            #pragma unroll
            for (int ni = 0; ni < 4; ++ni)
                wh[ni] = *(const f16x8*)(Wh + (wn * 64 + ni * 16 + (lane & 15)) * 32 + rsl);
            #pragma unroll
            for (int mi = 0; mi < 4; ++mi)
                #pragma unroll
                for (int ni = 0; ni < 4; ++ni)
                    acc[mi][ni] = __builtin_amdgcn_mfma_f32_16x16x32_f16(ah[mi], wh[ni], acc[mi][ni], 0, 0, 0);
        }
    };

    // 16 k-steps, 2-buf 1-ahead
    stage(0, 0);
    for (int kt = 0; kt < 14; kt += 2) {
        stage(1, kt + 1);
        VM_WAIT8; SBAR; SCHED0;
        compute(0);
        SBAR;
        stage(0, kt + 2);
        VM_WAIT8; SBAR; SCHED0;
        compute(1);
        SBAR;
    }
    stage(1, 15);
    VM_WAIT8; SBAR; SCHED0;
    compute(0);
    SBAR;
    VM_WAIT0; SBAR; SCHED0;
    compute(1);
    SBAR;   // protect LDS reuse by V-wave transpose below

    // ---- epilogue: write f16 image tiles (+ fused block-mean for q/k)
    const int gr_first = row0 + wm * 64;          // wave's 64-row token block
    const int bb = gr_first >> 11;
    const int mblk = (gr_first & 2047) >> 6;
    const int gc0 = col0 + wn * 64;               // wave's 64-col band (one head)
    const int tsel = gc0 >> 10;
    const int h = (gc0 >> 6) & 15;
    const int tile = ((bb << 4) + h) * 32 + mblk;
    const float sc = (tsel == 0) ? SCALE_F : 1.0f;

    if (tsel != 2) {
        short* baseH = ((tsel == 0) ? QhI : KhI) + (size_t)tile * 4096;
        float* mdst  = ((tsel == 0) ? qbf : kbf) + ((size_t)((bb << 4) + h) * 32 + mblk) * 64;
        #pragma unroll
        for (int ni = 0; ni < 4; ++ni) {
            const int d = ni * 16 + (lane & 15);
            float colsum = 0.f;
            #pragma unroll
            for (int mi = 0; mi < 4; ++mi) {
                #pragma unroll
                for (int r = 0; r < 4; ++r) {
                    const int row = mi * 16 + (lane >> 4) * 4 + r;
                    float v = acc[mi][ni][r] * sc;
                    colsum += v;
                    const int off = (row * 64 + d) ^ ((row & 7) << 3);   // shorts
                    baseH[off] = f16_bits(v);
                }
            }
            colsum += __shfl_xor(colsum, 16);
            colsum += __shfl_xor(colsum, 32);
            if ((lane >> 4) == 0) mdst[d] = colsum * (1.f / 64.f);
        }
    } else {
        // V: transpose 64x64 tile in per-wave LDS region, write Vt[d][kk] image
        short* tb = SM + wave * 4160;   // 64x65 shorts, per-wave exclusive
        #pragma unroll
        for (int ni = 0; ni < 4; ++ni)
            #pragma unroll
            for (int mi = 0; mi < 4; ++mi)
                #pragma unroll
                for (int r = 0; r < 4; ++r) {
                    const int row = mi * 16 + (lane >> 4) * 4 + r;   // kk
                    const int d = ni * 16 + (lane & 15);
                    tb[row * 65 + d] = f16_bits(acc[mi][ni][r]);
                }
        short* vout = VtI + (size_t)tile * 4096;
        #pragma unroll
        for (int c = 0; c < 8; ++c) {
            short8v tv;
            #pragma unroll
            for (int j = 0; j < 8; ++j)
                tv[j] = tb[(c * 8 + j) * 65 + lane];
            const int off = (lane * 64 + c * 8) ^ ((lane & 7) << 3);   // shorts
            *(short8v*)(vout + off) = tv;
        }
    }
}

// Block-scores + top-2 mask (FALLBACK PATH ONLY).
__global__ __launch_bounds__(256) void scores_splitw_kernel(
    const float* __restrict__ qbf, const float* __restrict__ kbf,
    unsigned int* __restrict__ maskbits, float scale,
    const float* __restrict__ projw, short* __restrict__ Wdst)
{
    __shared__ float qs_[32][64];
    __shared__ float ks_[32][64];
    __shared__ float cb[32][32];
    const int bid = blockIdx.x;
    const int tid = threadIdx.x;

    if (bid >= 32) {
        int idx = (bid - 32) * 256 + tid;
        int e = idx * 4;
        float4 v = *(const float4*)(projw + e);
        ushort4 o = make_ushort4((unsigned short)f16_bits(v.x), (unsigned short)f16_bits(v.y),
                                 (unsigned short)f16_bits(v.z), (unsigned short)f16_bits(v.w));
        *(ushort4*)(Wdst + e) = o;
        return;
    }

    #pragma unroll
    for (int i = 0; i < 8; ++i) {
        int e = tid + i * 256;
        qs_[e >> 6][e & 63] = qbf[(size_t)bid * 2048 + e];
        ks_[e >> 6][e & 63] = kbf[(size_t)bid * 2048 + e];
    }
    __syncthreads();

    #pragma unroll
    for (int i = 0; i < 4; ++i) {
        int idx = tid + i * 256;
        int r = idx >> 5, c = idx & 31;
        float s = 0.f;
        #pragma unroll
        for (int d = 0; d < 64; ++d) s += qs_[r][d] * ks_[c][d];
        cb[r][c] = s * scale;
    }
    __syncthreads();

    if (tid < 32) {
        float m1 = -INFINITY, m2 = -INFINITY;
        for (int n = 0; n < 32; ++n) {
            float v = cb[tid][n];
            if (v > m1) { m2 = m1; m1 = v; }
            else if (v > m2) { m2 = v; }
        }
        unsigned int bits = 1u << tid;
        for (int n = 0; n < 32; ++n)
            if (cb[tid][n] >= m2) bits |= 1u << n;
        maskbits[bid * 32 + tid] = bits;
    }
}

// Proj GEMM, f16 single-product + bias — R13 VERBATIM (BK=64, vmcnt(6)).
__global__ __launch_bounds__(256) void proj_mfma_kernel(
    const short* __restrict__ A, const short* __restrict__ W,
    const float* __restrict__ bias, float* __restrict__ out)
{
    __shared__ short Ahs[2][8192];   // 2 subs x 4096
    __shared__ short Whs[2][4096];   // 2 subs x 2048
    const int bid = blockIdx.x;
    const int wg = (bid & 7) * 64 + (bid >> 3);   // bijective (512 % 8 == 0)
    const int row0 = (wg >> 4) * 128;
    const int col0 = (wg & 15) * 64;
    const int tid = threadIdx.x;
    const int lane = tid & 63;
    const int wave = tid >> 6;

    f32x4 acc[2][4];
    const f32x4 zero = {0.f, 0.f, 0.f, 0.f};
    #pragma unroll
    for (int i = 0; i < 2; ++i)
        #pragma unroll
        for (int j = 0; j < 4; ++j) acc[i][j] = zero;

    const int ldr = lane >> 2;
    const int lko = (((lane & 3) ^ ((lane >> 3) & 3))) * 8;
    const int rsl = ((lane >> 4) ^ ((lane >> 1) & 3)) * 8;

    // 6 global_load_lds per wave per call (A: 2 chunks x 2 subs; W: 2 subs)
    auto stage = [&](int bufi, int ktn) {
        const int kk = ktn << 6;
        #pragma unroll
        for (int i = 0; i < 2; ++i) {
            const int chunk = wave * 2 + i;
            #pragma unroll
            for (int sub = 0; sub < 2; ++sub) {
                const short* gA = A + (size_t)(row0 + chunk * 16 + ldr) * 1024 + kk + sub * 32 + lko;
                async_copy16(gA, (char*)&Ahs[bufi][0] + sub * 8192 + chunk * 1024);
            }
        }
        #pragma unroll
        for (int sub = 0; sub < 2; ++sub) {
            const short* gW = W + (size_t)(col0 + wave * 16 + ldr) * 1024 + kk + sub * 32 + lko;
            async_copy16(gW, (char*)&Whs[bufi][0] + sub * 4096 + wave * 1024);
        }
    };

    auto compute = [&](int bufi) {
        #pragma unroll
        for (int sub = 0; sub < 2; ++sub) {
            const short* Ah = &Ahs[bufi][0] + sub * 4096;
            const short* Wh = &Whs[bufi][0] + sub * 2048;
            f16x8 ah[2], wh[4];
            #pragma unroll
            for (int mi = 0; mi < 2; ++mi)
                ah[mi] = *(const f16x8*)(Ah + (wave * 32 + mi * 16 + (lane & 15)) * 32 + rsl);
            #pragma unroll
            for (int ni = 0; ni < 4; ++ni)
                wh[ni] = *(const f16x8*)(Wh + (ni * 16 + (lane & 15)) * 32 + rsl);
            #pragma unroll
            for (int mi = 0; mi < 2; ++mi)
                #pragma unroll
                for (int ni = 0; ni < 4; ++ni)
                    acc[mi][ni] = __builtin_amdgcn_mfma_f32_16x16x32_f16(ah[mi], wh[ni], acc[mi][ni], 0, 0, 0);
        }
    };

    stage(0, 0);
    for (int kt = 0; kt < 14; kt += 2) {
        stage(1, kt + 1);
        VM_WAIT6; SBAR; SCHED0;
        compute(0);
        SBAR;
        stage(0, kt + 2);
        VM_WAIT6; SBAR; SCHED0;
        compute(1);
        SBAR;
    }
    stage(1, 15);
    VM_WAIT6; SBAR; SCHED0;
    compute(0);
    SBAR;
    VM_WAIT0; SBAR; SCHED0;
    compute(1);

    #pragma unroll
    for (int ni = 0; ni < 4; ++ni) {
        int gc = col0 + ni * 16 + (lane & 15);
        float bv = bias[gc];
        #pragma unroll
        for (int mi = 0; mi < 2; ++mi) {
            int gr0 = row0 + wave * 32 + mi * 16 + (lane >> 4) * 4;
            #pragma unroll
            for (int r = 0; r < 4; ++r)
                out[(size_t)(gr0 + r) * 1024 + gc] = acc[mi][ni][r] + bv;
        }
    }
}

// ---------------------------------------------------------------------------
// Sparse block attention — R12/R13 core. R14: Q in REGISTERS (2x f16x8 per
// lane, read once from the QhI image with the same swizzled offsets) and
// Pb at LSTR=64 with XOR swizzle idx^((row&7)<<3) (shorts). LDS = Kh 16K +
// Vt 16K + Pb 8K = 40960 B -> 4 blocks/CU. Values & FP order unchanged.
// ---------------------------------------------------------------------------
__global__ __launch_bounds__(256) void sparse_attn_mfma_kernel(
    const short* __restrict__ QhI, const short* __restrict__ KhI,
    const short* __restrict__ VtI,
    const float* __restrict__ qbf, const float* __restrict__ kbf,
    short* __restrict__ aout)
{
    __shared__ f16 Kh[2][4096];               // dbuf
    __shared__ f16 Vt[2][4096];               // dbuf, [d][kk] swizzled
    __shared__ f16 Pb[4096];                  // P[q][kk], LSTR=64, XOR swizzled

    const int bid = blockIdx.x;
    const int wg = (bid & 7) * 128 + (bid >> 3);  // bijective (1024 % 8 == 0)
    const int m  = wg & 31;
    const int bh = wg >> 5;
    const int b  = bh >> 4, h = bh & 15;
    const int tid = threadIdx.x;
    const int lane = tid & 63;
    const int wave = tid >> 6;
    const f32x4 zero = {0.f, 0.f, 0.f, 0.f};

    const int arow = wave * 16 + (lane & 15);
    const int kofs = (lane >> 4) * 8;      // shorts (for Pb)
    const int colb = (lane >> 4) * 16;     // bytes (for swizzled images)
    const int pswz = (arow & 7) << 3;      // Pb XOR (shorts)

    // ---- K/V tile stage: 4 issues/wave (the vmcnt quantum)
    auto stageKV = [&](int bufi, int nb) {
        const size_t t4 = (size_t)(bh * 32 + nb) * 4096;
        const int so = wave * 1024 + lane * 8;
        async_copy16(KhI + t4 + so,       (char*)&Kh[bufi][0] + wave * 2048);
        async_copy16(KhI + t4 + so + 512, (char*)&Kh[bufi][0] + wave * 2048 + 1024);
        async_copy16(VtI + t4 + so,       (char*)&Vt[bufi][0] + wave * 2048);
        async_copy16(VtI + t4 + so + 512, (char*)&Vt[bufi][0] + wave * 2048 + 1024);
    };

    // ---- diagonal tile is ALWAYS in the mask: stage it first
    stageKV(0, m);

    // ---- Q fragment to REGISTERS (same swizzled image offsets as before)
    f16x8 qreg[2];
    {
        const short* qt = QhI + (size_t)(bh * 32 + m) * 4096;
        #pragma unroll
        for (int c = 0; c < 2; ++c) {
            const int qoff = (arow * 128 + c * 64 + colb) ^ ((arow & 7) << 4);  // bytes
            qreg[c] = *(const f16x8*)((const char*)qt + qoff);
        }
    }

    // ---- in-kernel mask (R11-proven; FP order == old scores kernel).
    // Consuming the youngest mask load drains ALL older VMEM (Q regs + stage),
    // so the loop's vmcnt(4) accounting below is exact.
    unsigned int mask;
    {
        float c = -INFINITY;
        if (lane < 32) {
            const float* qrow = qbf + ((size_t)bh * 32 + m) * 64;
            const float* krow = kbf + ((size_t)bh * 32 + lane) * 64;
            float s = 0.f;
            for (int d = 0; d < 64; ++d) s += qrow[d] * krow[d];
            c = s;
        }
        float m1 = c;
        #pragma unroll
        for (int off = 1; off < 64; off <<= 1) m1 = fmaxf(m1, __shfl_xor(m1, off));
        unsigned long long eq = __ballot(c == m1);
        float cx = (c == m1) ? -INFINITY : c;
        #pragma unroll
        for (int off = 1; off < 64; off <<= 1) cx = fmaxf(cx, __shfl_xor(cx, off));
        float m2 = (__popcll(eq) >= 2) ? m1 : cx;
        unsigned long long ge = __ballot(c >= m2);
        mask = (unsigned int)(ge & 0xffffffffULL) | (1u << m);
    }

    f32x4 o_acc[4];
    float macc_s = -INFINITY, lacc_s = 0.f;   // per-lane: q = wave*16+(lane&15)
    #pragma unroll
    for (int t = 0; t < 4; ++t) o_acc[t] = zero;

    auto computeTile = [&](int bi) {
        const f16* KhB = &Kh[bi][0];
        // ---- QK^T, SWAPPED operands: mfma(K, Q) -> D[k_local][q]
        f32x4 s_acc[4];
        #pragma unroll
        for (int t = 0; t < 4; ++t) s_acc[t] = zero;
        #pragma unroll
        for (int c = 0; c < 2; ++c) {
            #pragma unroll
            for (int t = 0; t < 4; ++t) {
                const int krow = t * 16 + (lane & 15);
                const int koff = (krow * 128 + c * 64 + colb) ^ ((krow & 7) << 4);
                f16x8 bh_ = *(const f16x8*)((const char*)KhB + koff);
                s_acc[t] = __builtin_amdgcn_mfma_f32_16x16x32_f16(bh_, qreg[c], s_acc[t], 0, 0, 0);
            }
        }

        // ---- per-lane online softmax (q = arow)
        float vmax = s_acc[0][0];
        #pragma unroll
        for (int t = 0; t < 4; ++t)
            #pragma unroll
            for (int r = 0; r < 4; ++r) vmax = fmaxf(vmax, s_acc[t][r]);
        vmax = fmaxf(vmax, __shfl_xor(vmax, 16));
        vmax = fmaxf(vmax, __shfl_xor(vmax, 32));
        float mnew = fmaxf(macc_s, vmax);
        float alpha = expf(macc_s - mnew);
        macc_s = mnew;

        float psum = 0.f;
        #pragma unroll
        for (int t = 0; t < 4; ++t) {
            f16x4 pv;
            #pragma unroll
            for (int r = 0; r < 4; ++r) {
                float p = expf(s_acc[t][r] - mnew);
                psum += p;
                pv[r] = (f16)p;
            }
            // k = t*16 + (lane>>4)*4 + r; XOR flips bits 3-5 only (row-local)
            *(f16x4*)(Pb + ((arow * 64 + t * 16 + (lane >> 4) * 4) ^ pswz)) = pv;
        }
        psum += __shfl_xor(psum, 16);
        psum += __shfl_xor(psum, 32);
        lacc_s = lacc_s * alpha + psum;

        float ab[4];
        #pragma unroll
        for (int r = 0; r < 4; ++r) ab[r] = __shfl(alpha, (lane >> 4) * 4 + r);
        #pragma unroll
        for (int t = 0; t < 4; ++t)
            #pragma unroll
            for (int r = 0; r < 4; ++r) o_acc[t][r] *= ab[r];

        // ---- PV (Pb rows wave-private; same XOR on read)
        const f16* VtB = &Vt[bi][0];
        #pragma unroll
        for (int c = 0; c < 2; ++c) {
            f16x8 af = *(const f16x8*)(Pb + ((arow * 64 + c * 32 + kofs) ^ pswz));
            #pragma unroll
            for (int t = 0; t < 4; ++t) {
                const int vrow = t * 16 + (lane & 15);
                const int voff = (vrow * 128 + c * 64 + colb) ^ ((vrow & 7) << 4);
                f16x8 bf = *(const f16x8*)((const char*)VtB + voff);
                o_acc[t] = __builtin_amdgcn_mfma_f32_16x16x32_f16(af, bf, o_acc[t], 0, 0, 0);
            }
        }
    };

    // ---- pipelined masked loop: diagonal first, then set bits ascending.
    unsigned int mm = mask & ~(1u << m);
    int cur = 0;
    for (;;) {
        int nb_nxt = -1;
        if (mm) { nb_nxt = __builtin_ctz(mm); mm &= mm - 1; stageKV(cur ^ 1, nb_nxt); }
        if (nb_nxt >= 0) { VM_WAIT4; } else { VM_WAIT0; }
        SBAR; SCHED0;
        computeTile(cur);
        SBAR;
        if (nb_nxt < 0) break;
        cur ^= 1;
    }

    // ---- epilogue: normalize (broadcast inv to o_acc rows), write f16 out
    float inv_s = (lacc_s > 0.f) ? (1.f / lacc_s) : 0.f;
    float invb[4];
    #pragma unroll
    for (int r = 0; r < 4; ++r) invb[r] = __shfl(inv_s, (lane >> 4) * 4 + r);
    #pragma unroll
    for (int t = 0; t < 4; ++t) {
        int gc = h * 64 + t * 16 + (lane & 15);
        #pragma unroll
        for (int r = 0; r < 4; ++r) {
            int grow = b * NN + m * 64 + wave * 16 + (lane >> 4) * 4 + r;
            float v = o_acc[t][r] * invb[r];
            aout[(size_t)grow * 1024 + gc] = f16_bits(v);
        }
    }
}

// ===========================================================================
// FALLBACK KERNELS (round-2 proven fp32 path)
// ===========================================================================

__global__ __launch_bounds__(256) void block_mean_kernel(
    const float* __restrict__ qf, const float* __restrict__ kf,
    float* __restrict__ qbf, float* __restrict__ kbf)
{
    int idx = blockIdx.x * 256 + threadIdx.x;
    const float* src = (idx < 65536) ? qf : kf;
    float* dst       = (idx < 65536) ? qbf : kbf;
    int e = idx & 65535;
    int d = e & 63;
    int r = e >> 6;
    size_t base = (size_t)r * 4096 + d;
    float s = 0.f;
    #pragma unroll
    for (int i = 0; i < 64; ++i) s += src[base + (size_t)i * 64];
    dst[e] = s * (1.f / 64.f);
}

__global__ __launch_bounds__(256) void qkv_gemm_fb(
    const float* __restrict__ x, const float* __restrict__ w,
    float* __restrict__ qf, float* __restrict__ kf, float* __restrict__ vf)
{
    __shared__ float As[64][33];
    __shared__ float Bs[64][33];
    const int tid = threadIdx.x;
    const int row0 = blockIdx.y * 64;
    const int col0 = blockIdx.x * 64;
    const int ty = tid >> 4, tx = tid & 15;

    float acc[4][4] = {};
    for (int k0 = 0; k0 < 1024; k0 += 32) {
        #pragma unroll
        for (int i = 0; i < 8; ++i) {
            int e = tid + i * 256;
            int r = e >> 5, c = e & 31;
            As[r][c] = x[(size_t)(row0 + r) * 1024 + k0 + c];
            Bs[r][c] = w[(size_t)(col0 + r) * 1024 + k0 + c];
        }
        __syncthreads();
        #pragma unroll
        for (int kk = 0; kk < 32; ++kk) {
            float a[4], bq[4];
            #pragma unroll
            for (int i = 0; i < 4; ++i) a[i] = As[ty * 4 + i][kk];
            #pragma unroll
            for (int j = 0; j < 4; ++j) bq[j] = Bs[tx * 4 + j][kk];
            #pragma unroll
            for (int i = 0; i < 4; ++i)
                #pragma unroll
                for (int j = 0; j < 4; ++j)
                    acc[i][j] += a[i] * bq[j];
        }
        __syncthreads();
    }

    const int tsel = col0 >> 10;
    const int h    = (col0 & 1023) >> 6;
    float* dstbuf = (tsel == 0) ? qf : (tsel == 1) ? kf : vf;
    #pragma unroll
    for (int i = 0; i < 4; ++i) {
        int row = row0 + ty * 4 + i;
        int b   = row >> 11, n = row & 2047;
        size_t rb = ((size_t)(b * HH + h) * NN + n) * HD64;
        #pragma unroll
        for (int j = 0; j < 4; ++j)
            dstbuf[rb + tx * 4 + j] = acc[i][j];
    }
}

__global__ __launch_bounds__(256) void proj_gemm_fb(
    const float* __restrict__ attn, const float* __restrict__ w,
    const float* __restrict__ bias, float* __restrict__ out)
{
    __shared__ float As[64][33];
    __shared__ float Bs[64][33];
    const int tid = threadIdx.x;
    const int row0 = blockIdx.y * 64;
    const int col0 = blockIdx.x * 64;
    const int ty = tid >> 4, tx = tid & 15;

    float acc[4][4] = {};
    for (int k0 = 0; k0 < 1024; k0 += 32) {
        #pragma unroll
        for (int i = 0; i < 8; ++i) {
            int e = tid + i * 256;
            int r = e >> 5, c = e & 31;
            As[r][c] = attn[(size_t)(row0 + r) * 1024 + k0 + c];
            Bs[r][c] = w[(size_t)(col0 + r) * 1024 + k0 + c];
        }
        __syncthreads();
        #pragma unroll
        for (int kk = 0; kk < 32; ++kk) {
            float a[4], bq[4];
            #pragma unroll
            for (int i = 0; i < 4; ++i) a[i] = As[ty * 4 + i][kk];
            #pragma unroll
            for (int j = 0; j < 4; ++j) bq[j] = Bs[tx * 4 + j][kk];
            #pragma unroll
            for (int i = 0; i < 4; ++i)
                #pragma unroll
                for (int j = 0; j < 4; ++j)
                    acc[i][j] += a[i] * bq[j];
        }
        __syncthreads();
    }

    #pragma unroll
    for (int j = 0; j < 4; ++j) {
        int col = col0 + tx * 4 + j;
        float bv = bias[col];
        #pragma unroll
        for (int i = 0; i < 4; ++i) {
            int row = row0 + ty * 4 + i;
            out[(size_t)row * 1024 + col] = acc[i][j] + bv;
        }
    }
}

__global__ __launch_bounds__(256) void sparse_attn_fb(
    const float* __restrict__ qf, const float* __restrict__ kf,
    const float* __restrict__ vf, const unsigned int* __restrict__ maskbits,
    float* __restrict__ attnf)
{
    __shared__ float kbuf[64][64];
    __shared__ float vbuf[64][64];
    __shared__ float sbuf[64][65];
    const int m  = blockIdx.x & 31;
    const int bh = blockIdx.x >> 5;
    const int b  = bh >> 4, h = bh & 15;
    const int t  = threadIdx.x;
    const int qr = t >> 2;
    const int dg = t & 3;
    const int d0 = dg * 16;

    float qreg[16];
    {
        const float* qp = qf + ((size_t)bh * NN + m * 64 + qr) * HD64 + d0;
        #pragma unroll
        for (int j = 0; j < 16; j += 4) {
            float4 v = *(const float4*)(qp + j);
            qreg[j] = v.x; qreg[j+1] = v.y; qreg[j+2] = v.z; qreg[j+3] = v.w;
        }
    }

    const unsigned int mask = maskbits[bh * 32 + m];
    float macc = -INFINITY, lacc = 0.f;
    float oacc[16];
    #pragma unroll
    for (int j = 0; j < 16; ++j) oacc[j] = 0.f;

    for (int nb = 0; nb < 32; ++nb) {
        if (!((mask >> nb) & 1u)) continue;
        __syncthreads();
        {
            const float* gk = kf + ((size_t)bh * NN + nb * 64) * HD64;
            const float* gv = vf + ((size_t)bh * NN + nb * 64) * HD64;
            #pragma unroll
            for (int i = 0; i < 4; ++i) {
                async_copy16(gk + t * 4 + i * 1024, (char*)kbuf + t * 16 + i * 4096);
                async_copy16(gv + t * 4 + i * 1024, (char*)vbuf + t * 16 + i * 4096);
            }
        }
        __syncthreads();

        float bmax = -INFINITY;
        for (int kk = 0; kk < 64; ++kk) {
            float s = 0.f;
            #pragma unroll
            for (int j = 0; j < 16; ++j) s += qreg[j] * kbuf[kk][d0 + j];
            s += __shfl_xor(s, 1);
            s += __shfl_xor(s, 2);
            s *= SCALE_F;
            if (dg == 0) sbuf[qr][kk] = s;
            bmax = fmaxf(bmax, s);
        }
        float mnew  = fmaxf(macc, bmax);
        float alpha = expf(macc - mnew);
        lacc *= alpha;
        #pragma unroll
        for (int j = 0; j < 16; ++j) oacc[j] *= alpha;
        for (int kk = 0; kk < 64; ++kk) {
            float p = expf(sbuf[qr][kk] - mnew);
            lacc += p;
            #pragma unroll
            for (int j = 0; j < 16; ++j) oacc[j] += p * vbuf[kk][d0 + j];
        }
        macc = mnew;
    }

    float inv = (lacc > 0.f) ? (1.f / lacc) : 0.f;
    size_t orow = ((size_t)(b * NN + m * 64 + qr)) * DIMD + h * 64 + d0;
    #pragma unroll
    for (int j = 0; j < 16; ++j) attnf[orow + j] = oacc[j] * inv;
}

// ---------------------------------------------------------------------------
extern "C" void kernel_launch(void* const* d_in, const int* in_sizes, int n_in,
                              void* d_out, int out_size, void* d_ws, size_t ws_size,
                              hipStream_t stream)
{
    const float* x      = (const float*)d_in[0];
    const float* qkv_w  = (const float*)d_in[1];
    const float* proj_w = (const float*)d_in[2];
    const float* proj_b = (const float*)d_in[3];
    float* out = (float*)d_out;

    // Carve (fast path, ~41 MB):
    //   Qh/Kh/Vt images: 3 x 8 MB f16 tiles [1024 tiles][4096 shorts]
    //   qbf/kbf 512K | mask 4K (fallback only)
    //   Axs 8M f16 [4096][1024] (x-split; reused as attention output)
    //   Wqs 6M f16 [3072][1024] | Wp 2M f16 [1024][1024]
    short* QhI = (short*)d_ws;
    short* KhI = QhI + 4194304;
    short* VtI = KhI + 4194304;
    float* qbf = (float*)(VtI + 4194304);
    float* kbf = qbf + 65536;
    unsigned int* maskb = (unsigned int*)(kbf + 65536);
    short* Axs = (short*)(maskb + 1024);
    short* Wqs = Axs + (size_t)4096 * 1024;
    short* Wp  = Wqs + (size_t)3072 * 1024;
    const size_t need_fast = (size_t)((char*)(Wp + (size_t)1024 * 1024) - (char*)d_ws);

    if (ws_size >= need_fast) {
        split_in_fused_kernel<<<8192, 256, 0, stream>>>(x, Axs, qkv_w, Wqs, proj_w, Wp);
        qkv_mfma_kernel<<<768, 256, 0, stream>>>(Axs, Wqs, QhI, KhI, VtI, qbf, kbf);
        sparse_attn_mfma_kernel<<<1024, 256, 0, stream>>>(QhI, KhI, VtI, qbf, kbf, Axs);
        proj_mfma_kernel<<<512, 256, 0, stream>>>(Axs, Wp, proj_b, out);
    } else {
        float* qf2  = (float*)d_ws;
        float* kf2  = qf2 + 4194304;
        float* vf2  = kf2 + 4194304;
        float* qbf2 = vf2 + 4194304;
        float* kbf2 = qbf2 + 65536;
        unsigned int* maskb2 = (unsigned int*)(kbf2 + 65536);
        float* attnf = (float*)(maskb2 + 1024);
        qkv_gemm_fb<<<dim3(48, 64), 256, 0, stream>>>(x, qkv_w, qf2, kf2, vf2);
        block_mean_kernel<<<512, 256, 0, stream>>>(qf2, kf2, qbf2, kbf2);
        scores_splitw_kernel<<<32, 256, 0, stream>>>(qbf2, kbf2, maskb2, SCALE_F,
                                                     (const float*)nullptr, (short*)nullptr);
        sparse_attn_fb<<<1024, 256, 0, stream>>>(qf2, kf2, vf2, maskb2, attnf);
        proj_gemm_fb<<<dim3(16, 64), 256, 0, stream>>>(attnf, proj_w, proj_b, out);
    }
}